// Round 11
// baseline (768.373 us; speedup 1.0000x reference)
//
#include <hip/hip_runtime.h>
#include <hip/hip_bf16.h>
#include <math.h>

typedef __hip_bfloat16 bf16;
typedef __attribute__((ext_vector_type(8))) short short8;   // 8 bf16 in 4 VGPRs
typedef __attribute__((ext_vector_type(4))) float f32x4;

#define B_ 2
#define N_ 48
#define A_ 16
#define E_ 5
#define HID 384
#define NHD 8
#define HD 48
#define LYR 4
#define MLPD 1536
#define L_ 2352      // N_ + N_*N_
#define M_ 4704      // B_*L_
#define VLP 2432     // padded key stride of transposed-V buffer
// 1/sqrt(48) * log2(e): Q pre-scale so softmax runs in log2 domain (exp2f)
#define QSCALE 0.20823513f

// prepped-weight element offsets (bf16, transposed [n][k] per matrix)
#define WQ_  0LL
#define WK_  589824LL
#define WV_  1179648LL
#define WO_  1769472LL
#define WM1_ 2359296LL
#define WM2_ 4718592LL
#define WTOT 7077888
// prepped-bias offsets
#define BQ_  0
#define BK_  1536
#define BV_  3072
#define BO_  4608
#define BM1_ 6144
#define BM2_ 12288
#define BTOT 13824

// flash-decode partials: [16 bh][2368 q][2 half] — o normalized (48 bf16) + (m,l) f32
#define PO_E  ((size_t)16*2368*2*48)   // bf16 elems
#define PML_E ((size_t)16*2368*2*2)    // f32 elems

// async global->LDS 16B direct copy (gfx950); LDS dest must be linear per-lane
#define GLOAD16(gp, lp) __builtin_amdgcn_global_load_lds( \
    (const __attribute__((address_space(1))) unsigned int*)(gp), \
    (__attribute__((address_space(3))) unsigned int*)(lp), 16, 0, 0)

static __device__ __forceinline__ float b2f(bf16 v) { return __bfloat162float(v); }
static __device__ __forceinline__ float us2f(unsigned short u) {
    return __uint_as_float(((unsigned)u) << 16);
}
static __device__ __forceinline__ unsigned short f2us(float f) {
    bf16 h = __float2bfloat16(f);
    return *reinterpret_cast<unsigned short*>(&h);
}
// raw v_exp_f32: 1 inst vs libm exp2f's denorm-fixup sequence; inputs <= 0,
// HW flush-to-zero on underflow is exactly softmax semantics.
static __device__ __forceinline__ float exp2_raw(float x) {
    float r;
    asm("v_exp_f32 %0, %1" : "=v"(r) : "v"(x));
    return r;
}
static __device__ __forceinline__ float ldv(const float* p, size_t i) { return p[i]; }
static __device__ __forceinline__ float ldv(const bf16*  p, size_t i) { return b2f(p[i]); }
static __device__ __forceinline__ void  stv(float* p, size_t i, float v) { p[i] = v; }
static __device__ __forceinline__ void  stv(bf16*  p, size_t i, float v) { p[i] = __float2bfloat16(v); }
static __device__ __forceinline__ float4 ld4(const float* p, size_t i) {
    return *reinterpret_cast<const float4*>(p + i);
}
static __device__ __forceinline__ float4 ld4(const bf16* p, size_t i) {
    ushort4 u = *reinterpret_cast<const ushort4*>(p + i);
    return make_float4(us2f(u.x), us2f(u.y), us2f(u.z), us2f(u.w));
}

// ------------------------------------------------ dtype detect (flag: 1=fp32, 0=bf16)
__global__ void k_detect(const void* w, int* flag) {
    if (threadIdx.x == 0 && blockIdx.x == 0) {
        const bf16* p = (const bf16*)w;   // node_w: 6144 elems of 0.02*normal
        int isf = 0;
        for (int i = 0; i < 256; ++i) {
            float v = fabsf(b2f(p[i]));
            if (!(v <= 1000.0f)) { isf = 1; break; }
        }
        *flag = isf;
    }
}

// ------------------------------------- weight prep: convert + transpose to [n][k] bf16
template <typename T>
static __device__ void prepw_body(
    const T* q_w, const T* k_w, const T* v_w, const T* o_w,
    const T* m1_w, const T* m2_w, bf16* wbt)
{
    __shared__ unsigned short Ts[64][72];
    const int z = blockIdx.y;
    const int kind = z >> 2, l = z & 3;
    const T* src; int K, N; long long dbase;
    switch (kind) {
        case 0: src = q_w;  K = 384;  N = 384;  dbase = WQ_;  break;
        case 1: src = k_w;  K = 384;  N = 384;  dbase = WK_;  break;
        case 2: src = v_w;  K = 384;  N = 384;  dbase = WV_;  break;
        case 3: src = o_w;  K = 384;  N = 384;  dbase = WO_;  break;
        case 4: src = m1_w; K = 384;  N = 1536; dbase = WM1_; break;
        default: src = m2_w; K = 1536; N = 384; dbase = WM2_; break;
    }
    const int Nt = N >> 6;
    const int tiles = (K >> 6) * Nt;
    if (blockIdx.x >= tiles) return;
    const int tk = blockIdx.x / Nt, tn = blockIdx.x % Nt;
    const int k0 = tk*64, n0 = tn*64;
    const size_t soff = (size_t)l * K * N;
    const size_t doff = (size_t)dbase + (size_t)l * K * N;
    const int tid = threadIdx.x;
    {   // load 64x64 fp tile -> bf16 LDS
        const int kk = tid >> 2, nc = (tid & 3) * 16;
        #pragma unroll
        for (int j = 0; j < 16; ++j)
            Ts[kk][nc + j] = f2us(ldv(src, soff + (size_t)(k0 + kk)*N + n0 + nc + j));
    }
    __syncthreads();
    {   // store transposed [n][k] with b128 writes
        const int nn = tid >> 2, kc = (tid & 3) * 16;
        unsigned short tmp[16];
        #pragma unroll
        for (int j = 0; j < 16; ++j) tmp[j] = Ts[kc + j][nn];
        unsigned short* dst = (unsigned short*)wbt + doff + (size_t)(n0 + nn)*K + k0 + kc;
        *reinterpret_cast<short8*>(dst)     = *reinterpret_cast<short8*>(&tmp[0]);
        *reinterpret_cast<short8*>(dst + 8) = *reinterpret_cast<short8*>(&tmp[8]);
    }
}

__global__ __launch_bounds__(256) void k_prepw(
    const void* q_w, const void* k_w, const void* v_w, const void* o_w,
    const void* m1_w, const void* m2_w, const int* __restrict__ fl, bf16* __restrict__ wbt)
{
    if (*fl) prepw_body<float>((const float*)q_w, (const float*)k_w, (const float*)v_w,
                               (const float*)o_w, (const float*)m1_w, (const float*)m2_w, wbt);
    else     prepw_body<bf16>((const bf16*)q_w, (const bf16*)k_w, (const bf16*)v_w,
                              (const bf16*)o_w, (const bf16*)m1_w, (const bf16*)m2_w, wbt);
}

template <typename T>
static __device__ void prepb_body(
    const T* q_b, const T* k_b, const T* v_b, const T* o_b,
    const T* m1_b, const T* m2_b, bf16* bb)
{
    for (int i = threadIdx.x; i < BTOT; i += 256) {
        float v;
        if      (i < BK_)  v = ldv(q_b,  i);
        else if (i < BV_)  v = ldv(k_b,  i - BK_);
        else if (i < BO_)  v = ldv(v_b,  i - BV_);
        else if (i < BM1_) v = ldv(o_b,  i - BO_);
        else if (i < BM2_) v = ldv(m1_b, i - BM1_);
        else               v = ldv(m2_b, i - BM2_);
        bb[i] = __float2bfloat16(v);
    }
}

__global__ __launch_bounds__(256) void k_prepb(
    const void* q_b, const void* k_b, const void* v_b, const void* o_b,
    const void* m1_b, const void* m2_b, const int* __restrict__ fl, bf16* __restrict__ bb)
{
    if (*fl) prepb_body<float>((const float*)q_b, (const float*)k_b, (const float*)v_b,
                               (const float*)o_b, (const float*)m1_b, (const float*)m2_b, bb);
    else     prepb_body<bf16>((const bf16*)q_b, (const bf16*)k_b, (const bf16*)v_b,
                              (const bf16*)o_b, (const bf16*)m1_b, (const bf16*)m2_b, bb);
}

// ---------------------------------------------------------------- embed (-> f32 h)
template <typename T>
static __device__ void embed_body(
    const T* x, const T* adj, const T* node_w, const T* node_b,
    const T* edge_w, const T* edge_b, const T* pos, float* h)
{
    const int bl = blockIdx.x;
    const int b = bl / L_, l = bl % L_;
    const int c = threadIdx.x;          // 0..383
    float acc;
    if (l < N_) {
        acc = ldv(node_b, c);
        const size_t xr = (size_t)(b*N_ + l)*A_;
        #pragma unroll
        for (int a = 0; a < A_; ++a) acc += ldv(x, xr + a) * ldv(node_w, (size_t)a*HID + c);
    } else {
        const int e = l - N_;
        acc = ldv(edge_b, c);
        const size_t ar = ((size_t)b*N_*N_ + e)*E_;
        #pragma unroll
        for (int j = 0; j < E_; ++j) acc += ldv(adj, ar + j) * ldv(edge_w, (size_t)j*HID + c);
    }
    h[(size_t)bl*HID + c] = acc + ldv(pos, (size_t)l*HID + c);
}

__global__ __launch_bounds__(384) void k_embed(
    const void* x, const void* adj, const void* node_w, const void* node_b,
    const void* edge_w, const void* edge_b, const void* pos,
    const int* __restrict__ fl, float* __restrict__ h)
{
    if (*fl) embed_body<float>((const float*)x, (const float*)adj, (const float*)node_w,
                               (const float*)node_b, (const float*)edge_w, (const float*)edge_b,
                               (const float*)pos, h);
    else     embed_body<bf16>((const bf16*)x, (const bf16*)adj, (const bf16*)node_w,
                              (const bf16*)node_b, (const bf16*)edge_w, (const bf16*)edge_b,
                              (const bf16*)pos, h);
}

// ---------------------------------------- cond stage 1: temb -> hidden (SiLU)
template <typename T>
static __device__ void cond1_body(const T* t, const T* t_w1, const T* t_b1, float* hid)
{
    __shared__ float temb[HID];
    __shared__ float red[4][64];
    const int b = blockIdx.x, jb = blockIdx.y, tid = threadIdx.x;
    const float tv = ldv(t, b);
    for (int c = tid; c < HID; c += 256) {
        int i = (c < 192) ? c : c - 192;
        float f = expf(-9.2103403719761836f * (float)i / 192.0f);
        float ang = tv * f;
        temb[c] = (c < 192) ? sinf(ang) : cosf(ang);
    }
    __syncthreads();
    const int ko = tid >> 6, jo = tid & 63;
    const int j = jb*64 + jo;
    float acc = 0.f;
    for (int i = ko*96; i < (ko + 1)*96; ++i)
        acc += temb[i] * ldv(t_w1, (size_t)i*4*HID + j);
    red[ko][jo] = acc;
    __syncthreads();
    if (ko == 0) {
        float a = red[0][jo] + red[1][jo] + red[2][jo] + red[3][jo] + ldv(t_b1, j);
        hid[(size_t)b*4*HID + j] = a / (1.0f + expf(-a));   // SiLU
    }
}

__global__ __launch_bounds__(256) void k_cond1(
    const void* t, const void* t_w1, const void* t_b1,
    const int* __restrict__ fl, float* __restrict__ hid)
{
    if (*fl) cond1_body<float>((const float*)t, (const float*)t_w1, (const float*)t_b1, hid);
    else     cond1_body<bf16>((const bf16*)t, (const bf16*)t_w1, (const bf16*)t_b1, hid);
}

// ---------------------------------------- cond stage 2: hidden -> partial cond sums
template <typename T>
static __device__ void cond2_body(const T* t_w2, const T* t_b2, const float* hid, float* part)
{
    __shared__ float hs[128];
    const int b = blockIdx.x, ch = blockIdx.y, c = threadIdx.x;
    const int j0 = ch*128;
    if (c < 128) hs[c] = hid[(size_t)b*4*HID + j0 + c];
    __syncthreads();
    float acc = (ch == 0) ? ldv(t_b2, c) : 0.f;
    for (int jj = 0; jj < 128; ++jj)
        acc += hs[jj] * ldv(t_w2, (size_t)(j0 + jj)*HID + c);
    part[((size_t)b*12 + ch)*HID + c] = acc;
}

__global__ __launch_bounds__(384) void k_cond2(
    const void* t_w2, const void* t_b2, const int* __restrict__ fl,
    const float* __restrict__ hid, float* __restrict__ part)
{
    if (*fl) cond2_body<float>((const float*)t_w2, (const float*)t_b2, hid, part);
    else     cond2_body<bf16>((const bf16*)t_w2, (const bf16*)t_b2, hid, part);
}

// ---------------------------------------- cond stage 3: ada projections
template <typename T>
static __device__ void cond3_body(
    const T* ada1_w, const T* ada1_b, const T* ada2_w, const T* ada2_b,
    const float* part, float* ada_out)
{
    __shared__ float cs[HID];
    const int slot = blockIdx.x / 3, ob = blockIdx.x % 3, b = blockIdx.y;
    const int tid = threadIdx.x;
    for (int c = tid; c < HID; c += 256) {
        float s = 0.f;
        #pragma unroll
        for (int ch = 0; ch < 12; ++ch) s += part[((size_t)b*12 + ch)*HID + c];
        cs[c] = s;
    }
    __syncthreads();
    const int layer = slot >> 1, which = slot & 1;
    const int o = ob*256 + tid;
    const T* W  = which ? ada2_w : ada1_w;
    const T* Bi = which ? ada2_b : ada1_b;
    float acc = ldv(Bi, (size_t)layer*768 + o);
    const size_t wb = (size_t)layer*HID*768 + o;
    for (int c = 0; c < HID; ++c) acc += cs[c] * ldv(W, wb + (size_t)c*768);
    ada_out[((size_t)slot*B_ + b)*768 + o] = acc;
}

__global__ __launch_bounds__(256) void k_cond3(
    const void* ada1_w, const void* ada1_b, const void* ada2_w, const void* ada2_b,
    const int* __restrict__ fl, const float* __restrict__ part, float* __restrict__ ada_out)
{
    if (*fl) cond3_body<float>((const float*)ada1_w, (const float*)ada1_b,
                               (const float*)ada2_w, (const float*)ada2_b, part, ada_out);
    else     cond3_body<bf16>((const bf16*)ada1_w, (const bf16*)ada1_b,
                              (const bf16*)ada2_w, (const bf16*)ada2_b, part, ada_out);
}

// ---------------------------------------------------------------- adaLN (f32 h -> bf16 n)
__global__ __launch_bounds__(256) void k_adaln(
    const float* __restrict__ h, const float* __restrict__ ada,
    bf16* __restrict__ n, int slot)
{
    const int row  = blockIdx.x * 4 + (threadIdx.x >> 6);
    const int lane = threadIdx.x & 63;
    const int b = row / L_;
    const float* hr = h + (size_t)row*HID;
    float v[6]; float s = 0.f, ss = 0.f;
    #pragma unroll
    for (int j = 0; j < 6; ++j) { float t = hr[lane + j*64]; v[j] = t; s += t; ss += t*t; }
    #pragma unroll
    for (int off = 32; off; off >>= 1) { s += __shfl_xor(s, off); ss += __shfl_xor(ss, off); }
    const float mu = s * (1.0f/HID);
    const float rs = rsqrtf(fmaxf(ss * (1.0f/HID) - mu*mu, 0.0f) + 1e-5f);
    const float* ap = ada + ((size_t)slot*B_ + b)*768;
    bf16* nr = n + (size_t)row*HID;
    #pragma unroll
    for (int j = 0; j < 6; ++j) {
        int c = lane + j*64;
        nr[c] = __float2bfloat16((v[j] - mu)*rs*(1.0f + ap[c]) + ap[384 + c]);
    }
}

// ------------------------------------------------- MFMA GEMM epilogue (shared)
// mode: 0=bf16 store, 1=f32 +=, 2=V^T bf16 scatter, 3=bf16 store*QSCALE
static __device__ __forceinline__ void gemm_epilogue(
    f32x4 (&acc)[2][2], float bcol0, float bcol1,
    bf16* Cb, float* Cf, int M, int N, int act, int mode,
    int bm, int bn, int wm, int wn, int quad, int c)
{
    const float bcol[2] = {bcol0, bcol1};
    #pragma unroll
    for (int mi = 0; mi < 2; ++mi)
        #pragma unroll
        for (int ni = 0; ni < 2; ++ni) {
            const int col = bn + wn*32 + ni*16 + c;
            #pragma unroll
            for (int r = 0; r < 4; ++r) {
                const int row = bm + wm*32 + mi*16 + quad*4 + r;
                if (row < M) {
                    float v = acc[mi][ni][r] + bcol[ni];
                    if (act) v = 0.5f * v * (1.0f + erff(v * 0.70710678118654752f));  // GELU
                    if (mode == 1) Cf[(size_t)row*N + col] += v;
                    else if (mode == 0) Cb[(size_t)row*N + col] = __float2bfloat16(v);
                    else if (mode == 3) Cb[(size_t)row*N + col] = __float2bfloat16(v * QSCALE);
                    else {
                        const int b   = row >= L_ ? 1 : 0;
                        const int key = row - b*L_;
                        const int hh  = col / 48, d = col - hh*48;
                        Cb[((size_t)(b*8 + hh)*48 + d)*VLP + key] = __float2bfloat16(v);
                    }
                }
            }
        }
}

// -------- legacy GEMM: W fp32/bf16 [k][n], converted+transposed during staging
template <typename T>
static __device__ void gemm_body(
    const bf16* A, const T* W, long long woff, const T* bias, long long boff,
    bf16* Cb, float* Cf, int M, int N, int K, int act, int mode)
{
    __shared__ __align__(16) unsigned short As[64][72];
    __shared__ __align__(16) unsigned short Bt[64][72];
    const int tid  = threadIdx.x;
    const int wv   = tid >> 6, lane = tid & 63;
    const int quad = lane >> 4, c = lane & 15;
    const int wm = wv & 1, wn = wv >> 1;
    const int bm = blockIdx.x * 64, bn = blockIdx.y * 64;
    const int arow = tid >> 3, ach = tid & 7;
    f32x4 acc[2][2] = {{{0.f,0.f,0.f,0.f},{0.f,0.f,0.f,0.f}},
                       {{0.f,0.f,0.f,0.f},{0.f,0.f,0.f,0.f}}};
    for (int k0 = 0; k0 < K; k0 += 64) {
        short8 av[2]; float4 w0[2], w1[2];
        #pragma unroll
        for (int i = 0; i < 2; ++i) {
            const int row = i*32 + arow;
            av[i] = short8{0,0,0,0,0,0,0,0};
            if (bm + row < M)
                av[i] = *reinterpret_cast<const short8*>(
                            A + (size_t)(bm + row)*K + k0 + ach*8);
            const size_t wrow = (size_t)woff + (size_t)(k0 + i*32 + arow)*N + bn + ach*8;
            w0[i] = ld4(W, wrow);
            w1[i] = ld4(W, wrow + 4);
        }
        __syncthreads();
        #pragma unroll
        for (int i = 0; i < 2; ++i) {
            *reinterpret_cast<short8*>(&As[i*32 + arow][ach*8]) = av[i];
            const int kk = i*32 + arow, nb0 = ach*8;
            Bt[nb0+0][kk] = f2us(w0[i].x); Bt[nb0+1][kk] = f2us(w0[i].y);
            Bt[nb0+2][kk] = f2us(w0[i].z); Bt[nb0+3][kk] = f2us(w0[i].w);
            Bt[nb0+4][kk] = f2us(w1[i].x); Bt[nb0+5][kk] = f2us(w1[i].y);
            Bt[nb0+6][kk] = f2us(w1[i].z); Bt[nb0+7][kk] = f2us(w1[i].w);
        }
        __syncthreads();
        #pragma unroll
        for (int ks = 0; ks < 2; ++ks) {
            short8 af[2], bfr[2];
            #pragma unroll
            for (int mi = 0; mi < 2; ++mi)
                af[mi] = *reinterpret_cast<const short8*>(
                             &As[wm*32 + mi*16 + c][ks*32 + quad*8]);
            #pragma unroll
            for (int ni = 0; ni < 2; ++ni)
                bfr[ni] = *reinterpret_cast<const short8*>(
                              &Bt[wn*32 + ni*16 + c][ks*32 + quad*8]);
            #pragma unroll
            for (int mi = 0; mi < 2; ++mi)
                #pragma unroll
                for (int ni = 0; ni < 2; ++ni)
                    acc[mi][ni] = __builtin_amdgcn_mfma_f32_16x16x32_bf16(
                                      af[mi], bfr[ni], acc[mi][ni], 0, 0, 0);
        }
    }
    gemm_epilogue(acc, ldv(bias, (size_t)boff + bn + wn*32 + c),
                  ldv(bias, (size_t)boff + bn + wn*32 + 16 + c),
                  Cb, Cf, M, N, act, mode, bm, bn, wm, wn, quad, c);
}

__global__ __launch_bounds__(256) void k_gemm(
    const bf16* __restrict__ A, const void* W, long long woff, const void* bias, long long boff,
    bf16* Cb, float* Cf, int M, int N, int K, int act, int mode,
    const int* __restrict__ fl)
{
    if (*fl) gemm_body<float>(A, (const float*)W, woff, (const float*)bias, boff,
                              Cb, Cf, M, N, K, act, mode);
    else     gemm_body<bf16>(A, (const bf16*)W, woff, (const bf16*)bias, boff,
                             Cb, Cf, M, N, K, act, mode);
}

__global__ __launch_bounds__(256) void k_gemm_qkv(
    const bf16* __restrict__ A,
    const void* qw, const void* kw, const void* vw,
    const void* qb, const void* kb, const void* vb,
    long long woff, long long boff,
    bf16* Cq, bf16* Ck, bf16* Cv, const int* __restrict__ fl)
{
    const int z = blockIdx.z;
    const void* W  = (z == 0) ? qw : (z == 1) ? kw : vw;
    const void* Bi = (z == 0) ? qb : (z == 1) ? kb : vb;
    bf16* C        = (z == 0) ? Cq : (z == 1) ? Ck : Cv;
    const int mode = (z == 0) ? 3 : (z == 2) ? 2 : 0;
    if (*fl) gemm_body<float>(A, (const float*)W, woff, (const float*)Bi, boff,
                              C, nullptr, M_, HID, HID, 0, mode);
    else     gemm_body<bf16>(A, (const bf16*)W, woff, (const bf16*)Bi, boff,
                             C, nullptr, M_, HID, HID, 0, mode);
}

// -------- prepped GEMM: W bf16 pre-transposed [n][k].
// 2-phase schedule: double-buffered LDS, global_load_lds (16B, direct-to-LDS,
// no VGPR round-trip), ONE barrier per K-tile. Rule #21 both-sides swizzle.
static __device__ void gemm_t_body(
    const bf16* A, const bf16* Wt, long long woff, const bf16* bias, long long boff,
    bf16* Cb, float* Cf, int M, int N, int K, int act, int mode)
{
    __shared__ __align__(16) unsigned short Tz[2][2][4096];   // [buf][A/W][64*64] 32KB
    const int tid  = threadIdx.x;
    const int wv   = tid >> 6, lane = tid & 63;
    const int quad = lane >> 4, c = lane & 15;
    const int wm = wv & 1, wn = wv >> 1;
    const int bm = blockIdx.x * 64, bn = blockIdx.y * 64;
    const unsigned short* Ag = (const unsigned short*)A;
    const unsigned short* Wg = (const unsigned short*)Wt + woff;
    // staging geometry: thread -> 2 rows (j=0,1), 16B each, linear LDS dest
    const int sr = tid >> 3;                       // row within 32-row half
    const int csw0 = (((tid & 7) ^ (sr & 7)) << 3);      // inverse-swizzled col (elems)
    int ar0 = bm + sr;        ar0 = ar0 < M ? ar0 : M - 1;
    int ar1 = bm + 32 + sr;   ar1 = ar1 < M ? ar1 : M - 1;
    const int wr0 = bn + sr, wr1 = bn + 32 + sr;
    const int ldso = tid * 8;                      // elems within 2048-elem half

    f32x4 acc[2][2] = {{{0.f,0.f,0.f,0.f},{0.f,0.f,0.f,0.f}},
                       {{0.f,0.f,0.f,0.f},{0.f,0.f,0.f,0.f}}};

    #define STAGE_T(buf, k0) do { \
        GLOAD16(Ag + (size_t)ar0*K + (k0) + csw0, &Tz[buf][0][ldso]); \
        GLOAD16(Ag + (size_t)ar1*K + (k0) + csw0, &Tz[buf][0][2048 + ldso]); \
        GLOAD16(Wg + (size_t)wr0*K + (k0) + csw0, &Tz[buf][1][ldso]); \
        GLOAD16(Wg + (size_t)wr1*K + (k0) + csw0, &Tz[buf][1][2048 + ldso]); \
    } while (0)

    STAGE_T(0, 0);
    __syncthreads();                               // vmcnt(0) drain + barrier
    int cur = 0;
    for (int k0 = 0; k0 < K; k0 += 64) {
        if (k0 + 64 < K) STAGE_T(cur ^ 1, k0 + 64);    // async loads for next tile
        #pragma unroll
        for (int ks = 0; ks < 2; ++ks) {
            short8 af[2], bfr[2];
            #pragma unroll
            for (int mi = 0; mi < 2; ++mi) {
                const int row = wm*32 + mi*16 + c;
                const char* p = (const char*)&Tz[cur][0][0]
                              + (row*128 + (((ks*64 + quad*16)) ^ ((row & 7) << 4)));
                af[mi] = *reinterpret_cast<const short8*>(p);
            }
            #pragma unroll
            for (int ni = 0; ni < 2; ++ni) {
                const int row = wn*32 + ni*16 + c;
                const char* p = (const char*)&Tz[cur][1][0]
                              + (row*128 + (((ks*64 + quad*16)) ^ ((row & 7) << 4)));
                bfr[ni] = *reinterpret_cast<const short8*>(p);
            }
            #pragma unroll
            for (int mi = 0; mi < 2; ++mi)
                #pragma unroll
                for (int ni = 0; ni < 2; ++ni)
                    acc[mi][ni] = __builtin_amdgcn_mfma_f32_16x16x32_bf16(
                                      af[mi], bfr[ni], acc[mi][ni], 0, 0, 0);
        }
        __syncthreads();                           // drains next-tile loads + read fence
        cur ^= 1;
    }
    #undef STAGE_T
    gemm_epilogue(acc, b2f(bias[boff + bn + wn*32 + c]),
                  b2f(bias[boff + bn + wn*32 + 16 + c]),
                  Cb, Cf, M, N, act, mode, bm, bn, wm, wn, quad, c);
}

__global__ __launch_bounds__(256) void k_gemm_t(
    const bf16* __restrict__ A, const bf16* __restrict__ Wt, long long woff,
    const bf16* __restrict__ bias, long long boff,
    bf16* Cb, float* Cf, int M, int N, int K, int act, int mode)
{
    gemm_t_body(A, Wt, woff, bias, boff, Cb, Cf, M, N, K, act, mode);
}

__global__ __launch_bounds__(256) void k_gemm_qkv_t(
    const bf16* __restrict__ A, const bf16* __restrict__ wbt, const bf16* __restrict__ bb,
    int lyr, bf16* Cq, bf16* Ck, bf16* Cv)
{
    const int z = blockIdx.z;
    long long woff; long long boff; bf16* C; int mode;
    if (z == 0)      { woff = WQ_ + (long long)lyr*147456; boff = BQ_ + lyr*384; C = Cq; mode = 3; }
    else if (z == 1) { woff = WK_ + (long long)lyr*147456; boff = BK_ + lyr*384; C = Ck; mode = 0; }
    else             { woff = WV_ + (long long)lyr*147456; boff = BV_ + lyr*384; C = Cv; mode = 2; }
    gemm_t_body(A, wbt, woff, bb, boff, C, nullptr, M_, HID, HID, 0, mode);
}

// -------- 32-row-tile prepped GEMM (f32 += epilogue), for grid-starved dispatches.
// O-proj and M2 at 64-row tiles give 444 blocks = 1.7/CU (latency-bound). M=4704 =
// 147x32 exactly: 32-row tiles -> 882 blocks = 3.45/CU, LDS 24KB (6 blocks/CU cap).
// Same 2-phase gload_lds schedule + rule-#21 swizzle; each wave computes 16x32.
__global__ __launch_bounds__(256) void k_gemm_t32(
    const bf16* __restrict__ A, const bf16* __restrict__ Wt, long long woff,
    const bf16* __restrict__ bias, long long boff,
    float* __restrict__ Cf, int M, int N, int K)
{
    __shared__ __align__(16) unsigned short Az[2][2048];   // [buf][32 rows x 64 k]
    __shared__ __align__(16) unsigned short Wz[2][4096];   // [buf][64 cols x 64 k]
    const int tid  = threadIdx.x;
    const int wv   = tid >> 6, lane = tid & 63;
    const int quad = lane >> 4, c = lane & 15;
    const int wm = wv & 1, wn = wv >> 1;
    const int bm = blockIdx.x * 32, bn = blockIdx.y * 64;
    const unsigned short* Ag = (const unsigned short*)A;
    const unsigned short* Wg = (const unsigned short*)Wt + woff;
    const int sr = tid >> 3;                       // 0..31
    const int csw0 = (((tid & 7) ^ (sr & 7)) << 3);
    const int ar = bm + sr;                        // 147x32 = M exactly, no clamp
    const int wr0 = bn + sr, wr1 = bn + 32 + sr;
    const int ldso = tid * 8;

    f32x4 acc[2] = {{0.f,0.f,0.f,0.f},{0.f,0.f,0.f,0.f}};

    #define STAGE_T32(buf, k0) do { \
        GLOAD16(Ag + (size_t)ar*K + (k0) + csw0, &Az[buf][ldso]); \
        GLOAD16(Wg + (size_t)wr0*K + (k0) + csw0, &Wz[buf][ldso]); \
        GLOAD16(Wg + (size_t)wr1*K + (k0) + csw0, &Wz[buf][2048 + ldso]); \
    } while (0)

    STAGE_T32(0, 0);
    __syncthreads();
    int cur = 0;
    for (int k0 = 0; k0 < K; k0 += 64) {
        if (k0 + 64 < K) STAGE_T32(cur ^ 1, k0 + 64);
        #pragma unroll
        for (int ks = 0; ks < 2; ++ks) {
            short8 af, bfr[2];
            {
                const int row = wm*16 + c;
                const char* p = (const char*)&Az[cur][0]
                              + (row*128 + ((ks*64 + quad*16) ^ ((row & 7) << 4)));
                af = *reinterpret_cast<const short8*>(p);
            }
            #pragma unroll
            for (int ni = 0; ni < 2; ++ni) {
                const int row = wn*32 + ni*16 + c;
                const char* p = (const char*)&Wz[cur][0]
                              + (row*128 + ((ks*64 + quad*16) ^ ((row & 7) << 4)));
                bfr[ni] = *reinterpret_cast<const short8*>(p);
            }
            #pragma unroll
            for (int ni = 0; ni < 2; ++ni)
                acc[ni] = __builtin_amdgcn_mfma_f32_16x16x32_bf16(af, bfr[ni], acc[ni], 0, 0, 0);
        }
        __syncthreads();
        cur ^= 1;
    }
    #undef STAGE_T32
    // epilogue: f32 += (bias included)
    #pragma unroll
    for (int ni = 0; ni < 2; ++ni) {
        const int col = bn + wn*32 + ni*16 + c;
        const float bcol = b2f(bias[boff + col]);
        #pragma unroll
        for (int r = 0; r < 4; ++r) {
            const int row = bm + wm*16 + quad*4 + r;
            Cf[(size_t)row*N + col] += acc[ni][r] + bcol;
        }
    }
}

// ---------------------------------------------------------------- MFMA flash attention
// (fallback) 64 queries/block, 8 waves, in-block split-K x2 — used when ws lacks
// room for flash-decode partials.
__global__ __launch_bounds__(512) void k_attn(
    const bf16* __restrict__ q, const bf16* __restrict__ k,
    const bf16* __restrict__ vt, bf16* __restrict__ ao)
{
    __shared__ __align__(16) unsigned short Ks[2][64][80];   // [split][key][d 0..63 +pad]
    __shared__ __align__(16) unsigned short Vt[2][48][72];   // [split][d][key 0..63 +pad]
    __shared__ __align__(16) unsigned short Pq[8][16][72];   // [wave][query][key 0..63 +pad]
    const int tid  = threadIdx.x;
    const int w    = tid >> 6, lane = tid & 63;
    const int quad = lane >> 4, c = lane & 15;
    const int qt = w & 3, sp = w >> 2;               // q-tile 0..3, split 0..1
    const int bh = blockIdx.y;                       // b*8+hh
    const size_t base  = (size_t)(bh >> 3)*L_*HID + (size_t)(bh & 7)*HD;
    const size_t vbase = (size_t)bh*48*VLP;
    const int q0 = blockIdx.x*64 + qt*16;
    const bool qvalid = q0 < L_;                     // wave-uniform
    const int qrow = qvalid ? (q0 + c) : c;

    short8 qf0, qf1;
    {
        const unsigned short* qp = (const unsigned short*)(q + base + (size_t)qrow*HID);
        qf0 = *reinterpret_cast<const short8*>(qp + quad*8);                 // d 0..31
        if (quad < 2) qf1 = *reinterpret_cast<const short8*>(qp + 32 + quad*8);  // d 32..47
        else          qf1 = short8{0,0,0,0,0,0,0,0};                         // d 48..63 pad
    }
    f32x4 o0 = {0.f,0.f,0.f,0.f}, o1 = {0.f,0.f,0.f,0.f}, o2 = {0.f,0.f,0.f,0.f};
    float m = -3.0e38f, lsum = 0.f;

    // ---- staging assignment: 256-thread group per split
    const int t256 = tid & 255, grp = tid >> 8;
    const int krow0 = t256 >> 3, kch = t256 & 7;     // K row 0..31 / ch 0..7
    const int krow1 = 32 + krow0;                    // K row 32..63
    const int vd0 = krow0;                           // V d 0..31
    const int vd1 = 32 + (krow0 & 15);               // V d 32..47 (t256<128 only)
    const bool vl1 = (t256 < 128);
    const unsigned short* kq = (const unsigned short*)(k + base);
    const unsigned short* vq = (const unsigned short*)(vt + vbase);
    const short8 Z8 = short8{0,0,0,0,0,0,0,0};
    short8 kr0 = Z8, kr1 = Z8, vr0, vr1 = Z8;
    {   // prefetch tile 0 (keys unclamped: OOB tail lands inside workspace, masked in S)
        const int kb0 = grp*1216;
        if (kch < 6) {
            kr0 = *reinterpret_cast<const short8*>(kq + (size_t)(kb0 + krow0)*HID + kch*8);
            kr1 = *reinterpret_cast<const short8*>(kq + (size_t)(kb0 + krow1)*HID + kch*8);
        }
        vr0 = *reinterpret_cast<const short8*>(vq + (size_t)vd0*VLP + kb0 + kch*8);
        if (vl1) vr1 = *reinterpret_cast<const short8*>(vq + (size_t)vd1*VLP + kb0 + kch*8);
    }

    for (int tt = 0; tt < 19; ++tt) {
        __syncthreads();                             // prev tile's LDS reads done
        *reinterpret_cast<short8*>(&Ks[grp][krow0][kch*8]) = kr0;
        *reinterpret_cast<short8*>(&Ks[grp][krow1][kch*8]) = kr1;
        *reinterpret_cast<short8*>(&Vt[grp][vd0][kch*8])   = vr0;
        if (vl1) *reinterpret_cast<short8*>(&Vt[grp][vd1][kch*8]) = vr1;
        __syncthreads();                             // this tile's LDS ready
        if (tt < 18) {                               // issue next tile's loads -> regs
            const int nb0 = grp*1216 + (tt + 1)*64;
            if (kch < 6) {
                kr0 = *reinterpret_cast<const short8*>(kq + (size_t)(nb0 + krow0)*HID + kch*8);
                kr1 = *reinterpret_cast<const short8*>(kq + (size_t)(nb0 + krow1)*HID + kch*8);
            }
            vr0 = *reinterpret_cast<const short8*>(vq + (size_t)vd0*VLP + nb0 + kch*8);
            if (vl1) vr1 = *reinterpret_cast<const short8*>(vq + (size_t)vd1*VLP + nb0 + kch*8);
        }

        const int kt = sp*1216 + tt*64;              // compute key base for this wave
        float sv[16];
        #pragma unroll
        for (int t = 0; t < 4; ++t) {
            f32x4 acc = {0.f,0.f,0.f,0.f};
            short8 a0 = *reinterpret_cast<const short8*>(&Ks[sp][t*16 + c][quad*8]);
            short8 a1 = *reinterpret_cast<const short8*>(&Ks[sp][t*16 + c][32 + quad*8]);
            acc = __builtin_amdgcn_mfma_f32_16x16x32_bf16(a0, qf0, acc, 0, 0, 0);
            acc = __builtin_amdgcn_mfma_f32_16x16x32_bf16(a1, qf1, acc, 0, 0, 0);
            #pragma unroll
            for (int r = 0; r < 4; ++r) sv[t*4 + r] = acc[r];   // already log2-scaled
        }
        if (sp == 1 && tt >= 17) {                   // tiles with keys >= L_ (2304.. / 2368..)
            #pragma unroll
            for (int t = 0; t < 4; ++t)
                #pragma unroll
                for (int r = 0; r < 4; ++r)
                    if (kt + t*16 + quad*4 + r >= L_) sv[t*4 + r] = -3.0e38f;
        }
        // tree max (depth 4, max3-fusable)
        float tmax = fmaxf(fmaxf(fmaxf(sv[0], sv[1]),  fmaxf(sv[2],  sv[3])),
                           fmaxf(fmaxf(sv[4], sv[5]),  fmaxf(sv[6],  sv[7])));
        float tmx2 = fmaxf(fmaxf(fmaxf(sv[8], sv[9]),  fmaxf(sv[10], sv[11])),
                           fmaxf(fmaxf(sv[12], sv[13]), fmaxf(sv[14], sv[15])));
        tmax = fmaxf(tmax, tmx2);
        tmax = fmaxf(tmax, __shfl_xor(tmax, 16));
        tmax = fmaxf(tmax, __shfl_xor(tmax, 32));
        if (!__all(tmax <= m + 8.0f)) {              // defer-max: rescale only on growth
            const float mn = fmaxf(m, tmax);
            const float alpha = exp2f(m - mn);
            m = mn;
            lsum *= alpha;
            o0 *= alpha; o1 *= alpha; o2 *= alpha;
        }
        float psum = 0.f;
        unsigned short pv[16];
        #pragma unroll
        for (int i = 0; i < 16; ++i) {
            const float p = exp2f(sv[i] - m);        // bounded by 2^8
            psum += p;
            pv[i] = f2us(p);
        }
        lsum += psum;
        // P row (query c) -> LDS; same-wave rw, no barrier needed
        #pragma unroll
        for (int t = 0; t < 4; ++t)
            *reinterpret_cast<ushort4*>(&Pq[w][c][t*16 + quad*4]) =
                make_ushort4(pv[t*4+0], pv[t*4+1], pv[t*4+2], pv[t*4+3]);
        // PV in 2 steps of 32 keys (b128 fragments)
        #pragma unroll
        for (int s = 0; s < 2; ++s) {
            short8 pf  = *reinterpret_cast<const short8*>(&Pq[w][c][s*32 + quad*8]);
            short8 vf0 = *reinterpret_cast<const short8*>(&Vt[sp][c][s*32 + quad*8]);
            short8 vf1 = *reinterpret_cast<const short8*>(&Vt[sp][16 + c][s*32 + quad*8]);
            short8 vf2 = *reinterpret_cast<const short8*>(&Vt[sp][32 + c][s*32 + quad*8]);
            o0 = __builtin_amdgcn_mfma_f32_16x16x32_bf16(vf0, pf, o0, 0, 0, 0);
            o1 = __builtin_amdgcn_mfma_f32_16x16x32_bf16(vf1, pf, o1, 0, 0, 0);
            o2 = __builtin_amdgcn_mfma_f32_16x16x32_bf16(vf2, pf, o2, 0, 0, 0);
        }
    }
    // ---- reduce l across quads within wave
    float lw = lsum;
    lw += __shfl_xor(lw, 16);
    lw += __shfl_xor(lw, 32);
    // ---- split merge through LDS (reuse Ks: 20480 B >= 4*64*14*4 = 14336 B; Ks dead here)
    float* Mg = (float*)&Ks[0][0][0];
    __syncthreads();
    if (sp == 1) {
        float* dst = Mg + (size_t)(qt*64 + lane)*14;
        dst[0] = o0[0]; dst[1] = o0[1]; dst[2]  = o0[2]; dst[3]  = o0[3];
        dst[4] = o1[0]; dst[5] = o1[1]; dst[6]  = o1[2]; dst[7]  = o1[3];
        dst[8] = o2[0]; dst[9] = o2[1]; dst[10] = o2[2]; dst[11] = o2[3];
        dst[12] = m; dst[13] = lw;
    }
    __syncthreads();
    if (sp == 0 && qvalid) {
        const float* src = Mg + (size_t)(qt*64 + lane)*14;
        const float m2 = src[12], l2 = src[13];
        const float mm = fmaxf(m, m2);
        const float a1 = exp2f(m - mm), a2 = exp2f(m2 - mm);
        const float inv = 1.0f / (lw*a1 + l2*a2);
        unsigned short* orow = (unsigned short*)(ao + base + (size_t)(q0 + c)*HID);
        const f32x4 ot[3] = {o0, o1, o2};
        #pragma unroll
        for (int dt = 0; dt < 3; ++dt) {
            ushort4 w4;
            w4.x = f2us((ot[dt][0]*a1 + src[dt*4+0]*a2) * inv);
            w4.y = f2us((ot[dt][1]*a1 + src[dt*4+1]*a2) * inv);
            w4.z = f2us((ot[dt][2]*a1 + src[dt*4+2]*a2) * inv);
            w4.w = f2us((ot[dt][3]*a1 + src[dt*4+3]*a2) * inv);
            *reinterpret_cast<ushort4*>(orow + dt*16 + quad*4) = w4;
        }
    }
}

// ---------------------------------------------------------------- flash-decode attention
// Key-split ACROSS blocks, XCD-aware bijective remap (T1, round 10: FETCH 34->6.7MB
// confirmed), plus T5 s_setprio around the MFMA clusters (round 11): the kernel is
// latency-bound on its in-block serial chain (Mfma 14%, VALU 43%, HBM 3%); resident
// blocks sit at different tile phases, so raising a wave's priority during its MFMA
// cluster lets the CU scheduler favor matrix-feeding waves over softmax/staging VALU.
// gload_lds 2-phase double-buffer staging (rule #21 swizzle), raw v_exp_f32,
// truncation-packed bf16 P, max3-fusable reduce. K d-pad cols pre-zeroed.
__global__ __launch_bounds__(256) void k_attn_fd(
    const bf16* __restrict__ q, const bf16* __restrict__ k,
    const bf16* __restrict__ vt, bf16* __restrict__ pob, float* __restrict__ pml)
{
    __shared__ __align__(16) unsigned short Kz[2][4096];  // [buf][64 key x 64 d] swizzled
    __shared__ __align__(16) unsigned short Vz[2][3072];  // [buf][48 d x 64 key] swizzled
    __shared__ __align__(16) unsigned short Pq[4][16][72];
    const int tid  = threadIdx.x;
    const int w    = tid >> 6, lane = tid & 63;
    const int quad = lane >> 4, c = lane & 15;
    // XCD-aware decomposition of the 1184-block 1D grid
    const int bid  = blockIdx.x;
    const int wg   = (bid & 7)*148 + (bid >> 3);     // bijective: 148 blocks per XCD
    const int g    = wg / 37;                        // (bh,half) group 0..31
    const int qblk = wg - g*37;
    const int bh   = g >> 1;
    const int half = g & 1;
    const size_t base  = (size_t)(bh >> 3)*L_*HID + (size_t)(bh & 7)*HD;
    const size_t vbase = (size_t)bh*48*VLP;
    const int q0 = qblk*64 + w*16;
    const bool qvalid = q0 < L_;                     // wave-uniform
    const int qrow = qvalid ? (q0 + c) : c;

    short8 qf0, qf1;
    {
        const unsigned short* qp = (const unsigned short*)(q + base + (size_t)qrow*HID);
        qf0 = *reinterpret_cast<const short8*>(qp + quad*8);                 // d 0..31
        if (quad < 2) qf1 = *reinterpret_cast<const short8*>(qp + 32 + quad*8);  // d 32..47
        else          qf1 = short8{0,0,0,0,0,0,0,0};                         // d 48..63 pad
    }
    f32x4 o0 = {0.f,0.f,0.f,0.f}, o1 = {0.f,0.f,0.f,0.f}, o2 = {0.f,0.f,0.f,0.f};
    float m = -3.0e38f, lsum = 0.f;

    // staging geometry: per thread 2 K-slots + 1-2 V-slots, all linear (tid*16B) dests
    const int srow = tid >> 3;                       // 0..31
    const int sc   = (tid & 7) ^ (srow & 7);         // inverse-swizzled slot
    const int scol = sc << 3;                        // global col (elems)
    const bool kld = (sc < 6);                       // K cols 48..63 never loaded
    const int ldo  = tid * 8;                        // linear LDS dest (elems)
    const unsigned short* kq = (const unsigned short*)(k + base);
    const unsigned short* vq = (const unsigned short*)(vt + vbase);
    const int kbase = half*1216;

    #define STAGE_FD(buf, kb) do { \
        if (kld) { \
            GLOAD16(kq + (size_t)((kb) + srow)*HID + scol,      &Kz[buf][ldo]); \
            GLOAD16(kq + (size_t)((kb) + 32 + srow)*HID + scol, &Kz[buf][2048 + ldo]); \
        } \
        GLOAD16(vq + (size_t)srow*VLP + (kb) + scol, &Vz[buf][ldo]); \
        if (tid < 128) \
            GLOAD16(vq + (size_t)(32 + srow)*VLP + (kb) + scol, &Vz[buf][2048 + ldo]); \
    } while (0)

    {   // pre-zero K d-pad slots (cols 48..63) in both buffers — never loaded
        const short8 Z8 = short8{0,0,0,0,0,0,0,0};
        if (tid < 128) {
            const int r = tid >> 1, j = tid & 1;
            const int s = (6 + j) ^ (r & 7);
            *reinterpret_cast<short8*>(&Kz[0][r*64 + s*8]) = Z8;
            *reinterpret_cast<short8*>(&Kz[1][r*64 + s*8]) = Z8;
        }
    }
    STAGE_FD(0, kbase);
    __syncthreads();                                 // vmcnt drain + barrier
    int cur = 0;

    for (int tt = 0; tt < 19; ++tt) {
        if (tt < 18) STAGE_FD(cur ^ 1, kbase + (tt + 1)*64);   // async next-tile loads

        const int kt = kbase + tt*64;
        const char* kzb = (const char*)&Kz[cur][0];
        const char* vzb = (const char*)&Vz[cur][0];
        const int qx = quad << 4;                    // colbyte of this quad's 16B
        float sv[16];
        __builtin_amdgcn_s_setprio(1);               // T5: favor QK^T MFMA cluster
        #pragma unroll
        for (int t = 0; t < 4; ++t) {
            const int kr = t*16 + c;
            const int rx = kr*128;
            const int x0 = qx ^ ((kr & 7) << 4);
            f32x4 acc = {0.f,0.f,0.f,0.f};
            short8 a0 = *reinterpret_cast<const short8*>(kzb + rx + x0);
            short8 a1 = *reinterpret_cast<const short8*>(kzb + rx + (x0 ^ 64));
            acc = __builtin_amdgcn_mfma_f32_16x16x32_bf16(a0, qf0, acc, 0, 0, 0);
            acc = __builtin_amdgcn_mfma_f32_16x16x32_bf16(a1, qf1, acc, 0, 0, 0);
            #pragma unroll
            for (int r = 0; r < 4; ++r) sv[t*4 + r] = acc[r];   // already log2-scaled
        }
        __builtin_amdgcn_s_setprio(0);
        if (half == 1 && tt >= 17) {                 // keys >= L_ (2304.. / 2368..)
            #pragma unroll
            for (int t = 0; t < 4; ++t)
                #pragma unroll
                for (int r = 0; r < 4; ++r)
                    if (kt + t*16 + quad*4 + r >= L_) sv[t*4 + r] = -3.0e38f;
        }
        // tree max: two max3-fusable chains + combine
        float h0 = fmaxf(fmaxf(sv[0], sv[1]), sv[2]);
        h0 = fmaxf(fmaxf(h0, sv[3]), sv[4]);
        h0 = fmaxf(fmaxf(h0, sv[5]), sv[6]);
        h0 = fmaxf(h0, sv[7]);
        float h1 = fmaxf(fmaxf(sv[8], sv[9]), sv[10]);
        h1 = fmaxf(fmaxf(h1, sv[11]), sv[12]);
        h1 = fmaxf(fmaxf(h1, sv[13]), sv[14]);
        h1 = fmaxf(h1, sv[15]);
        float tmax = fmaxf(h0, h1);
        tmax = fmaxf(tmax, __shfl_xor(tmax, 16));
        tmax = fmaxf(tmax, __shfl_xor(tmax, 32));
        if (!__all(tmax <= m + 8.0f)) {              // defer-max
            const float mn = fmaxf(m, tmax);
            const float alpha = exp2_raw(m - mn);
            m = mn;
            lsum *= alpha;
            o0 *= alpha; o1 *= alpha; o2 *= alpha;
        }
        // P = exp2(S - m), truncation-packed to bf16 pairs
        float psum = 0.f;
        unsigned pk[8];
        #pragma unroll
        for (int i = 0; i < 8; ++i) {
            const float p0 = exp2_raw(sv[2*i]     - m);   // bounded by 2^8
            const float p1 = exp2_raw(sv[2*i + 1] - m);
            psum += p0 + p1;
            pk[i] = (__float_as_uint(p0) >> 16) | (__float_as_uint(p1) & 0xFFFF0000u);
        }
        lsum += psum;
        // P row (query c) -> LDS as b64 pairs; same-wave rw, no barrier needed
        #pragma unroll
        for (int t = 0; t < 4; ++t)
            *reinterpret_cast<uint2*>(&Pq[w][c][t*16 + quad*4]) =
                make_uint2(pk[2*t], pk[2*t + 1]);
        // PV in 2 steps of 32 keys (b128 fragments, swizzled V reads)
        const int mx = (c & 7) << 4;
        __builtin_amdgcn_s_setprio(1);               // T5: favor PV MFMA cluster
        #pragma unroll
        for (int s = 0; s < 2; ++s) {
            const int va = ((s << 6) | qx) ^ mx;
            short8 pf  = *reinterpret_cast<const short8*>(&Pq[w][c][s*32 + quad*8]);
            short8 vf0 = *reinterpret_cast<const short8*>(vzb + c*128 + va);
            short8 vf1 = *reinterpret_cast<const short8*>(vzb + (16 + c)*128 + va);
            short8 vf2 = *reinterpret_cast<const short8*>(vzb + (32 + c)*128 + va);
            o0 = __builtin_amdgcn_mfma_f32_16x16x32_bf16(vf0, pf, o0, 0, 0, 0);
            o1 = __builtin_amdgcn_mfma_f32_16x16x32_bf16(vf1, pf, o1, 0, 0, 0);
            o2 = __builtin_amdgcn_mfma_f32_16x16x32_bf16(vf2, pf, o2, 0, 0, 0);
        }
        __builtin_amdgcn_s_setprio(0);
        __syncthreads();                             // drains next-tile loads + read fence
        cur ^= 1;
    }
    #undef STAGE_FD
    // reduce l across quads, normalize, store partials
    float lw = lsum;
    lw += __shfl_xor(lw, 16);
    lw += __shfl_xor(lw, 32);
    const float invl = 1.0f / lw;
    const size_t ro = ((size_t)bh*2368 + q0 + c)*2 + half;
    unsigned short* pr = (unsigned short*)pob + ro*48;
    const f32x4 ot[3] = {o0, o1, o2};
    #pragma unroll
    for (int dt = 0; dt < 3; ++dt) {
        ushort4 w4;
        w4.x = f2us(ot[dt][0]*invl);
        w4.y = f2us(ot[dt][1]*invl);
        w4.z = f2us(ot[dt][2]*invl);
        w4.w = f2us(ot[dt][3]*invl);
        *reinterpret_cast<ushort4*>(pr + dt*16 + quad*4) = w4;
    }
    if (quad == 0) { pml[ro*2 + 0] = m; pml[ro*2 + 1] = lw; }
}

// merge the two key-halves: out = (o1*l1*a1 + o2*l2*a2) / (l1*a1 + l2*a2)
__global__ __launch_bounds__(256) void k_amerge(
    const bf16* __restrict__ pob, const float* __restrict__ pml, bf16* __restrict__ ao)
{
    const int tid = threadIdx.x;
    const int bh = blockIdx.y;
    const int qq = blockIdx.x*16 + (tid >> 4);       // 0..2351
    const int j = tid & 15;
    const size_t ro = ((size_t)bh*2368 + qq)*2;
    const float m1 = pml[ro*2 + 0], l1 = pml[ro*2 + 1];
    const float m2 = pml[ro*2 + 2], l2 = pml[ro*2 + 3];
    const float mm = fmaxf(m1, m2);
    const float b1 = exp2f(m1 - mm)*l1, b2 = exp2f(m2 - mm)*l2;
    const float inv = 1.0f / (b1 + b2);
    const float w1 = b1*inv, w2 = b2*inv;
    if (j < 12) {
        const unsigned short* p1 = (const unsigned short*)pob + ro*48 + j*4;
        ushort4 u1 = *reinterpret_cast<const ushort4*>(p1);
        ushort4 u2 = *reinterpret_cast<const ushort4*>(p1 + 48);
        ushort4 o4;
        o4.x = f2us(us2f(u1.x)*w1 + us2f(u2.x)*w2);
        o4.y = f2us(us2f(u1.y)*w1 + us2f(u2.y)*w2);
        o4.z = f2us(us2f(u1.z)*w1 + us2f(u2.z)*w2);
        o4.w = f2us(us2f(u1.w)*w1 + us2f(u2.w)*w2);
        const size_t base = (size_t)(bh >> 3)*L_*HID + (size_t)(bh & 7)*HD;
        *reinterpret_cast<ushort4*>((unsigned short*)ao + base + (size_t)qq*HID + j*4) = o4;
    }
}

// ------------------------------------------------------- final LN + heads
template <typename T, typename TO>
static __device__ void final_body(
    const float* h, const T* fn_g, const T* fn_b,
    const T* on_w, const T* on_b, const T* oe_w, const T* oe_b, TO* out)
{
    __shared__ float hf[HID];
    const int row = blockIdx.x;
    const int b = row / L_, l = row % L_;
    const int lane = threadIdx.x;
    const float* hr = h + (size_t)row*HID;
    float v[6]; float s = 0.f, ss = 0.f;
    #pragma unroll
    for (int j = 0; j < 6; ++j) { float t = hr[lane + j*64]; v[j] = t; s += t; ss += t*t; }
    #pragma unroll
    for (int off = 32; off; off >>= 1) { s += __shfl_xor(s, off); ss += __shfl_xor(ss, off); }
    const float mu = s * (1.0f/HID);
    const float rs = rsqrtf(fmaxf(ss * (1.0f/HID) - mu*mu, 0.0f) + 1e-5f);
    #pragma unroll
    for (int j = 0; j < 6; ++j) {
        int c = lane + j*64;
        hf[c] = (v[j] - mu) * rs * ldv(fn_g, c) + ldv(fn_b, c);
    }
    __syncthreads();
    if (l < N_) {
        if (lane < A_) {
            float acc = ldv(on_b, lane);
            for (int c = 0; c < HID; ++c) acc += hf[c] * ldv(on_w, (size_t)c*A_ + lane);
            stv(out, (size_t)(b*N_ + l)*A_ + lane, acc);
        }
    } else {
        const int e = l - N_;
        if (lane < E_) {
            float acc = ldv(oe_b, lane);
            for (int c = 0; c < HID; ++c) acc += hf[c] * ldv(oe_w, (size_t)c*E_ + lane);
            stv(out, (size_t)B_*N_*A_ + ((size_t)b*N_*N_ + e)*E_ + lane, acc);
        }
    }
}

__global__ __launch_bounds__(64) void k_final(
    const float* __restrict__ h, const void* fn_g, const void* fn_b,
    const void* on_w, const void* on_b, const void* oe_w, const void* oe_b,
    const int* __restrict__ fl, void* out)
{
    if (*fl) final_body<float, float>(h, (const float*)fn_g, (const float*)fn_b,
                                      (const float*)on_w, (const float*)on_b,
                                      (const float*)oe_w, (const float*)oe_b, (float*)out);
    else     final_body<bf16, bf16>(h, (const bf16*)fn_g, (const bf16*)fn_b,
                                    (const bf16*)on_w, (const bf16*)on_b,
                                    (const bf16*)oe_w, (const bf16*)oe_b, (bf16*)out);
}

// ---------------------------------------------------------------- launch
extern "C" void kernel_launch(void* const* d_in, const int* in_sizes, int n_in,
                              void* d_out, int out_size, void* d_ws, size_t ws_size,
                              hipStream_t stream) {
    const void* x      = d_in[0];
    const void* adj    = d_in[1];
    const void* t      = d_in[2];
    const void* node_w = d_in[3];
    const void* node_b = d_in[4];
    const void* edge_w = d_in[5];
    const void* edge_b = d_in[6];
    const void* pos    = d_in[7];
    const void* t_w1   = d_in[8];
    const void* t_b1   = d_in[9];
    const void* t_w2   = d_in[10];
    const void* t_b2   = d_in[11];
    const void* ada1_w = d_in[12];
    const void* ada1_b = d_in[13];
    const void* ada2_w = d_in[14];
    const void* ada2_b = d_in[15];
    const void* q_w    = d_in[16];
    const void* q_b    = d_in[17];
    const void* k_w    = d_in[18];
    const void* k_b    = d_in[19];
    const void* v_w    = d_in[20];
    const void* v_b    = d_in[21];
    const void* o_w    = d_in[22];
    const void* o_b    = d_in[23];
    const void* m1_w   = d_in[24];
    const void* m1_b   = d_in[25];
    const void* m2_w   = d_in[26];
    const void* m2_b   = d_in[27];
    const void* fn_g   = d_in[28];
    const void* fn_b   = d_in[29];
    const void* on_w   = d_in[30];
    const void* on_b   = d_in[31];
    const void* oe_w   = d_in[32];
    const void* oe_b   = d_in[33];

    const size_t SZ  = (size_t)M_ * HID;          // 1,806,336 elements
    const size_t VTZ = (size_t)B_*NHD*HD*VLP;     // 1,867,776 elements (padded V^T)
    const size_t FLT = SZ + 12288 + (size_t)B_*4*HID + (size_t)B_*12*HID;  // 1,830,912
    const size_t M1FULL = (size_t)M_ * MLPD;      // 7,225,344
    const size_t BF_BASE = 3*SZ + VTZ;            // nb..vtb end = 7,286,784
    const size_t BF_BIG  = SZ + M1FULL;           // nb + m1f(from qb) end = 9,031,680
    const size_t NEED      = 256 + sizeof(float)*FLT + sizeof(bf16)*BF_BASE;   // ~21.9 MB
    const size_t NEED_BIG  = 256 + sizeof(float)*FLT + sizeof(bf16)*BF_BIG;    // ~25.4 MB
    const size_t NEED_PREP = 256 + sizeof(float)*FLT
                           + sizeof(bf16)*(BF_BIG + WTOT + BTOT);              // ~39.6 MB
    const size_t NEED_FD   = NEED_PREP + sizeof(bf16)*PO_E + sizeof(float)*PML_E; // ~47.5 MB
    if (ws_size < NEED) {
        hipMemsetAsync(d_out, 0, (size_t)out_size*sizeof(bf16), stream);  // 1.14 signature
        return;
    }
    const bool big  = (ws_size >= NEED_BIG);
    const bool prep = (ws_size >= NEED_PREP);
    const bool fd   = (ws_size >= NEED_FD);
    int*   fl   = (int*)d_ws;
    float* h    = (float*)((char*)d_ws + 256);
    float* ada  = h + SZ;                  // [8][B_][768]
    float* hid  = ada + 12288;             // [B_][1536]
    float* part = hid + (size_t)B_*4*HID;  // [B_][12][384] cond partials
    bf16* nb  = (bf16*)(part + (size_t)B_*12*HID);
    bf16* qb  = nb + SZ;
    bf16* kb  = qb + SZ;
    bf16* vtb = kb + SZ;                   // transposed V, [bh*48+d][VLP]
    bf16* m1c = kb;                        // chunked m1: [2352,1536] spans kb+vtb
    bf16* m1f = qb;                        // full m1: [M_,1536] spans qb..vtb+tail
    bf16* wbt = nb + BF_BIG;               // prepped weights (bf16, [n][k])
    bf16* bb  = wbt + WTOT;                // prepped biases
    bf16* pob = bb + BTOT;                 // flash-decode partial o (normalized)
    float* pml = (float*)(pob + PO_E);     // flash-decode partial (m, l)

    k_detect<<<1, 64, 0, stream>>>(node_w, fl);
    if (prep) {
        k_prepw<<<dim3(144, 24), 256, 0, stream>>>(q_w, k_w, v_w, o_w, m1_w, m2_w, fl, wbt);
        k_prepb<<<1, 256, 0, stream>>>(q_b, k_b, v_b, o_b, m1_b, m2_b, fl, bb);
    }
    k_embed<<<M_, HID, 0, stream>>>(x, adj, node_w, node_b, edge_w, edge_b, pos, fl, h);
    k_cond1<<<dim3(B_, 24), 256, 0, stream>>>(t, t_w1, t_b1, fl, hid);
    k_cond2<<<dim3(B_, 12), 384, 0, stream>>>(t_w2, t_b2, fl, hid, part);
    k_cond3<<<dim3(24, B_), 256, 0, stream>>>(ada1_w, ada1_b, ada2_w, ada2_b, fl, part, ada);
    for (int i = 0; i < LYR; ++i) {
        const long long woff   = (long long)i * HID * HID;
        const long long boff   = (long long)i * HID;
        const long long m1woff = (long long)i * HID * MLPD;
        const long long m1boff = (long long)i * MLPD;
        const long long m2woff = (long long)i * MLPD * HID;

        k_adaln<<<M_/4, 256, 0, stream>>>(h, ada, nb, 2*i);
        if (prep) {
            k_gemm_qkv_t<<<dim3(74, 6, 3), 256, 0, stream>>>(nb, wbt, bb, i, qb, kb, vtb);
            if (fd) {
                k_attn_fd<<<1184, 256, 0, stream>>>(qb, kb, vtb, pob, pml);
                k_amerge<<<dim3(147, 16), 256, 0, stream>>>(pob, pml, nb);   // ao -> nb
            } else {
                k_attn<<<dim3(37, B_*NHD), 512, 0, stream>>>(qb, kb, vtb, nb);
            }
            k_gemm_t32<<<dim3(147, 6), 256, 0, stream>>>(nb, wbt, WO_ + (long long)i*147456,
                                                         bb, BO_ + i*384,
                                                         h, M_, HID, HID);
            k_adaln<<<M_/4, 256, 0, stream>>>(h, ada, nb, 2*i + 1);          // n2 -> nb
            k_gemm_t<<<dim3(74, 24), 256, 0, stream>>>(nb, wbt, WM1_ + (long long)i*589824,
                                                       bb, BM1_ + i*MLPD,
                                                       m1f, nullptr, M_, MLPD, HID, 1, 0);
            k_gemm_t32<<<dim3(147, 6), 256, 0, stream>>>(m1f, wbt, WM2_ + (long long)i*589824,
                                                         bb, BM2_ + i*384,
                                                         h, M_, HID, MLPD);
        } else {
            k_gemm_qkv<<<dim3(74, 6, 3), 256, 0, stream>>>(nb, q_w, k_w, v_w, q_b, k_b, v_b,
                                                           woff, boff, qb, kb, vtb, fl);
            k_attn<<<dim3(37, B_*NHD), 512, 0, stream>>>(qb, kb, vtb, nb);   // ao -> nb
            k_gemm<<<dim3(74, 6), 256, 0, stream>>>(nb, o_w, woff, o_b, boff,
                                                    nullptr, h, M_, HID, HID, 0, 1, fl);
            k_adaln<<<M_/4, 256, 0, stream>>>(h, ada, nb, 2*i + 1);          // n2 -> nb
            if (big) {
                k_gemm<<<dim3(74, 24), 256, 0, stream>>>(nb, m1_w, m1woff, m1_b, m1boff,
                                                         m1f, nullptr, M_, MLPD, HID, 1, 0, fl);
                k_gemm<<<dim3(74, 6), 256, 0, stream>>>(m1f, m2_w, m2woff, m2_b, boff,
                                                        nullptr, h, M_, HID, MLPD, 0, 1, fl);
            } else {
                for (int c = 0; c < 2; ++c) {
                    k_gemm<<<dim3(37, 24), 256, 0, stream>>>(nb + (size_t)c*2352*HID,
                                                             m1_w, m1woff, m1_b, m1boff,
                                                             m1c, nullptr, 2352, MLPD, HID, 1, 0, fl);
                    k_gemm<<<dim3(37, 6), 256, 0, stream>>>(m1c, m2_w, m2woff, m2_b, boff,
                                                            nullptr, h + (size_t)c*2352*HID,
                                                            2352, HID, MLPD, 0, 1, fl);
                }
            }
        }
    }
    k_final<<<M_, 64, 0, stream>>>(h, fn_g, fn_b, on_w, on_b, oe_w, oe_b, fl, (void*)d_out);
}

// Round 12
// 752.701 us; speedup vs baseline: 1.0208x; 1.0208x over previous
//
#include <hip/hip_runtime.h>
#include <hip/hip_bf16.h>
#include <math.h>

typedef __hip_bfloat16 bf16;
typedef __attribute__((ext_vector_type(8))) short short8;   // 8 bf16 in 4 VGPRs
typedef __attribute__((ext_vector_type(4))) float f32x4;

#define B_ 2
#define N_ 48
#define A_ 16
#define E_ 5
#define HID 384
#define NHD 8
#define HD 48
#define LYR 4
#define MLPD 1536
#define L_ 2352      // N_ + N_*N_
#define M_ 4704      // B_*L_
#define VLP 2432     // padded key stride of transposed-V buffer
// 1/sqrt(48) * log2(e): Q pre-scale so softmax runs in log2 domain (exp2f)
#define QSCALE 0.20823513f

// prepped-weight element offsets (bf16, transposed [n][k] per matrix)
#define WQ_  0LL
#define WK_  589824LL
#define WV_  1179648LL
#define WO_  1769472LL
#define WM1_ 2359296LL
#define WM2_ 4718592LL
#define WTOT 7077888
// prepped-bias offsets
#define BQ_  0
#define BK_  1536
#define BV_  3072
#define BO_  4608
#define BM1_ 6144
#define BM2_ 12288
#define BTOT 13824

// flash-decode partials: [16 bh][2368 q][2 half] — o normalized (48 bf16) + (m,l) f32
#define PO_E  ((size_t)16*2368*2*48)   // bf16 elems
#define PML_E ((size_t)16*2368*2*2)    // f32 elems

// async global->LDS 16B direct copy (gfx950); LDS dest must be linear per-lane
#define GLOAD16(gp, lp) __builtin_amdgcn_global_load_lds( \
    (const __attribute__((address_space(1))) unsigned int*)(gp), \
    (__attribute__((address_space(3))) unsigned int*)(lp), 16, 0, 0)

static __device__ __forceinline__ float b2f(bf16 v) { return __bfloat162float(v); }
static __device__ __forceinline__ float us2f(unsigned short u) {
    return __uint_as_float(((unsigned)u) << 16);
}
static __device__ __forceinline__ unsigned short f2us(float f) {
    bf16 h = __float2bfloat16(f);
    return *reinterpret_cast<unsigned short*>(&h);
}
// raw v_exp_f32: 1 inst vs libm exp2f's denorm-fixup sequence; inputs <= 0,
// HW flush-to-zero on underflow is exactly softmax semantics.
static __device__ __forceinline__ float exp2_raw(float x) {
    float r;
    asm("v_exp_f32 %0, %1" : "=v"(r) : "v"(x));
    return r;
}
static __device__ __forceinline__ float ldv(const float* p, size_t i) { return p[i]; }
static __device__ __forceinline__ float ldv(const bf16*  p, size_t i) { return b2f(p[i]); }
static __device__ __forceinline__ void  stv(float* p, size_t i, float v) { p[i] = v; }
static __device__ __forceinline__ void  stv(bf16*  p, size_t i, float v) { p[i] = __float2bfloat16(v); }
static __device__ __forceinline__ float4 ld4(const float* p, size_t i) {
    return *reinterpret_cast<const float4*>(p + i);
}
static __device__ __forceinline__ float4 ld4(const bf16* p, size_t i) {
    ushort4 u = *reinterpret_cast<const ushort4*>(p + i);
    return make_float4(us2f(u.x), us2f(u.y), us2f(u.z), us2f(u.w));
}

// ------------------------------------------------ dtype detect (flag: 1=fp32, 0=bf16)
__global__ void k_detect(const void* w, int* flag) {
    if (threadIdx.x == 0 && blockIdx.x == 0) {
        const bf16* p = (const bf16*)w;   // node_w: 6144 elems of 0.02*normal
        int isf = 0;
        for (int i = 0; i < 256; ++i) {
            float v = fabsf(b2f(p[i]));
            if (!(v <= 1000.0f)) { isf = 1; break; }
        }
        *flag = isf;
    }
}

// ------------------------------------- weight prep: convert + transpose to [n][k] bf16
template <typename T>
static __device__ void prepw_body(
    const T* q_w, const T* k_w, const T* v_w, const T* o_w,
    const T* m1_w, const T* m2_w, bf16* wbt)
{
    __shared__ unsigned short Ts[64][72];
    const int z = blockIdx.y;
    const int kind = z >> 2, l = z & 3;
    const T* src; int K, N; long long dbase;
    switch (kind) {
        case 0: src = q_w;  K = 384;  N = 384;  dbase = WQ_;  break;
        case 1: src = k_w;  K = 384;  N = 384;  dbase = WK_;  break;
        case 2: src = v_w;  K = 384;  N = 384;  dbase = WV_;  break;
        case 3: src = o_w;  K = 384;  N = 384;  dbase = WO_;  break;
        case 4: src = m1_w; K = 384;  N = 1536; dbase = WM1_; break;
        default: src = m2_w; K = 1536; N = 384; dbase = WM2_; break;
    }
    const int Nt = N >> 6;
    const int tiles = (K >> 6) * Nt;
    if (blockIdx.x >= tiles) return;
    const int tk = blockIdx.x / Nt, tn = blockIdx.x % Nt;
    const int k0 = tk*64, n0 = tn*64;
    const size_t soff = (size_t)l * K * N;
    const size_t doff = (size_t)dbase + (size_t)l * K * N;
    const int tid = threadIdx.x;
    {   // load 64x64 fp tile -> bf16 LDS
        const int kk = tid >> 2, nc = (tid & 3) * 16;
        #pragma unroll
        for (int j = 0; j < 16; ++j)
            Ts[kk][nc + j] = f2us(ldv(src, soff + (size_t)(k0 + kk)*N + n0 + nc + j));
    }
    __syncthreads();
    {   // store transposed [n][k] with b128 writes
        const int nn = tid >> 2, kc = (tid & 3) * 16;
        unsigned short tmp[16];
        #pragma unroll
        for (int j = 0; j < 16; ++j) tmp[j] = Ts[kc + j][nn];
        unsigned short* dst = (unsigned short*)wbt + doff + (size_t)(n0 + nn)*K + k0 + kc;
        *reinterpret_cast<short8*>(dst)     = *reinterpret_cast<short8*>(&tmp[0]);
        *reinterpret_cast<short8*>(dst + 8) = *reinterpret_cast<short8*>(&tmp[8]);
    }
}

__global__ __launch_bounds__(256) void k_prepw(
    const void* q_w, const void* k_w, const void* v_w, const void* o_w,
    const void* m1_w, const void* m2_w, const int* __restrict__ fl, bf16* __restrict__ wbt)
{
    if (*fl) prepw_body<float>((const float*)q_w, (const float*)k_w, (const float*)v_w,
                               (const float*)o_w, (const float*)m1_w, (const float*)m2_w, wbt);
    else     prepw_body<bf16>((const bf16*)q_w, (const bf16*)k_w, (const bf16*)v_w,
                              (const bf16*)o_w, (const bf16*)m1_w, (const bf16*)m2_w, wbt);
}

template <typename T>
static __device__ void prepb_body(
    const T* q_b, const T* k_b, const T* v_b, const T* o_b,
    const T* m1_b, const T* m2_b, bf16* bb)
{
    for (int i = threadIdx.x; i < BTOT; i += 256) {
        float v;
        if      (i < BK_)  v = ldv(q_b,  i);
        else if (i < BV_)  v = ldv(k_b,  i - BK_);
        else if (i < BO_)  v = ldv(v_b,  i - BV_);
        else if (i < BM1_) v = ldv(o_b,  i - BO_);
        else if (i < BM2_) v = ldv(m1_b, i - BM1_);
        else               v = ldv(m2_b, i - BM2_);
        bb[i] = __float2bfloat16(v);
    }
}

__global__ __launch_bounds__(256) void k_prepb(
    const void* q_b, const void* k_b, const void* v_b, const void* o_b,
    const void* m1_b, const void* m2_b, const int* __restrict__ fl, bf16* __restrict__ bb)
{
    if (*fl) prepb_body<float>((const float*)q_b, (const float*)k_b, (const float*)v_b,
                               (const float*)o_b, (const float*)m1_b, (const float*)m2_b, bb);
    else     prepb_body<bf16>((const bf16*)q_b, (const bf16*)k_b, (const bf16*)v_b,
                              (const bf16*)o_b, (const bf16*)m1_b, (const bf16*)m2_b, bb);
}

// ---------------------------------------------------------------- embed (-> f32 h)
template <typename T>
static __device__ void embed_body(
    const T* x, const T* adj, const T* node_w, const T* node_b,
    const T* edge_w, const T* edge_b, const T* pos, float* h)
{
    const int bl = blockIdx.x;
    const int b = bl / L_, l = bl % L_;
    const int c = threadIdx.x;          // 0..383
    float acc;
    if (l < N_) {
        acc = ldv(node_b, c);
        const size_t xr = (size_t)(b*N_ + l)*A_;
        #pragma unroll
        for (int a = 0; a < A_; ++a) acc += ldv(x, xr + a) * ldv(node_w, (size_t)a*HID + c);
    } else {
        const int e = l - N_;
        acc = ldv(edge_b, c);
        const size_t ar = ((size_t)b*N_*N_ + e)*E_;
        #pragma unroll
        for (int j = 0; j < E_; ++j) acc += ldv(adj, ar + j) * ldv(edge_w, (size_t)j*HID + c);
    }
    h[(size_t)bl*HID + c] = acc + ldv(pos, (size_t)l*HID + c);
}

__global__ __launch_bounds__(384) void k_embed(
    const void* x, const void* adj, const void* node_w, const void* node_b,
    const void* edge_w, const void* edge_b, const void* pos,
    const int* __restrict__ fl, float* __restrict__ h)
{
    if (*fl) embed_body<float>((const float*)x, (const float*)adj, (const float*)node_w,
                               (const float*)node_b, (const float*)edge_w, (const float*)edge_b,
                               (const float*)pos, h);
    else     embed_body<bf16>((const bf16*)x, (const bf16*)adj, (const bf16*)node_w,
                              (const bf16*)node_b, (const bf16*)edge_w, (const bf16*)edge_b,
                              (const bf16*)pos, h);
}

// ---------------------------------------- cond stage 1: temb -> hidden (SiLU)
template <typename T>
static __device__ void cond1_body(const T* t, const T* t_w1, const T* t_b1, float* hid)
{
    __shared__ float temb[HID];
    __shared__ float red[4][64];
    const int b = blockIdx.x, jb = blockIdx.y, tid = threadIdx.x;
    const float tv = ldv(t, b);
    for (int c = tid; c < HID; c += 256) {
        int i = (c < 192) ? c : c - 192;
        float f = expf(-9.2103403719761836f * (float)i / 192.0f);
        float ang = tv * f;
        temb[c] = (c < 192) ? sinf(ang) : cosf(ang);
    }
    __syncthreads();
    const int ko = tid >> 6, jo = tid & 63;
    const int j = jb*64 + jo;
    float acc = 0.f;
    for (int i = ko*96; i < (ko + 1)*96; ++i)
        acc += temb[i] * ldv(t_w1, (size_t)i*4*HID + j);
    red[ko][jo] = acc;
    __syncthreads();
    if (ko == 0) {
        float a = red[0][jo] + red[1][jo] + red[2][jo] + red[3][jo] + ldv(t_b1, j);
        hid[(size_t)b*4*HID + j] = a / (1.0f + expf(-a));   // SiLU
    }
}

__global__ __launch_bounds__(256) void k_cond1(
    const void* t, const void* t_w1, const void* t_b1,
    const int* __restrict__ fl, float* __restrict__ hid)
{
    if (*fl) cond1_body<float>((const float*)t, (const float*)t_w1, (const float*)t_b1, hid);
    else     cond1_body<bf16>((const bf16*)t, (const bf16*)t_w1, (const bf16*)t_b1, hid);
}

// ---------------------------------------- cond stage 2: hidden -> partial cond sums
template <typename T>
static __device__ void cond2_body(const T* t_w2, const T* t_b2, const float* hid, float* part)
{
    __shared__ float hs[128];
    const int b = blockIdx.x, ch = blockIdx.y, c = threadIdx.x;
    const int j0 = ch*128;
    if (c < 128) hs[c] = hid[(size_t)b*4*HID + j0 + c];
    __syncthreads();
    float acc = (ch == 0) ? ldv(t_b2, c) : 0.f;
    for (int jj = 0; jj < 128; ++jj)
        acc += hs[jj] * ldv(t_w2, (size_t)(j0 + jj)*HID + c);
    part[((size_t)b*12 + ch)*HID + c] = acc;
}

__global__ __launch_bounds__(384) void k_cond2(
    const void* t_w2, const void* t_b2, const int* __restrict__ fl,
    const float* __restrict__ hid, float* __restrict__ part)
{
    if (*fl) cond2_body<float>((const float*)t_w2, (const float*)t_b2, hid, part);
    else     cond2_body<bf16>((const bf16*)t_w2, (const bf16*)t_b2, hid, part);
}

// ---------------------------------------- cond stage 3: ada projections
template <typename T>
static __device__ void cond3_body(
    const T* ada1_w, const T* ada1_b, const T* ada2_w, const T* ada2_b,
    const float* part, float* ada_out)
{
    __shared__ float cs[HID];
    const int slot = blockIdx.x / 3, ob = blockIdx.x % 3, b = blockIdx.y;
    const int tid = threadIdx.x;
    for (int c = tid; c < HID; c += 256) {
        float s = 0.f;
        #pragma unroll
        for (int ch = 0; ch < 12; ++ch) s += part[((size_t)b*12 + ch)*HID + c];
        cs[c] = s;
    }
    __syncthreads();
    const int layer = slot >> 1, which = slot & 1;
    const int o = ob*256 + tid;
    const T* W  = which ? ada2_w : ada1_w;
    const T* Bi = which ? ada2_b : ada1_b;
    float acc = ldv(Bi, (size_t)layer*768 + o);
    const size_t wb = (size_t)layer*HID*768 + o;
    for (int c = 0; c < HID; ++c) acc += cs[c] * ldv(W, wb + (size_t)c*768);
    ada_out[((size_t)slot*B_ + b)*768 + o] = acc;
}

__global__ __launch_bounds__(256) void k_cond3(
    const void* ada1_w, const void* ada1_b, const void* ada2_w, const void* ada2_b,
    const int* __restrict__ fl, const float* __restrict__ part, float* __restrict__ ada_out)
{
    if (*fl) cond3_body<float>((const float*)ada1_w, (const float*)ada1_b,
                               (const float*)ada2_w, (const float*)ada2_b, part, ada_out);
    else     cond3_body<bf16>((const bf16*)ada1_w, (const bf16*)ada1_b,
                              (const bf16*)ada2_w, (const bf16*)ada2_b, part, ada_out);
}

// ---------------------------------------------------------------- adaLN (f32 h -> bf16 n)
__global__ __launch_bounds__(256) void k_adaln(
    const float* __restrict__ h, const float* __restrict__ ada,
    bf16* __restrict__ n, int slot)
{
    const int row  = blockIdx.x * 4 + (threadIdx.x >> 6);
    const int lane = threadIdx.x & 63;
    const int b = row / L_;
    const float* hr = h + (size_t)row*HID;
    float v[6]; float s = 0.f, ss = 0.f;
    #pragma unroll
    for (int j = 0; j < 6; ++j) { float t = hr[lane + j*64]; v[j] = t; s += t; ss += t*t; }
    #pragma unroll
    for (int off = 32; off; off >>= 1) { s += __shfl_xor(s, off); ss += __shfl_xor(ss, off); }
    const float mu = s * (1.0f/HID);
    const float rs = rsqrtf(fmaxf(ss * (1.0f/HID) - mu*mu, 0.0f) + 1e-5f);
    const float* ap = ada + ((size_t)slot*B_ + b)*768;
    bf16* nr = n + (size_t)row*HID;
    #pragma unroll
    for (int j = 0; j < 6; ++j) {
        int c = lane + j*64;
        nr[c] = __float2bfloat16((v[j] - mu)*rs*(1.0f + ap[c]) + ap[384 + c]);
    }
}

// ------------------------------------------------- MFMA GEMM epilogue (shared)
// mode: 0=bf16 store, 1=f32 +=, 2=V^T bf16 scatter, 3=bf16 store*QSCALE
static __device__ __forceinline__ void gemm_epilogue(
    f32x4 (&acc)[2][2], float bcol0, float bcol1,
    bf16* Cb, float* Cf, int M, int N, int act, int mode,
    int bm, int bn, int wm, int wn, int quad, int c)
{
    const float bcol[2] = {bcol0, bcol1};
    #pragma unroll
    for (int mi = 0; mi < 2; ++mi)
        #pragma unroll
        for (int ni = 0; ni < 2; ++ni) {
            const int col = bn + wn*32 + ni*16 + c;
            #pragma unroll
            for (int r = 0; r < 4; ++r) {
                const int row = bm + wm*32 + mi*16 + quad*4 + r;
                if (row < M) {
                    float v = acc[mi][ni][r] + bcol[ni];
                    if (act) v = 0.5f * v * (1.0f + erff(v * 0.70710678118654752f));  // GELU
                    if (mode == 1) Cf[(size_t)row*N + col] += v;
                    else if (mode == 0) Cb[(size_t)row*N + col] = __float2bfloat16(v);
                    else if (mode == 3) Cb[(size_t)row*N + col] = __float2bfloat16(v * QSCALE);
                    else {
                        const int b   = row >= L_ ? 1 : 0;
                        const int key = row - b*L_;
                        const int hh  = col / 48, d = col - hh*48;
                        Cb[((size_t)(b*8 + hh)*48 + d)*VLP + key] = __float2bfloat16(v);
                    }
                }
            }
        }
}

// -------- legacy GEMM: W fp32/bf16 [k][n], converted+transposed during staging
template <typename T>
static __device__ void gemm_body(
    const bf16* A, const T* W, long long woff, const T* bias, long long boff,
    bf16* Cb, float* Cf, int M, int N, int K, int act, int mode)
{
    __shared__ __align__(16) unsigned short As[64][72];
    __shared__ __align__(16) unsigned short Bt[64][72];
    const int tid  = threadIdx.x;
    const int wv   = tid >> 6, lane = tid & 63;
    const int quad = lane >> 4, c = lane & 15;
    const int wm = wv & 1, wn = wv >> 1;
    const int bm = blockIdx.x * 64, bn = blockIdx.y * 64;
    const int arow = tid >> 3, ach = tid & 7;
    f32x4 acc[2][2] = {{{0.f,0.f,0.f,0.f},{0.f,0.f,0.f,0.f}},
                       {{0.f,0.f,0.f,0.f},{0.f,0.f,0.f,0.f}}};
    for (int k0 = 0; k0 < K; k0 += 64) {
        short8 av[2]; float4 w0[2], w1[2];
        #pragma unroll
        for (int i = 0; i < 2; ++i) {
            const int row = i*32 + arow;
            av[i] = short8{0,0,0,0,0,0,0,0};
            if (bm + row < M)
                av[i] = *reinterpret_cast<const short8*>(
                            A + (size_t)(bm + row)*K + k0 + ach*8);
            const size_t wrow = (size_t)woff + (size_t)(k0 + i*32 + arow)*N + bn + ach*8;
            w0[i] = ld4(W, wrow);
            w1[i] = ld4(W, wrow + 4);
        }
        __syncthreads();
        #pragma unroll
        for (int i = 0; i < 2; ++i) {
            *reinterpret_cast<short8*>(&As[i*32 + arow][ach*8]) = av[i];
            const int kk = i*32 + arow, nb0 = ach*8;
            Bt[nb0+0][kk] = f2us(w0[i].x); Bt[nb0+1][kk] = f2us(w0[i].y);
            Bt[nb0+2][kk] = f2us(w0[i].z); Bt[nb0+3][kk] = f2us(w0[i].w);
            Bt[nb0+4][kk] = f2us(w1[i].x); Bt[nb0+5][kk] = f2us(w1[i].y);
            Bt[nb0+6][kk] = f2us(w1[i].z); Bt[nb0+7][kk] = f2us(w1[i].w);
        }
        __syncthreads();
        #pragma unroll
        for (int ks = 0; ks < 2; ++ks) {
            short8 af[2], bfr[2];
            #pragma unroll
            for (int mi = 0; mi < 2; ++mi)
                af[mi] = *reinterpret_cast<const short8*>(
                             &As[wm*32 + mi*16 + c][ks*32 + quad*8]);
            #pragma unroll
            for (int ni = 0; ni < 2; ++ni)
                bfr[ni] = *reinterpret_cast<const short8*>(
                              &Bt[wn*32 + ni*16 + c][ks*32 + quad*8]);
            #pragma unroll
            for (int mi = 0; mi < 2; ++mi)
                #pragma unroll
                for (int ni = 0; ni < 2; ++ni)
                    acc[mi][ni] = __builtin_amdgcn_mfma_f32_16x16x32_bf16(
                                      af[mi], bfr[ni], acc[mi][ni], 0, 0, 0);
        }
    }
    gemm_epilogue(acc, ldv(bias, (size_t)boff + bn + wn*32 + c),
                  ldv(bias, (size_t)boff + bn + wn*32 + 16 + c),
                  Cb, Cf, M, N, act, mode, bm, bn, wm, wn, quad, c);
}

__global__ __launch_bounds__(256) void k_gemm(
    const bf16* __restrict__ A, const void* W, long long woff, const void* bias, long long boff,
    bf16* Cb, float* Cf, int M, int N, int K, int act, int mode,
    const int* __restrict__ fl)
{
    if (*fl) gemm_body<float>(A, (const float*)W, woff, (const float*)bias, boff,
                              Cb, Cf, M, N, K, act, mode);
    else     gemm_body<bf16>(A, (const bf16*)W, woff, (const bf16*)bias, boff,
                             Cb, Cf, M, N, K, act, mode);
}

__global__ __launch_bounds__(256) void k_gemm_qkv(
    const bf16* __restrict__ A,
    const void* qw, const void* kw, const void* vw,
    const void* qb, const void* kb, const void* vb,
    long long woff, long long boff,
    bf16* Cq, bf16* Ck, bf16* Cv, const int* __restrict__ fl)
{
    const int z = blockIdx.z;
    const void* W  = (z == 0) ? qw : (z == 1) ? kw : vw;
    const void* Bi = (z == 0) ? qb : (z == 1) ? kb : vb;
    bf16* C        = (z == 0) ? Cq : (z == 1) ? Ck : Cv;
    const int mode = (z == 0) ? 3 : (z == 2) ? 2 : 0;
    if (*fl) gemm_body<float>(A, (const float*)W, woff, (const float*)Bi, boff,
                              C, nullptr, M_, HID, HID, 0, mode);
    else     gemm_body<bf16>(A, (const bf16*)W, woff, (const bf16*)Bi, boff,
                             C, nullptr, M_, HID, HID, 0, mode);
}

// -------- prepped GEMM: W bf16 pre-transposed [n][k].
// 2-phase schedule: double-buffered LDS, global_load_lds (16B, direct-to-LDS,
// no VGPR round-trip), ONE barrier per K-tile. Rule #21 both-sides swizzle.
static __device__ void gemm_t_body(
    const bf16* A, const bf16* Wt, long long woff, const bf16* bias, long long boff,
    bf16* Cb, float* Cf, int M, int N, int K, int act, int mode)
{
    __shared__ __align__(16) unsigned short Tz[2][2][4096];   // [buf][A/W][64*64] 32KB
    const int tid  = threadIdx.x;
    const int wv   = tid >> 6, lane = tid & 63;
    const int quad = lane >> 4, c = lane & 15;
    const int wm = wv & 1, wn = wv >> 1;
    const int bm = blockIdx.x * 64, bn = blockIdx.y * 64;
    const unsigned short* Ag = (const unsigned short*)A;
    const unsigned short* Wg = (const unsigned short*)Wt + woff;
    // staging geometry: thread -> 2 rows (j=0,1), 16B each, linear LDS dest
    const int sr = tid >> 3;                       // row within 32-row half
    const int csw0 = (((tid & 7) ^ (sr & 7)) << 3);      // inverse-swizzled col (elems)
    int ar0 = bm + sr;        ar0 = ar0 < M ? ar0 : M - 1;
    int ar1 = bm + 32 + sr;   ar1 = ar1 < M ? ar1 : M - 1;
    const int wr0 = bn + sr, wr1 = bn + 32 + sr;
    const int ldso = tid * 8;                      // elems within 2048-elem half

    f32x4 acc[2][2] = {{{0.f,0.f,0.f,0.f},{0.f,0.f,0.f,0.f}},
                       {{0.f,0.f,0.f,0.f},{0.f,0.f,0.f,0.f}}};

    #define STAGE_T(buf, k0) do { \
        GLOAD16(Ag + (size_t)ar0*K + (k0) + csw0, &Tz[buf][0][ldso]); \
        GLOAD16(Ag + (size_t)ar1*K + (k0) + csw0, &Tz[buf][0][2048 + ldso]); \
        GLOAD16(Wg + (size_t)wr0*K + (k0) + csw0, &Tz[buf][1][ldso]); \
        GLOAD16(Wg + (size_t)wr1*K + (k0) + csw0, &Tz[buf][1][2048 + ldso]); \
    } while (0)

    STAGE_T(0, 0);
    __syncthreads();                               // vmcnt(0) drain + barrier
    int cur = 0;
    for (int k0 = 0; k0 < K; k0 += 64) {
        if (k0 + 64 < K) STAGE_T(cur ^ 1, k0 + 64);    // async loads for next tile
        #pragma unroll
        for (int ks = 0; ks < 2; ++ks) {
            short8 af[2], bfr[2];
            #pragma unroll
            for (int mi = 0; mi < 2; ++mi) {
                const int row = wm*32 + mi*16 + c;
                const char* p = (const char*)&Tz[cur][0][0]
                              + (row*128 + (((ks*64 + quad*16)) ^ ((row & 7) << 4)));
                af[mi] = *reinterpret_cast<const short8*>(p);
            }
            #pragma unroll
            for (int ni = 0; ni < 2; ++ni) {
                const int row = wn*32 + ni*16 + c;
                const char* p = (const char*)&Tz[cur][1][0]
                              + (row*128 + (((ks*64 + quad*16)) ^ ((row & 7) << 4)));
                bfr[ni] = *reinterpret_cast<const short8*>(p);
            }
            #pragma unroll
            for (int mi = 0; mi < 2; ++mi)
                #pragma unroll
                for (int ni = 0; ni < 2; ++ni)
                    acc[mi][ni] = __builtin_amdgcn_mfma_f32_16x16x32_bf16(
                                      af[mi], bfr[ni], acc[mi][ni], 0, 0, 0);
        }
        __syncthreads();                           // drains next-tile loads + read fence
        cur ^= 1;
    }
    #undef STAGE_T
    gemm_epilogue(acc, b2f(bias[boff + bn + wn*32 + c]),
                  b2f(bias[boff + bn + wn*32 + 16 + c]),
                  Cb, Cf, M, N, act, mode, bm, bn, wm, wn, quad, c);
}

__global__ __launch_bounds__(256) void k_gemm_t(
    const bf16* __restrict__ A, const bf16* __restrict__ Wt, long long woff,
    const bf16* __restrict__ bias, long long boff,
    bf16* Cb, float* Cf, int M, int N, int K, int act, int mode)
{
    gemm_t_body(A, Wt, woff, bias, boff, Cb, Cf, M, N, K, act, mode);
}

__global__ __launch_bounds__(256) void k_gemm_qkv_t(
    const bf16* __restrict__ A, const bf16* __restrict__ wbt, const bf16* __restrict__ bb,
    int lyr, bf16* Cq, bf16* Ck, bf16* Cv)
{
    const int z = blockIdx.z;
    long long woff; long long boff; bf16* C; int mode;
    if (z == 0)      { woff = WQ_ + (long long)lyr*147456; boff = BQ_ + lyr*384; C = Cq; mode = 3; }
    else if (z == 1) { woff = WK_ + (long long)lyr*147456; boff = BK_ + lyr*384; C = Ck; mode = 0; }
    else             { woff = WV_ + (long long)lyr*147456; boff = BV_ + lyr*384; C = Cv; mode = 2; }
    gemm_t_body(A, wbt, woff, bb, boff, C, nullptr, M_, HID, HID, 0, mode);
}

// -------- 32-row-tile prepped GEMM (f32 += epilogue), for grid-starved dispatches.
// O-proj and M2 at 64-row tiles give 444 blocks = 1.7/CU (latency-bound). M=4704 =
// 147x32 exactly: 32-row tiles -> 882 blocks = 3.45/CU, LDS 24KB (6 blocks/CU cap).
// Same 2-phase gload_lds schedule + rule-#21 swizzle; each wave computes 16x32.
__global__ __launch_bounds__(256) void k_gemm_t32(
    const bf16* __restrict__ A, const bf16* __restrict__ Wt, long long woff,
    const bf16* __restrict__ bias, long long boff,
    float* __restrict__ Cf, int M, int N, int K)
{
    __shared__ __align__(16) unsigned short Az[2][2048];   // [buf][32 rows x 64 k]
    __shared__ __align__(16) unsigned short Wz[2][4096];   // [buf][64 cols x 64 k]
    const int tid  = threadIdx.x;
    const int wv   = tid >> 6, lane = tid & 63;
    const int quad = lane >> 4, c = lane & 15;
    const int wm = wv & 1, wn = wv >> 1;
    const int bm = blockIdx.x * 32, bn = blockIdx.y * 64;
    const unsigned short* Ag = (const unsigned short*)A;
    const unsigned short* Wg = (const unsigned short*)Wt + woff;
    const int sr = tid >> 3;                       // 0..31
    const int csw0 = (((tid & 7) ^ (sr & 7)) << 3);
    const int ar = bm + sr;                        // 147x32 = M exactly, no clamp
    const int wr0 = bn + sr, wr1 = bn + 32 + sr;
    const int ldso = tid * 8;

    f32x4 acc[2] = {{0.f,0.f,0.f,0.f},{0.f,0.f,0.f,0.f}};

    #define STAGE_T32(buf, k0) do { \
        GLOAD16(Ag + (size_t)ar*K + (k0) + csw0, &Az[buf][ldso]); \
        GLOAD16(Wg + (size_t)wr0*K + (k0) + csw0, &Wz[buf][ldso]); \
        GLOAD16(Wg + (size_t)wr1*K + (k0) + csw0, &Wz[buf][2048 + ldso]); \
    } while (0)

    STAGE_T32(0, 0);
    __syncthreads();
    int cur = 0;
    for (int k0 = 0; k0 < K; k0 += 64) {
        if (k0 + 64 < K) STAGE_T32(cur ^ 1, k0 + 64);
        #pragma unroll
        for (int ks = 0; ks < 2; ++ks) {
            short8 af, bfr[2];
            {
                const int row = wm*16 + c;
                const char* p = (const char*)&Az[cur][0]
                              + (row*128 + ((ks*64 + quad*16) ^ ((row & 7) << 4)));
                af = *reinterpret_cast<const short8*>(p);
            }
            #pragma unroll
            for (int ni = 0; ni < 2; ++ni) {
                const int row = wn*32 + ni*16 + c;
                const char* p = (const char*)&Wz[cur][0]
                              + (row*128 + ((ks*64 + quad*16) ^ ((row & 7) << 4)));
                bfr[ni] = *reinterpret_cast<const short8*>(p);
            }
            #pragma unroll
            for (int ni = 0; ni < 2; ++ni)
                acc[ni] = __builtin_amdgcn_mfma_f32_16x16x32_bf16(af, bfr[ni], acc[ni], 0, 0, 0);
        }
        __syncthreads();
        cur ^= 1;
    }
    #undef STAGE_T32
    // epilogue: f32 += (bias included)
    #pragma unroll
    for (int ni = 0; ni < 2; ++ni) {
        const int col = bn + wn*32 + ni*16 + c;
        const float bcol = b2f(bias[boff + col]);
        #pragma unroll
        for (int r = 0; r < 4; ++r) {
            const int row = bm + wm*16 + quad*4 + r;
            Cf[(size_t)row*N + col] += acc[ni][r] + bcol;
        }
    }
}

// ---------------------------------------------------------------- MFMA flash attention
// (fallback) 64 queries/block, 8 waves, in-block split-K x2 — used when ws lacks
// room for flash-decode partials.
__global__ __launch_bounds__(512) void k_attn(
    const bf16* __restrict__ q, const bf16* __restrict__ k,
    const bf16* __restrict__ vt, bf16* __restrict__ ao)
{
    __shared__ __align__(16) unsigned short Ks[2][64][80];   // [split][key][d 0..63 +pad]
    __shared__ __align__(16) unsigned short Vt[2][48][72];   // [split][d][key 0..63 +pad]
    __shared__ __align__(16) unsigned short Pq[8][16][72];   // [wave][query][key 0..63 +pad]
    const int tid  = threadIdx.x;
    const int w    = tid >> 6, lane = tid & 63;
    const int quad = lane >> 4, c = lane & 15;
    const int qt = w & 3, sp = w >> 2;               // q-tile 0..3, split 0..1
    const int bh = blockIdx.y;                       // b*8+hh
    const size_t base  = (size_t)(bh >> 3)*L_*HID + (size_t)(bh & 7)*HD;
    const size_t vbase = (size_t)bh*48*VLP;
    const int q0 = blockIdx.x*64 + qt*16;
    const bool qvalid = q0 < L_;                     // wave-uniform
    const int qrow = qvalid ? (q0 + c) : c;

    short8 qf0, qf1;
    {
        const unsigned short* qp = (const unsigned short*)(q + base + (size_t)qrow*HID);
        qf0 = *reinterpret_cast<const short8*>(qp + quad*8);                 // d 0..31
        if (quad < 2) qf1 = *reinterpret_cast<const short8*>(qp + 32 + quad*8);  // d 32..47
        else          qf1 = short8{0,0,0,0,0,0,0,0};                         // d 48..63 pad
    }
    f32x4 o0 = {0.f,0.f,0.f,0.f}, o1 = {0.f,0.f,0.f,0.f}, o2 = {0.f,0.f,0.f,0.f};
    float m = -3.0e38f, lsum = 0.f;

    // ---- staging assignment: 256-thread group per split
    const int t256 = tid & 255, grp = tid >> 8;
    const int krow0 = t256 >> 3, kch = t256 & 7;     // K row 0..31 / ch 0..7
    const int krow1 = 32 + krow0;                    // K row 32..63
    const int vd0 = krow0;                           // V d 0..31
    const int vd1 = 32 + (krow0 & 15);               // V d 32..47 (t256<128 only)
    const bool vl1 = (t256 < 128);
    const unsigned short* kq = (const unsigned short*)(k + base);
    const unsigned short* vq = (const unsigned short*)(vt + vbase);
    const short8 Z8 = short8{0,0,0,0,0,0,0,0};
    short8 kr0 = Z8, kr1 = Z8, vr0, vr1 = Z8;
    {   // prefetch tile 0 (keys unclamped: OOB tail lands inside workspace, masked in S)
        const int kb0 = grp*1216;
        if (kch < 6) {
            kr0 = *reinterpret_cast<const short8*>(kq + (size_t)(kb0 + krow0)*HID + kch*8);
            kr1 = *reinterpret_cast<const short8*>(kq + (size_t)(kb0 + krow1)*HID + kch*8);
        }
        vr0 = *reinterpret_cast<const short8*>(vq + (size_t)vd0*VLP + kb0 + kch*8);
        if (vl1) vr1 = *reinterpret_cast<const short8*>(vq + (size_t)vd1*VLP + kb0 + kch*8);
    }

    for (int tt = 0; tt < 19; ++tt) {
        __syncthreads();                             // prev tile's LDS reads done
        *reinterpret_cast<short8*>(&Ks[grp][krow0][kch*8]) = kr0;
        *reinterpret_cast<short8*>(&Ks[grp][krow1][kch*8]) = kr1;
        *reinterpret_cast<short8*>(&Vt[grp][vd0][kch*8])   = vr0;
        if (vl1) *reinterpret_cast<short8*>(&Vt[grp][vd1][kch*8]) = vr1;
        __syncthreads();                             // this tile's LDS ready
        if (tt < 18) {                               // issue next tile's loads -> regs
            const int nb0 = grp*1216 + (tt + 1)*64;
            if (kch < 6) {
                kr0 = *reinterpret_cast<const short8*>(kq + (size_t)(nb0 + krow0)*HID + kch*8);
                kr1 = *reinterpret_cast<const short8*>(kq + (size_t)(nb0 + krow1)*HID + kch*8);
            }
            vr0 = *reinterpret_cast<const short8*>(vq + (size_t)vd0*VLP + nb0 + kch*8);
            if (vl1) vr1 = *reinterpret_cast<const short8*>(vq + (size_t)vd1*VLP + nb0 + kch*8);
        }

        const int kt = sp*1216 + tt*64;              // compute key base for this wave
        float sv[16];
        #pragma unroll
        for (int t = 0; t < 4; ++t) {
            f32x4 acc = {0.f,0.f,0.f,0.f};
            short8 a0 = *reinterpret_cast<const short8*>(&Ks[sp][t*16 + c][quad*8]);
            short8 a1 = *reinterpret_cast<const short8*>(&Ks[sp][t*16 + c][32 + quad*8]);
            acc = __builtin_amdgcn_mfma_f32_16x16x32_bf16(a0, qf0, acc, 0, 0, 0);
            acc = __builtin_amdgcn_mfma_f32_16x16x32_bf16(a1, qf1, acc, 0, 0, 0);
            #pragma unroll
            for (int r = 0; r < 4; ++r) sv[t*4 + r] = acc[r];   // already log2-scaled
        }
        if (sp == 1 && tt >= 17) {                   // tiles with keys >= L_ (2304.. / 2368..)
            #pragma unroll
            for (int t = 0; t < 4; ++t)
                #pragma unroll
                for (int r = 0; r < 4; ++r)
                    if (kt + t*16 + quad*4 + r >= L_) sv[t*4 + r] = -3.0e38f;
        }
        // tree max (depth 4, max3-fusable)
        float tmax = fmaxf(fmaxf(fmaxf(sv[0], sv[1]),  fmaxf(sv[2],  sv[3])),
                           fmaxf(fmaxf(sv[4], sv[5]),  fmaxf(sv[6],  sv[7])));
        float tmx2 = fmaxf(fmaxf(fmaxf(sv[8], sv[9]),  fmaxf(sv[10], sv[11])),
                           fmaxf(fmaxf(sv[12], sv[13]), fmaxf(sv[14], sv[15])));
        tmax = fmaxf(tmax, tmx2);
        tmax = fmaxf(tmax, __shfl_xor(tmax, 16));
        tmax = fmaxf(tmax, __shfl_xor(tmax, 32));
        if (!__all(tmax <= m + 8.0f)) {              // defer-max: rescale only on growth
            const float mn = fmaxf(m, tmax);
            const float alpha = exp2f(m - mn);
            m = mn;
            lsum *= alpha;
            o0 *= alpha; o1 *= alpha; o2 *= alpha;
        }
        float psum = 0.f;
        unsigned short pv[16];
        #pragma unroll
        for (int i = 0; i < 16; ++i) {
            const float p = exp2f(sv[i] - m);        // bounded by 2^8
            psum += p;
            pv[i] = f2us(p);
        }
        lsum += psum;
        // P row (query c) -> LDS; same-wave rw, no barrier needed
        #pragma unroll
        for (int t = 0; t < 4; ++t)
            *reinterpret_cast<ushort4*>(&Pq[w][c][t*16 + quad*4]) =
                make_ushort4(pv[t*4+0], pv[t*4+1], pv[t*4+2], pv[t*4+3]);
        // PV in 2 steps of 32 keys (b128 fragments)
        #pragma unroll
        for (int s = 0; s < 2; ++s) {
            short8 pf  = *reinterpret_cast<const short8*>(&Pq[w][c][s*32 + quad*8]);
            short8 vf0 = *reinterpret_cast<const short8*>(&Vt[sp][c][s*32 + quad*8]);
            short8 vf1 = *reinterpret_cast<const short8*>(&Vt[sp][16 + c][s*32 + quad*8]);
            short8 vf2 = *reinterpret_cast<const short8*>(&Vt[sp][32 + c][s*32 + quad*8]);
            o0 = __builtin_amdgcn_mfma_f32_16x16x32_bf16(vf0, pf, o0, 0, 0, 0);
            o1 = __builtin_amdgcn_mfma_f32_16x16x32_bf16(vf1, pf, o1, 0, 0, 0);
            o2 = __builtin_amdgcn_mfma_f32_16x16x32_bf16(vf2, pf, o2, 0, 0, 0);
        }
    }
    // ---- reduce l across quads within wave
    float lw = lsum;
    lw += __shfl_xor(lw, 16);
    lw += __shfl_xor(lw, 32);
    // ---- split merge through LDS (reuse Ks: 20480 B >= 4*64*14*4 = 14336 B; Ks dead here)
    float* Mg = (float*)&Ks[0][0][0];
    __syncthreads();
    if (sp == 1) {
        float* dst = Mg + (size_t)(qt*64 + lane)*14;
        dst[0] = o0[0]; dst[1] = o0[1]; dst[2]  = o0[2]; dst[3]  = o0[3];
        dst[4] = o1[0]; dst[5] = o1[1]; dst[6]  = o1[2]; dst[7]  = o1[3];
        dst[8] = o2[0]; dst[9] = o2[1]; dst[10] = o2[2]; dst[11] = o2[3];
        dst[12] = m; dst[13] = lw;
    }
    __syncthreads();
    if (sp == 0 && qvalid) {
        const float* src = Mg + (size_t)(qt*64 + lane)*14;
        const float m2 = src[12], l2 = src[13];
        const float mm = fmaxf(m, m2);
        const float a1 = exp2f(m - mm), a2 = exp2f(m2 - mm);
        const float inv = 1.0f / (lw*a1 + l2*a2);
        unsigned short* orow = (unsigned short*)(ao + base + (size_t)(q0 + c)*HID);
        const f32x4 ot[3] = {o0, o1, o2};
        #pragma unroll
        for (int dt = 0; dt < 3; ++dt) {
            ushort4 w4;
            w4.x = f2us((ot[dt][0]*a1 + src[dt*4+0]*a2) * inv);
            w4.y = f2us((ot[dt][1]*a1 + src[dt*4+1]*a2) * inv);
            w4.z = f2us((ot[dt][2]*a1 + src[dt*4+2]*a2) * inv);
            w4.w = f2us((ot[dt][3]*a1 + src[dt*4+3]*a2) * inv);
            *reinterpret_cast<ushort4*>(orow + dt*16 + quad*4) = w4;
        }
    }
}

// ---------------------------------------------------------------- flash-decode attention
// Key-split ACROSS blocks, XCD-aware bijective remap (T1, round 10: FETCH 34->6.7MB,
// hbm 812->255 GB/s confirmed). Round 11's T5 setprio was null-to-negative (waves are
// barrier-lockstep per block — no role diversity to arbitrate; matches m190) — reverted.
// gload_lds 2-phase double-buffer staging (rule #21 swizzle), raw v_exp_f32,
// truncation-packed bf16 P, max3-fusable reduce. K d-pad cols pre-zeroed.
__global__ __launch_bounds__(256) void k_attn_fd(
    const bf16* __restrict__ q, const bf16* __restrict__ k,
    const bf16* __restrict__ vt, bf16* __restrict__ pob, float* __restrict__ pml)
{
    __shared__ __align__(16) unsigned short Kz[2][4096];  // [buf][64 key x 64 d] swizzled
    __shared__ __align__(16) unsigned short Vz[2][3072];  // [buf][48 d x 64 key] swizzled
    __shared__ __align__(16) unsigned short Pq[4][16][72];
    const int tid  = threadIdx.x;
    const int w    = tid >> 6, lane = tid & 63;
    const int quad = lane >> 4, c = lane & 15;
    // XCD-aware decomposition of the 1184-block 1D grid
    const int bid  = blockIdx.x;
    const int wg   = (bid & 7)*148 + (bid >> 3);     // bijective: 148 blocks per XCD
    const int g    = wg / 37;                        // (bh,half) group 0..31
    const int qblk = wg - g*37;
    const int bh   = g >> 1;
    const int half = g & 1;
    const size_t base  = (size_t)(bh >> 3)*L_*HID + (size_t)(bh & 7)*HD;
    const size_t vbase = (size_t)bh*48*VLP;
    const int q0 = qblk*64 + w*16;
    const bool qvalid = q0 < L_;                     // wave-uniform
    const int qrow = qvalid ? (q0 + c) : c;

    short8 qf0, qf1;
    {
        const unsigned short* qp = (const unsigned short*)(q + base + (size_t)qrow*HID);
        qf0 = *reinterpret_cast<const short8*>(qp + quad*8);                 // d 0..31
        if (quad < 2) qf1 = *reinterpret_cast<const short8*>(qp + 32 + quad*8);  // d 32..47
        else          qf1 = short8{0,0,0,0,0,0,0,0};                         // d 48..63 pad
    }
    f32x4 o0 = {0.f,0.f,0.f,0.f}, o1 = {0.f,0.f,0.f,0.f}, o2 = {0.f,0.f,0.f,0.f};
    float m = -3.0e38f, lsum = 0.f;

    // staging geometry: per thread 2 K-slots + 1-2 V-slots, all linear (tid*16B) dests
    const int srow = tid >> 3;                       // 0..31
    const int sc   = (tid & 7) ^ (srow & 7);         // inverse-swizzled slot
    const int scol = sc << 3;                        // global col (elems)
    const bool kld = (sc < 6);                       // K cols 48..63 never loaded
    const int ldo  = tid * 8;                        // linear LDS dest (elems)
    const unsigned short* kq = (const unsigned short*)(k + base);
    const unsigned short* vq = (const unsigned short*)(vt + vbase);
    const int kbase = half*1216;

    #define STAGE_FD(buf, kb) do { \
        if (kld) { \
            GLOAD16(kq + (size_t)((kb) + srow)*HID + scol,      &Kz[buf][ldo]); \
            GLOAD16(kq + (size_t)((kb) + 32 + srow)*HID + scol, &Kz[buf][2048 + ldo]); \
        } \
        GLOAD16(vq + (size_t)srow*VLP + (kb) + scol, &Vz[buf][ldo]); \
        if (tid < 128) \
            GLOAD16(vq + (size_t)(32 + srow)*VLP + (kb) + scol, &Vz[buf][2048 + ldo]); \
    } while (0)

    {   // pre-zero K d-pad slots (cols 48..63) in both buffers — never loaded
        const short8 Z8 = short8{0,0,0,0,0,0,0,0};
        if (tid < 128) {
            const int r = tid >> 1, j = tid & 1;
            const int s = (6 + j) ^ (r & 7);
            *reinterpret_cast<short8*>(&Kz[0][r*64 + s*8]) = Z8;
            *reinterpret_cast<short8*>(&Kz[1][r*64 + s*8]) = Z8;
        }
    }
    STAGE_FD(0, kbase);
    __syncthreads();                                 // vmcnt drain + barrier
    int cur = 0;

    for (int tt = 0; tt < 19; ++tt) {
        if (tt < 18) STAGE_FD(cur ^ 1, kbase + (tt + 1)*64);   // async next-tile loads

        const int kt = kbase + tt*64;
        const char* kzb = (const char*)&Kz[cur][0];
        const char* vzb = (const char*)&Vz[cur][0];
        const int qx = quad << 4;                    // colbyte of this quad's 16B
        float sv[16];
        #pragma unroll
        for (int t = 0; t < 4; ++t) {
            const int kr = t*16 + c;
            const int rx = kr*128;
            const int x0 = qx ^ ((kr & 7) << 4);
            f32x4 acc = {0.f,0.f,0.f,0.f};
            short8 a0 = *reinterpret_cast<const short8*>(kzb + rx + x0);
            short8 a1 = *reinterpret_cast<const short8*>(kzb + rx + (x0 ^ 64));
            acc = __builtin_amdgcn_mfma_f32_16x16x32_bf16(a0, qf0, acc, 0, 0, 0);
            acc = __builtin_amdgcn_mfma_f32_16x16x32_bf16(a1, qf1, acc, 0, 0, 0);
            #pragma unroll
            for (int r = 0; r < 4; ++r) sv[t*4 + r] = acc[r];   // already log2-scaled
        }
        if (half == 1 && tt >= 17) {                 // keys >= L_ (2304.. / 2368..)
            #pragma unroll
            for (int t = 0; t < 4; ++t)
                #pragma unroll
                for (int r = 0; r < 4; ++r)
                    if (kt + t*16 + quad*4 + r >= L_) sv[t*4 + r] = -3.0e38f;
        }
        // tree max: two max3-fusable chains + combine
        float h0 = fmaxf(fmaxf(sv[0], sv[1]), sv[2]);
        h0 = fmaxf(fmaxf(h0, sv[3]), sv[4]);
        h0 = fmaxf(fmaxf(h0, sv[5]), sv[6]);
        h0 = fmaxf(h0, sv[7]);
        float h1 = fmaxf(fmaxf(sv[8], sv[9]), sv[10]);
        h1 = fmaxf(fmaxf(h1, sv[11]), sv[12]);
        h1 = fmaxf(fmaxf(h1, sv[13]), sv[14]);
        h1 = fmaxf(h1, sv[15]);
        float tmax = fmaxf(h0, h1);
        tmax = fmaxf(tmax, __shfl_xor(tmax, 16));
        tmax = fmaxf(tmax, __shfl_xor(tmax, 32));
        if (!__all(tmax <= m + 8.0f)) {              // defer-max
            const float mn = fmaxf(m, tmax);
            const float alpha = exp2_raw(m - mn);
            m = mn;
            lsum *= alpha;
            o0 *= alpha; o1 *= alpha; o2 *= alpha;
        }
        // P = exp2(S - m), truncation-packed to bf16 pairs
        float psum = 0.f;
        unsigned pk[8];
        #pragma unroll
        for (int i = 0; i < 8; ++i) {
            const float p0 = exp2_raw(sv[2*i]     - m);   // bounded by 2^8
            const float p1 = exp2_raw(sv[2*i + 1] - m);
            psum += p0 + p1;
            pk[i] = (__float_as_uint(p0) >> 16) | (__float_as_uint(p1) & 0xFFFF0000u);
        }
        lsum += psum;
        // P row (query c) -> LDS as b64 pairs; same-wave rw, no barrier needed
        #pragma unroll
        for (int t = 0; t < 4; ++t)
            *reinterpret_cast<uint2*>(&Pq[w][c][t*16 + quad*4]) =
                make_uint2(pk[2*t], pk[2*t + 1]);
        // PV in 2 steps of 32 keys (b128 fragments, swizzled V reads)
        const int mx = (c & 7) << 4;
        #pragma unroll
        for (int s = 0; s < 2; ++s) {
            const int va = ((s << 6) | qx) ^ mx;
            short8 pf  = *reinterpret_cast<const short8*>(&Pq[w][c][s*32 + quad*8]);
            short8 vf0 = *reinterpret_cast<const short8*>(vzb + c*128 + va);
            short8 vf1 = *reinterpret_cast<const short8*>(vzb + (16 + c)*128 + va);
            short8 vf2 = *reinterpret_cast<const short8*>(vzb + (32 + c)*128 + va);
            o0 = __builtin_amdgcn_mfma_f32_16x16x32_bf16(vf0, pf, o0, 0, 0, 0);
            o1 = __builtin_amdgcn_mfma_f32_16x16x32_bf16(vf1, pf, o1, 0, 0, 0);
            o2 = __builtin_amdgcn_mfma_f32_16x16x32_bf16(vf2, pf, o2, 0, 0, 0);
        }
        __syncthreads();                             // drains next-tile loads + read fence
        cur ^= 1;
    }
    #undef STAGE_FD
    // reduce l across quads, normalize, store partials
    float lw = lsum;
    lw += __shfl_xor(lw, 16);
    lw += __shfl_xor(lw, 32);
    const float invl = 1.0f / lw;
    const size_t ro = ((size_t)bh*2368 + q0 + c)*2 + half;
    unsigned short* pr = (unsigned short*)pob + ro*48;
    const f32x4 ot[3] = {o0, o1, o2};
    #pragma unroll
    for (int dt = 0; dt < 3; ++dt) {
        ushort4 w4;
        w4.x = f2us(ot[dt][0]*invl);
        w4.y = f2us(ot[dt][1]*invl);
        w4.z = f2us(ot[dt][2]*invl);
        w4.w = f2us(ot[dt][3]*invl);
        *reinterpret_cast<ushort4*>(pr + dt*16 + quad*4) = w4;
    }
    if (quad == 0) { pml[ro*2 + 0] = m; pml[ro*2 + 1] = lw; }
}

// merge the two key-halves: out = (o1*l1*a1 + o2*l2*a2) / (l1*a1 + l2*a2)
__global__ __launch_bounds__(256) void k_amerge(
    const bf16* __restrict__ pob, const float* __restrict__ pml, bf16* __restrict__ ao)
{
    const int tid = threadIdx.x;
    const int bh = blockIdx.y;
    const int qq = blockIdx.x*16 + (tid >> 4);       // 0..2351
    const int j = tid & 15;
    const size_t ro = ((size_t)bh*2368 + qq)*2;
    const float m1 = pml[ro*2 + 0], l1 = pml[ro*2 + 1];
    const float m2 = pml[ro*2 + 2], l2 = pml[ro*2 + 3];
    const float mm = fmaxf(m1, m2);
    const float b1 = exp2f(m1 - mm)*l1, b2 = exp2f(m2 - mm)*l2;
    const float inv = 1.0f / (b1 + b2);
    const float w1 = b1*inv, w2 = b2*inv;
    if (j < 12) {
        const unsigned short* p1 = (const unsigned short*)pob + ro*48 + j*4;
        ushort4 u1 = *reinterpret_cast<const ushort4*>(p1);
        ushort4 u2 = *reinterpret_cast<const ushort4*>(p1 + 48);
        ushort4 o4;
        o4.x = f2us(us2f(u1.x)*w1 + us2f(u2.x)*w2);
        o4.y = f2us(us2f(u1.y)*w1 + us2f(u2.y)*w2);
        o4.z = f2us(us2f(u1.z)*w1 + us2f(u2.z)*w2);
        o4.w = f2us(us2f(u1.w)*w1 + us2f(u2.w)*w2);
        const size_t base = (size_t)(bh >> 3)*L_*HID + (size_t)(bh & 7)*HD;
        *reinterpret_cast<ushort4*>((unsigned short*)ao + base + (size_t)qq*HID + j*4) = o4;
    }
}

// ------------------------------------------------------- final LN + heads
template <typename T, typename TO>
static __device__ void final_body(
    const float* h, const T* fn_g, const T* fn_b,
    const T* on_w, const T* on_b, const T* oe_w, const T* oe_b, TO* out)
{
    __shared__ float hf[HID];
    const int row = blockIdx.x;
    const int b = row / L_, l = row % L_;
    const int lane = threadIdx.x;
    const float* hr = h + (size_t)row*HID;
    float v[6]; float s = 0.f, ss = 0.f;
    #pragma unroll
    for (int j = 0; j < 6; ++j) { float t = hr[lane + j*64]; v[j] = t; s += t; ss += t*t; }
    #pragma unroll
    for (int off = 32; off; off >>= 1) { s += __shfl_xor(s, off); ss += __shfl_xor(ss, off); }
    const float mu = s * (1.0f/HID);
    const float rs = rsqrtf(fmaxf(ss * (1.0f/HID) - mu*mu, 0.0f) + 1e-5f);
    #pragma unroll
    for (int j = 0; j < 6; ++j) {
        int c = lane + j*64;
        hf[c] = (v[j] - mu) * rs * ldv(fn_g, c) + ldv(fn_b, c);
    }
    __syncthreads();
    if (l < N_) {
        if (lane < A_) {
            float acc = ldv(on_b, lane);
            for (int c = 0; c < HID; ++c) acc += hf[c] * ldv(on_w, (size_t)c*A_ + lane);
            stv(out, (size_t)(b*N_ + l)*A_ + lane, acc);
        }
    } else {
        const int e = l - N_;
        if (lane < E_) {
            float acc = ldv(oe_b, lane);
            for (int c = 0; c < HID; ++c) acc += hf[c] * ldv(oe_w, (size_t)c*E_ + lane);
            stv(out, (size_t)B_*N_*A_ + ((size_t)b*N_*N_ + e)*E_ + lane, acc);
        }
    }
}

__global__ __launch_bounds__(64) void k_final(
    const float* __restrict__ h, const void* fn_g, const void* fn_b,
    const void* on_w, const void* on_b, const void* oe_w, const void* oe_b,
    const int* __restrict__ fl, void* out)
{
    if (*fl) final_body<float, float>(h, (const float*)fn_g, (const float*)fn_b,
                                      (const float*)on_w, (const float*)on_b,
                                      (const float*)oe_w, (const float*)oe_b, (float*)out);
    else     final_body<bf16, bf16>(h, (const bf16*)fn_g, (const bf16*)fn_b,
                                    (const bf16*)on_w, (const bf16*)on_b,
                                    (const bf16*)oe_w, (const bf16*)oe_b, (bf16*)out);
}

// ---------------------------------------------------------------- launch
extern "C" void kernel_launch(void* const* d_in, const int* in_sizes, int n_in,
                              void* d_out, int out_size, void* d_ws, size_t ws_size,
                              hipStream_t stream) {
    const void* x      = d_in[0];
    const void* adj    = d_in[1];
    const void* t      = d_in[2];
    const void* node_w = d_in[3];
    const void* node_b = d_in[4];
    const void* edge_w = d_in[5];
    const void* edge_b = d_in[6];
    const void* pos    = d_in[7];
    const void* t_w1   = d_in[8];
    const void* t_b1   = d_in[9];
    const void* t_w2   = d_in[10];
    const void* t_b2   = d_in[11];
    const void* ada1_w = d_in[12];
    const void* ada1_b = d_in[13];
    const void* ada2_w = d_in[14];
    const void* ada2_b = d_in[15];
    const void* q_w    = d_in[16];
    const void* q_b    = d_in[17];
    const void* k_w    = d_in[18];
    const void* k_b    = d_in[19];
    const void* v_w    = d_in[20];
    const void* v_b    = d_in[21];
    const void* o_w    = d_in[22];
    const void* o_b    = d_in[23];
    const void* m1_w   = d_in[24];
    const void* m1_b   = d_in[25];
    const void* m2_w   = d_in[26];
    const void* m2_b   = d_in[27];
    const void* fn_g   = d_in[28];
    const void* fn_b   = d_in[29];
    const void* on_w   = d_in[30];
    const void* on_b   = d_in[31];
    const void* oe_w   = d_in[32];
    const void* oe_b   = d_in[33];

    const size_t SZ  = (size_t)M_ * HID;          // 1,806,336 elements
    const size_t VTZ = (size_t)B_*NHD*HD*VLP;     // 1,867,776 elements (padded V^T)
    const size_t FLT = SZ + 12288 + (size_t)B_*4*HID + (size_t)B_*12*HID;  // 1,830,912
    const size_t M1FULL = (size_t)M_ * MLPD;      // 7,225,344
    const size_t BF_BASE = 3*SZ + VTZ;            // nb..vtb end = 7,286,784
    const size_t BF_BIG  = SZ + M1FULL;           // nb + m1f(from qb) end = 9,031,680
    const size_t NEED      = 256 + sizeof(float)*FLT + sizeof(bf16)*BF_BASE;   // ~21.9 MB
    const size_t NEED_BIG  = 256 + sizeof(float)*FLT + sizeof(bf16)*BF_BIG;    // ~25.4 MB
    const size_t NEED_PREP = 256 + sizeof(float)*FLT
                           + sizeof(bf16)*(BF_BIG + WTOT + BTOT);              // ~39.6 MB
    const size_t NEED_FD   = NEED_PREP + sizeof(bf16)*PO_E + sizeof(float)*PML_E; // ~47.5 MB
    if (ws_size < NEED) {
        hipMemsetAsync(d_out, 0, (size_t)out_size*sizeof(bf16), stream);  // 1.14 signature
        return;
    }
    const bool big  = (ws_size >= NEED_BIG);
    const bool prep = (ws_size >= NEED_PREP);
    const bool fd   = (ws_size >= NEED_FD);
    int*   fl   = (int*)d_ws;
    float* h    = (float*)((char*)d_ws + 256);
    float* ada  = h + SZ;                  // [8][B_][768]
    float* hid  = ada + 12288;             // [B_][1536]
    float* part = hid + (size_t)B_*4*HID;  // [B_][12][384] cond partials
    bf16* nb  = (bf16*)(part + (size_t)B_*12*HID);
    bf16* qb  = nb + SZ;
    bf16* kb  = qb + SZ;
    bf16* vtb = kb + SZ;                   // transposed V, [bh*48+d][VLP]
    bf16* m1c = kb;                        // chunked m1: [2352,1536] spans kb+vtb
    bf16* m1f = qb;                        // full m1: [M_,1536] spans qb..vtb+tail
    bf16* wbt = nb + BF_BIG;               // prepped weights (bf16, [n][k])
    bf16* bb  = wbt + WTOT;                // prepped biases
    bf16* pob = bb + BTOT;                 // flash-decode partial o (normalized)
    float* pml = (float*)(pob + PO_E);     // flash-decode partial (m, l)

    k_detect<<<1, 64, 0, stream>>>(node_w, fl);
    if (prep) {
        k_prepw<<<dim3(144, 24), 256, 0, stream>>>(q_w, k_w, v_w, o_w, m1_w, m2_w, fl, wbt);
        k_prepb<<<1, 256, 0, stream>>>(q_b, k_b, v_b, o_b, m1_b, m2_b, fl, bb);
    }
    k_embed<<<M_, HID, 0, stream>>>(x, adj, node_w, node_b, edge_w, edge_b, pos, fl, h);
    k_cond1<<<dim3(B_, 24), 256, 0, stream>>>(t, t_w1, t_b1, fl, hid);
    k_cond2<<<dim3(B_, 12), 384, 0, stream>>>(t_w2, t_b2, fl, hid, part);
    k_cond3<<<dim3(24, B_), 256, 0, stream>>>(ada1_w, ada1_b, ada2_w, ada2_b, fl, part, ada);
    for (int i = 0; i < LYR; ++i) {
        const long long woff   = (long long)i * HID * HID;
        const long long boff   = (long long)i * HID;
        const long long m1woff = (long long)i * HID * MLPD;
        const long long m1boff = (long long)i * MLPD;
        const long long m2woff = (long long)i * MLPD * HID;

        k_adaln<<<M_/4, 256, 0, stream>>>(h, ada, nb, 2*i);
        if (prep) {
            k_gemm_qkv_t<<<dim3(74, 6, 3), 256, 0, stream>>>(nb, wbt, bb, i, qb, kb, vtb);
            if (fd) {
                k_attn_fd<<<1184, 256, 0, stream>>>(qb, kb, vtb, pob, pml);
                k_amerge<<<dim3(147, 16), 256, 0, stream>>>(pob, pml, nb);   // ao -> nb
            } else {
                k_attn<<<dim3(37, B_*NHD), 512, 0, stream>>>(qb, kb, vtb, nb);
            }
            k_gemm_t32<<<dim3(147, 6), 256, 0, stream>>>(nb, wbt, WO_ + (long long)i*147456,
                                                         bb, BO_ + i*384,
                                                         h, M_, HID, HID);
            k_adaln<<<M_/4, 256, 0, stream>>>(h, ada, nb, 2*i + 1);          // n2 -> nb
            k_gemm_t<<<dim3(74, 24), 256, 0, stream>>>(nb, wbt, WM1_ + (long long)i*589824,
                                                       bb, BM1_ + i*MLPD,
                                                       m1f, nullptr, M_, MLPD, HID, 1, 0);
            k_gemm_t32<<<dim3(147, 6), 256, 0, stream>>>(m1f, wbt, WM2_ + (long long)i*589824,
                                                         bb, BM2_ + i*384,
                                                         h, M_, HID, MLPD);
        } else {
            k_gemm_qkv<<<dim3(74, 6, 3), 256, 0, stream>>>(nb, q_w, k_w, v_w, q_b, k_b, v_b,
                                                           woff, boff, qb, kb, vtb, fl);
            k_attn<<<dim3(37, B_*NHD), 512, 0, stream>>>(qb, kb, vtb, nb);   // ao -> nb
            k_gemm<<<dim3(74, 6), 256, 0, stream>>>(nb, o_w, woff, o_b, boff,
                                                    nullptr, h, M_, HID, HID, 0, 1, fl);
            k_adaln<<<M_/4, 256, 0, stream>>>(h, ada, nb, 2*i + 1);          // n2 -> nb
            if (big) {
                k_gemm<<<dim3(74, 24), 256, 0, stream>>>(nb, m1_w, m1woff, m1_b, m1boff,
                                                         m1f, nullptr, M_, MLPD, HID, 1, 0, fl);
                k_gemm<<<dim3(74, 6), 256, 0, stream>>>(m1f, m2_w, m2woff, m2_b, boff,
                                                        nullptr, h, M_, HID, MLPD, 0, 1, fl);
            } else {
                for (int c = 0; c < 2; ++c) {
                    k_gemm<<<dim3(37, 24), 256, 0, stream>>>(nb + (size_t)c*2352*HID,
                                                             m1_w, m1woff, m1_b, m1boff,
                                                             m1c, nullptr, 2352, MLPD, HID, 1, 0, fl);
                    k_gemm<<<dim3(37, 6), 256, 0, stream>>>(m1c, m2_w, m2woff, m2_b, boff,
                                                            nullptr, h + (size_t)c*2352*HID,
                                                            2352, HID, MLPD, 0, 1, fl);
                }
            }
        }
    }
    k_final<<<M_, 64, 0, stream>>>(h, fn_g, fn_b, on_w, on_b, oe_w, oe_b, fl, (void*)d_out);
}

// Round 13
// 710.801 us; speedup vs baseline: 1.0810x; 1.0589x over previous
//
#include <hip/hip_runtime.h>
#include <hip/hip_bf16.h>
#include <math.h>

typedef __hip_bfloat16 bf16;
typedef __attribute__((ext_vector_type(8))) short short8;   // 8 bf16 in 4 VGPRs
typedef __attribute__((ext_vector_type(4))) float f32x4;

#define B_ 2
#define N_ 48
#define A_ 16
#define E_ 5
#define HID 384
#define NHD 8
#define HD 48
#define LYR 4
#define MLPD 1536
#define L_ 2352      // N_ + N_*N_
#define M_ 4704      // B_*L_
#define VLP 2432     // padded key stride of transposed-V buffer
// 1/sqrt(48) * log2(e): Q pre-scale so softmax runs in log2 domain (exp2f)
#define QSCALE 0.20823513f

// prepped-weight element offsets (bf16, transposed [n][k] per matrix)
#define WQ_  0LL
#define WK_  589824LL
#define WV_  1179648LL
#define WO_  1769472LL
#define WM1_ 2359296LL
#define WM2_ 4718592LL
#define WTOT 7077888
// prepped-bias offsets
#define BQ_  0
#define BK_  1536
#define BV_  3072
#define BO_  4608
#define BM1_ 6144
#define BM2_ 12288
#define BTOT 13824

// flash-decode partials: [16 bh][2368 q][2 half] — o normalized (48 bf16) + (m,l) f32
#define PO_E  ((size_t)16*2368*2*48)   // bf16 elems
#define PML_E ((size_t)16*2368*2*2)    // f32 elems

// async global->LDS 16B direct copy (gfx950); LDS dest must be linear per-lane
#define GLOAD16(gp, lp) __builtin_amdgcn_global_load_lds( \
    (const __attribute__((address_space(1))) unsigned int*)(gp), \
    (__attribute__((address_space(3))) unsigned int*)(lp), 16, 0, 0)

static __device__ __forceinline__ float b2f(bf16 v) { return __bfloat162float(v); }
static __device__ __forceinline__ float us2f(unsigned short u) {
    return __uint_as_float(((unsigned)u) << 16);
}
static __device__ __forceinline__ unsigned short f2us(float f) {
    bf16 h = __float2bfloat16(f);
    return *reinterpret_cast<unsigned short*>(&h);
}
// raw v_exp_f32: 1 inst vs libm exp2f's denorm-fixup sequence; inputs <= 0,
// HW flush-to-zero on underflow is exactly softmax semantics.
static __device__ __forceinline__ float exp2_raw(float x) {
    float r;
    asm("v_exp_f32 %0, %1" : "=v"(r) : "v"(x));
    return r;
}
static __device__ __forceinline__ float ldv(const float* p, size_t i) { return p[i]; }
static __device__ __forceinline__ float ldv(const bf16*  p, size_t i) { return b2f(p[i]); }
static __device__ __forceinline__ void  stv(float* p, size_t i, float v) { p[i] = v; }
static __device__ __forceinline__ void  stv(bf16*  p, size_t i, float v) { p[i] = __float2bfloat16(v); }
static __device__ __forceinline__ float4 ld4(const float* p, size_t i) {
    return *reinterpret_cast<const float4*>(p + i);
}
static __device__ __forceinline__ float4 ld4(const bf16* p, size_t i) {
    ushort4 u = *reinterpret_cast<const ushort4*>(p + i);
    return make_float4(us2f(u.x), us2f(u.y), us2f(u.z), us2f(u.w));
}

// ------------------------------------------------ dtype detect (flag: 1=fp32, 0=bf16)
__global__ void k_detect(const void* w, int* flag) {
    if (threadIdx.x == 0 && blockIdx.x == 0) {
        const bf16* p = (const bf16*)w;   // node_w: 6144 elems of 0.02*normal
        int isf = 0;
        for (int i = 0; i < 256; ++i) {
            float v = fabsf(b2f(p[i]));
            if (!(v <= 1000.0f)) { isf = 1; break; }
        }
        *flag = isf;
    }
}

// ------------------------------------- weight prep: convert + transpose to [n][k] bf16
template <typename T>
static __device__ void prepw_body(
    const T* q_w, const T* k_w, const T* v_w, const T* o_w,
    const T* m1_w, const T* m2_w, bf16* wbt)
{
    __shared__ unsigned short Ts[64][72];
    const int z = blockIdx.y;
    const int kind = z >> 2, l = z & 3;
    const T* src; int K, N; long long dbase;
    switch (kind) {
        case 0: src = q_w;  K = 384;  N = 384;  dbase = WQ_;  break;
        case 1: src = k_w;  K = 384;  N = 384;  dbase = WK_;  break;
        case 2: src = v_w;  K = 384;  N = 384;  dbase = WV_;  break;
        case 3: src = o_w;  K = 384;  N = 384;  dbase = WO_;  break;
        case 4: src = m1_w; K = 384;  N = 1536; dbase = WM1_; break;
        default: src = m2_w; K = 1536; N = 384; dbase = WM2_; break;
    }
    const int Nt = N >> 6;
    const int tiles = (K >> 6) * Nt;
    if (blockIdx.x >= tiles) return;
    const int tk = blockIdx.x / Nt, tn = blockIdx.x % Nt;
    const int k0 = tk*64, n0 = tn*64;
    const size_t soff = (size_t)l * K * N;
    const size_t doff = (size_t)dbase + (size_t)l * K * N;
    const int tid = threadIdx.x;
    {   // load 64x64 fp tile -> bf16 LDS
        const int kk = tid >> 2, nc = (tid & 3) * 16;
        #pragma unroll
        for (int j = 0; j < 16; ++j)
            Ts[kk][nc + j] = f2us(ldv(src, soff + (size_t)(k0 + kk)*N + n0 + nc + j));
    }
    __syncthreads();
    {   // store transposed [n][k] with b128 writes
        const int nn = tid >> 2, kc = (tid & 3) * 16;
        unsigned short tmp[16];
        #pragma unroll
        for (int j = 0; j < 16; ++j) tmp[j] = Ts[kc + j][nn];
        unsigned short* dst = (unsigned short*)wbt + doff + (size_t)(n0 + nn)*K + k0 + kc;
        *reinterpret_cast<short8*>(dst)     = *reinterpret_cast<short8*>(&tmp[0]);
        *reinterpret_cast<short8*>(dst + 8) = *reinterpret_cast<short8*>(&tmp[8]);
    }
}

__global__ __launch_bounds__(256) void k_prepw(
    const void* q_w, const void* k_w, const void* v_w, const void* o_w,
    const void* m1_w, const void* m2_w, const int* __restrict__ fl, bf16* __restrict__ wbt)
{
    if (*fl) prepw_body<float>((const float*)q_w, (const float*)k_w, (const float*)v_w,
                               (const float*)o_w, (const float*)m1_w, (const float*)m2_w, wbt);
    else     prepw_body<bf16>((const bf16*)q_w, (const bf16*)k_w, (const bf16*)v_w,
                              (const bf16*)o_w, (const bf16*)m1_w, (const bf16*)m2_w, wbt);
}

template <typename T>
static __device__ void prepb_body(
    const T* q_b, const T* k_b, const T* v_b, const T* o_b,
    const T* m1_b, const T* m2_b, bf16* bb)
{
    for (int i = threadIdx.x; i < BTOT; i += 256) {
        float v;
        if      (i < BK_)  v = ldv(q_b,  i);
        else if (i < BV_)  v = ldv(k_b,  i - BK_);
        else if (i < BO_)  v = ldv(v_b,  i - BV_);
        else if (i < BM1_) v = ldv(o_b,  i - BO_);
        else if (i < BM2_) v = ldv(m1_b, i - BM1_);
        else               v = ldv(m2_b, i - BM2_);
        bb[i] = __float2bfloat16(v);
    }
}

__global__ __launch_bounds__(256) void k_prepb(
    const void* q_b, const void* k_b, const void* v_b, const void* o_b,
    const void* m1_b, const void* m2_b, const int* __restrict__ fl, bf16* __restrict__ bb)
{
    if (*fl) prepb_body<float>((const float*)q_b, (const float*)k_b, (const float*)v_b,
                               (const float*)o_b, (const float*)m1_b, (const float*)m2_b, bb);
    else     prepb_body<bf16>((const bf16*)q_b, (const bf16*)k_b, (const bf16*)v_b,
                              (const bf16*)o_b, (const bf16*)m1_b, (const bf16*)m2_b, bb);
}

// ---------------------------------------------------------------- embed (-> f32 h)
template <typename T>
static __device__ void embed_body(
    const T* x, const T* adj, const T* node_w, const T* node_b,
    const T* edge_w, const T* edge_b, const T* pos, float* h)
{
    const int bl = blockIdx.x;
    const int b = bl / L_, l = bl % L_;
    const int c = threadIdx.x;          // 0..383
    float acc;
    if (l < N_) {
        acc = ldv(node_b, c);
        const size_t xr = (size_t)(b*N_ + l)*A_;
        #pragma unroll
        for (int a = 0; a < A_; ++a) acc += ldv(x, xr + a) * ldv(node_w, (size_t)a*HID + c);
    } else {
        const int e = l - N_;
        acc = ldv(edge_b, c);
        const size_t ar = ((size_t)b*N_*N_ + e)*E_;
        #pragma unroll
        for (int j = 0; j < E_; ++j) acc += ldv(adj, ar + j) * ldv(edge_w, (size_t)j*HID + c);
    }
    h[(size_t)bl*HID + c] = acc + ldv(pos, (size_t)l*HID + c);
}

__global__ __launch_bounds__(384) void k_embed(
    const void* x, const void* adj, const void* node_w, const void* node_b,
    const void* edge_w, const void* edge_b, const void* pos,
    const int* __restrict__ fl, float* __restrict__ h)
{
    if (*fl) embed_body<float>((const float*)x, (const float*)adj, (const float*)node_w,
                               (const float*)node_b, (const float*)edge_w, (const float*)edge_b,
                               (const float*)pos, h);
    else     embed_body<bf16>((const bf16*)x, (const bf16*)adj, (const bf16*)node_w,
                              (const bf16*)node_b, (const bf16*)edge_w, (const bf16*)edge_b,
                              (const bf16*)pos, h);
}

// ---------------------------------------- cond stage 1: temb -> hidden (SiLU)
template <typename T>
static __device__ void cond1_body(const T* t, const T* t_w1, const T* t_b1, float* hid)
{
    __shared__ float temb[HID];
    __shared__ float red[4][64];
    const int b = blockIdx.x, jb = blockIdx.y, tid = threadIdx.x;
    const float tv = ldv(t, b);
    for (int c = tid; c < HID; c += 256) {
        int i = (c < 192) ? c : c - 192;
        float f = expf(-9.2103403719761836f * (float)i / 192.0f);
        float ang = tv * f;
        temb[c] = (c < 192) ? sinf(ang) : cosf(ang);
    }
    __syncthreads();
    const int ko = tid >> 6, jo = tid & 63;
    const int j = jb*64 + jo;
    float acc = 0.f;
    for (int i = ko*96; i < (ko + 1)*96; ++i)
        acc += temb[i] * ldv(t_w1, (size_t)i*4*HID + j);
    red[ko][jo] = acc;
    __syncthreads();
    if (ko == 0) {
        float a = red[0][jo] + red[1][jo] + red[2][jo] + red[3][jo] + ldv(t_b1, j);
        hid[(size_t)b*4*HID + j] = a / (1.0f + expf(-a));   // SiLU
    }
}

__global__ __launch_bounds__(256) void k_cond1(
    const void* t, const void* t_w1, const void* t_b1,
    const int* __restrict__ fl, float* __restrict__ hid)
{
    if (*fl) cond1_body<float>((const float*)t, (const float*)t_w1, (const float*)t_b1, hid);
    else     cond1_body<bf16>((const bf16*)t, (const bf16*)t_w1, (const bf16*)t_b1, hid);
}

// ---------------------------------------- cond stage 2: hidden -> partial cond sums
template <typename T>
static __device__ void cond2_body(const T* t_w2, const T* t_b2, const float* hid, float* part)
{
    __shared__ float hs[128];
    const int b = blockIdx.x, ch = blockIdx.y, c = threadIdx.x;
    const int j0 = ch*128;
    if (c < 128) hs[c] = hid[(size_t)b*4*HID + j0 + c];
    __syncthreads();
    float acc = (ch == 0) ? ldv(t_b2, c) : 0.f;
    for (int jj = 0; jj < 128; ++jj)
        acc += hs[jj] * ldv(t_w2, (size_t)(j0 + jj)*HID + c);
    part[((size_t)b*12 + ch)*HID + c] = acc;
}

__global__ __launch_bounds__(384) void k_cond2(
    const void* t_w2, const void* t_b2, const int* __restrict__ fl,
    const float* __restrict__ hid, float* __restrict__ part)
{
    if (*fl) cond2_body<float>((const float*)t_w2, (const float*)t_b2, hid, part);
    else     cond2_body<bf16>((const bf16*)t_w2, (const bf16*)t_b2, hid, part);
}

// ---------------------------------------- cond stage 3: ada projections
template <typename T>
static __device__ void cond3_body(
    const T* ada1_w, const T* ada1_b, const T* ada2_w, const T* ada2_b,
    const float* part, float* ada_out)
{
    __shared__ float cs[HID];
    const int slot = blockIdx.x / 3, ob = blockIdx.x % 3, b = blockIdx.y;
    const int tid = threadIdx.x;
    for (int c = tid; c < HID; c += 256) {
        float s = 0.f;
        #pragma unroll
        for (int ch = 0; ch < 12; ++ch) s += part[((size_t)b*12 + ch)*HID + c];
        cs[c] = s;
    }
    __syncthreads();
    const int layer = slot >> 1, which = slot & 1;
    const int o = ob*256 + tid;
    const T* W  = which ? ada2_w : ada1_w;
    const T* Bi = which ? ada2_b : ada1_b;
    float acc = ldv(Bi, (size_t)layer*768 + o);
    const size_t wb = (size_t)layer*HID*768 + o;
    for (int c = 0; c < HID; ++c) acc += cs[c] * ldv(W, wb + (size_t)c*768);
    ada_out[((size_t)slot*B_ + b)*768 + o] = acc;
}

__global__ __launch_bounds__(256) void k_cond3(
    const void* ada1_w, const void* ada1_b, const void* ada2_w, const void* ada2_b,
    const int* __restrict__ fl, const float* __restrict__ part, float* __restrict__ ada_out)
{
    if (*fl) cond3_body<float>((const float*)ada1_w, (const float*)ada1_b,
                               (const float*)ada2_w, (const float*)ada2_b, part, ada_out);
    else     cond3_body<bf16>((const bf16*)ada1_w, (const bf16*)ada1_b,
                              (const bf16*)ada2_w, (const bf16*)ada2_b, part, ada_out);
}

// ---------------------------------------------------------------- adaLN (f32 h -> bf16 n)
__global__ __launch_bounds__(256) void k_adaln(
    const float* __restrict__ h, const float* __restrict__ ada,
    bf16* __restrict__ n, int slot)
{
    const int row  = blockIdx.x * 4 + (threadIdx.x >> 6);
    const int lane = threadIdx.x & 63;
    const int b = row / L_;
    const float* hr = h + (size_t)row*HID;
    float v[6]; float s = 0.f, ss = 0.f;
    #pragma unroll
    for (int j = 0; j < 6; ++j) { float t = hr[lane + j*64]; v[j] = t; s += t; ss += t*t; }
    #pragma unroll
    for (int off = 32; off; off >>= 1) { s += __shfl_xor(s, off); ss += __shfl_xor(ss, off); }
    const float mu = s * (1.0f/HID);
    const float rs = rsqrtf(fmaxf(ss * (1.0f/HID) - mu*mu, 0.0f) + 1e-5f);
    const float* ap = ada + ((size_t)slot*B_ + b)*768;
    bf16* nr = n + (size_t)row*HID;
    #pragma unroll
    for (int j = 0; j < 6; ++j) {
        int c = lane + j*64;
        nr[c] = __float2bfloat16((v[j] - mu)*rs*(1.0f + ap[c]) + ap[384 + c]);
    }
}

// ------------------------------------------------- MFMA GEMM epilogue (shared)
// mode: 0=bf16 store, 1=f32 +=, 2=V^T bf16 scatter, 3=bf16 store*QSCALE
static __device__ __forceinline__ void gemm_epilogue(
    f32x4 (&acc)[2][2], float bcol0, float bcol1,
    bf16* Cb, float* Cf, int M, int N, int act, int mode,
    int bm, int bn, int wm, int wn, int quad, int c)
{
    const float bcol[2] = {bcol0, bcol1};
    #pragma unroll
    for (int mi = 0; mi < 2; ++mi)
        #pragma unroll
        for (int ni = 0; ni < 2; ++ni) {
            const int col = bn + wn*32 + ni*16 + c;
            #pragma unroll
            for (int r = 0; r < 4; ++r) {
                const int row = bm + wm*32 + mi*16 + quad*4 + r;
                if (row < M) {
                    float v = acc[mi][ni][r] + bcol[ni];
                    if (act) v = 0.5f * v * (1.0f + erff(v * 0.70710678118654752f));  // GELU
                    if (mode == 1) Cf[(size_t)row*N + col] += v;
                    else if (mode == 0) Cb[(size_t)row*N + col] = __float2bfloat16(v);
                    else if (mode == 3) Cb[(size_t)row*N + col] = __float2bfloat16(v * QSCALE);
                    else {
                        const int b   = row >= L_ ? 1 : 0;
                        const int key = row - b*L_;
                        const int hh  = col / 48, d = col - hh*48;
                        Cb[((size_t)(b*8 + hh)*48 + d)*VLP + key] = __float2bfloat16(v);
                    }
                }
            }
        }
}

// -------- legacy GEMM: W fp32/bf16 [k][n], converted+transposed during staging
template <typename T>
static __device__ void gemm_body(
    const bf16* A, const T* W, long long woff, const T* bias, long long boff,
    bf16* Cb, float* Cf, int M, int N, int K, int act, int mode)
{
    __shared__ __align__(16) unsigned short As[64][72];
    __shared__ __align__(16) unsigned short Bt[64][72];
    const int tid  = threadIdx.x;
    const int wv   = tid >> 6, lane = tid & 63;
    const int quad = lane >> 4, c = lane & 15;
    const int wm = wv & 1, wn = wv >> 1;
    const int bm = blockIdx.x * 64, bn = blockIdx.y * 64;
    const int arow = tid >> 3, ach = tid & 7;
    f32x4 acc[2][2] = {{{0.f,0.f,0.f,0.f},{0.f,0.f,0.f,0.f}},
                       {{0.f,0.f,0.f,0.f},{0.f,0.f,0.f,0.f}}};
    for (int k0 = 0; k0 < K; k0 += 64) {
        short8 av[2]; float4 w0[2], w1[2];
        #pragma unroll
        for (int i = 0; i < 2; ++i) {
            const int row = i*32 + arow;
            av[i] = short8{0,0,0,0,0,0,0,0};
            if (bm + row < M)
                av[i] = *reinterpret_cast<const short8*>(
                            A + (size_t)(bm + row)*K + k0 + ach*8);
            const size_t wrow = (size_t)woff + (size_t)(k0 + i*32 + arow)*N + bn + ach*8;
            w0[i] = ld4(W, wrow);
            w1[i] = ld4(W, wrow + 4);
        }
        __syncthreads();
        #pragma unroll
        for (int i = 0; i < 2; ++i) {
            *reinterpret_cast<short8*>(&As[i*32 + arow][ach*8]) = av[i];
            const int kk = i*32 + arow, nb0 = ach*8;
            Bt[nb0+0][kk] = f2us(w0[i].x); Bt[nb0+1][kk] = f2us(w0[i].y);
            Bt[nb0+2][kk] = f2us(w0[i].z); Bt[nb0+3][kk] = f2us(w0[i].w);
            Bt[nb0+4][kk] = f2us(w1[i].x); Bt[nb0+5][kk] = f2us(w1[i].y);
            Bt[nb0+6][kk] = f2us(w1[i].z); Bt[nb0+7][kk] = f2us(w1[i].w);
        }
        __syncthreads();
        #pragma unroll
        for (int ks = 0; ks < 2; ++ks) {
            short8 af[2], bfr[2];
            #pragma unroll
            for (int mi = 0; mi < 2; ++mi)
                af[mi] = *reinterpret_cast<const short8*>(
                             &As[wm*32 + mi*16 + c][ks*32 + quad*8]);
            #pragma unroll
            for (int ni = 0; ni < 2; ++ni)
                bfr[ni] = *reinterpret_cast<const short8*>(
                              &Bt[wn*32 + ni*16 + c][ks*32 + quad*8]);
            #pragma unroll
            for (int mi = 0; mi < 2; ++mi)
                #pragma unroll
                for (int ni = 0; ni < 2; ++ni)
                    acc[mi][ni] = __builtin_amdgcn_mfma_f32_16x16x32_bf16(
                                      af[mi], bfr[ni], acc[mi][ni], 0, 0, 0);
        }
    }
    gemm_epilogue(acc, ldv(bias, (size_t)boff + bn + wn*32 + c),
                  ldv(bias, (size_t)boff + bn + wn*32 + 16 + c),
                  Cb, Cf, M, N, act, mode, bm, bn, wm, wn, quad, c);
}

__global__ __launch_bounds__(256) void k_gemm(
    const bf16* __restrict__ A, const void* W, long long woff, const void* bias, long long boff,
    bf16* Cb, float* Cf, int M, int N, int K, int act, int mode,
    const int* __restrict__ fl)
{
    if (*fl) gemm_body<float>(A, (const float*)W, woff, (const float*)bias, boff,
                              Cb, Cf, M, N, K, act, mode);
    else     gemm_body<bf16>(A, (const bf16*)W, woff, (const bf16*)bias, boff,
                             Cb, Cf, M, N, K, act, mode);
}

__global__ __launch_bounds__(256) void k_gemm_qkv(
    const bf16* __restrict__ A,
    const void* qw, const void* kw, const void* vw,
    const void* qb, const void* kb, const void* vb,
    long long woff, long long boff,
    bf16* Cq, bf16* Ck, bf16* Cv, const int* __restrict__ fl)
{
    const int z = blockIdx.z;
    const void* W  = (z == 0) ? qw : (z == 1) ? kw : vw;
    const void* Bi = (z == 0) ? qb : (z == 1) ? kb : vb;
    bf16* C        = (z == 0) ? Cq : (z == 1) ? Ck : Cv;
    const int mode = (z == 0) ? 3 : (z == 2) ? 2 : 0;
    if (*fl) gemm_body<float>(A, (const float*)W, woff, (const float*)Bi, boff,
                              C, nullptr, M_, HID, HID, 0, mode);
    else     gemm_body<bf16>(A, (const bf16*)W, woff, (const bf16*)Bi, boff,
                             C, nullptr, M_, HID, HID, 0, mode);
}

// -------- prepped GEMM: W bf16 pre-transposed [n][k].
// 2-phase schedule: double-buffered LDS, global_load_lds (16B, direct-to-LDS,
// no VGPR round-trip), ONE barrier per K-tile. Rule #21 both-sides swizzle.
// bm/bn passed in so callers can apply XCD-aware block remaps (T1).
static __device__ void gemm_t_body(
    const bf16* A, const bf16* Wt, long long woff, const bf16* bias, long long boff,
    bf16* Cb, float* Cf, int M, int N, int K, int act, int mode,
    int bm, int bn)
{
    __shared__ __align__(16) unsigned short Tz[2][2][4096];   // [buf][A/W][64*64] 32KB
    const int tid  = threadIdx.x;
    const int wv   = tid >> 6, lane = tid & 63;
    const int quad = lane >> 4, c = lane & 15;
    const int wm = wv & 1, wn = wv >> 1;
    const unsigned short* Ag = (const unsigned short*)A;
    const unsigned short* Wg = (const unsigned short*)Wt + woff;
    // staging geometry: thread -> 2 rows (j=0,1), 16B each, linear LDS dest
    const int sr = tid >> 3;                       // row within 32-row half
    const int csw0 = (((tid & 7) ^ (sr & 7)) << 3);      // inverse-swizzled col (elems)
    int ar0 = bm + sr;        ar0 = ar0 < M ? ar0 : M - 1;
    int ar1 = bm + 32 + sr;   ar1 = ar1 < M ? ar1 : M - 1;
    const int wr0 = bn + sr, wr1 = bn + 32 + sr;
    const int ldso = tid * 8;                      // elems within 2048-elem half

    f32x4 acc[2][2] = {{{0.f,0.f,0.f,0.f},{0.f,0.f,0.f,0.f}},
                       {{0.f,0.f,0.f,0.f},{0.f,0.f,0.f,0.f}}};

    #define STAGE_T(buf, k0) do { \
        GLOAD16(Ag + (size_t)ar0*K + (k0) + csw0, &Tz[buf][0][ldso]); \
        GLOAD16(Ag + (size_t)ar1*K + (k0) + csw0, &Tz[buf][0][2048 + ldso]); \
        GLOAD16(Wg + (size_t)wr0*K + (k0) + csw0, &Tz[buf][1][ldso]); \
        GLOAD16(Wg + (size_t)wr1*K + (k0) + csw0, &Tz[buf][1][2048 + ldso]); \
    } while (0)

    STAGE_T(0, 0);
    __syncthreads();                               // vmcnt(0) drain + barrier
    int cur = 0;
    for (int k0 = 0; k0 < K; k0 += 64) {
        if (k0 + 64 < K) STAGE_T(cur ^ 1, k0 + 64);    // async loads for next tile
        #pragma unroll
        for (int ks = 0; ks < 2; ++ks) {
            short8 af[2], bfr[2];
            #pragma unroll
            for (int mi = 0; mi < 2; ++mi) {
                const int row = wm*32 + mi*16 + c;
                const char* p = (const char*)&Tz[cur][0][0]
                              + (row*128 + (((ks*64 + quad*16)) ^ ((row & 7) << 4)));
                af[mi] = *reinterpret_cast<const short8*>(p);
            }
            #pragma unroll
            for (int ni = 0; ni < 2; ++ni) {
                const int row = wn*32 + ni*16 + c;
                const char* p = (const char*)&Tz[cur][1][0]
                              + (row*128 + (((ks*64 + quad*16)) ^ ((row & 7) << 4)));
                bfr[ni] = *reinterpret_cast<const short8*>(p);
            }
            #pragma unroll
            for (int mi = 0; mi < 2; ++mi)
                #pragma unroll
                for (int ni = 0; ni < 2; ++ni)
                    acc[mi][ni] = __builtin_amdgcn_mfma_f32_16x16x32_bf16(
                                      af[mi], bfr[ni], acc[mi][ni], 0, 0, 0);
        }
        __syncthreads();                           // drains next-tile loads + read fence
        cur ^= 1;
    }
    #undef STAGE_T
    gemm_epilogue(acc, b2f(bias[boff + bn + wn*32 + c]),
                  b2f(bias[boff + bn + wn*32 + 16 + c]),
                  Cb, Cf, M, N, act, mode, bm, bn, wm, wn, quad, c);
}

__global__ __launch_bounds__(256) void k_gemm_t(
    const bf16* __restrict__ A, const bf16* __restrict__ Wt, long long woff,
    const bf16* __restrict__ bias, long long boff,
    bf16* Cb, float* Cf, int M, int N, int K, int act, int mode)
{
    gemm_t_body(A, Wt, woff, bias, boff, Cb, Cf, M, N, K, act, mode,
                blockIdx.x*64, blockIdx.y*64);
}

// qkv GEMM, 1D grid 1332 with XCD-aware bijective remap (T1) + M-major decode:
// each XCD gets ~167 consecutive wg = a contiguous slice of A rows (0.45MB, L2-fits)
// for ALL (n-tile, matrix) pairs; W (0.9MB/layer total) L2-fits per XCD. Without the
// remap, A row-tiles are read by 18 blocks spread over all 8 XCDs -> A fetched ~8x.
__global__ __launch_bounds__(256) void k_gemm_qkv_t(
    const bf16* __restrict__ A, const bf16* __restrict__ wbt, const bf16* __restrict__ bb,
    int lyr, bf16* Cq, bf16* Ck, bf16* Cv)
{
    const int bid = blockIdx.x;                    // 0..1331
    const int xcd = bid & 7, idx = bid >> 3;       // 1332 = 8*166 + 4
    const int wg  = (xcd < 4 ? xcd*167 : 668 + (xcd - 4)*166) + idx;
    const int bx  = wg / 18;                       // M-tile 0..73 (M-major)
    const int rem = wg - bx*18;
    const int by  = rem % 6;                       // N-tile 0..5
    const int z   = rem / 6;                       // matrix 0..2
    long long woff; long long boff; bf16* C; int mode;
    if (z == 0)      { woff = WQ_ + (long long)lyr*147456; boff = BQ_ + lyr*384; C = Cq; mode = 3; }
    else if (z == 1) { woff = WK_ + (long long)lyr*147456; boff = BK_ + lyr*384; C = Ck; mode = 0; }
    else             { woff = WV_ + (long long)lyr*147456; boff = BV_ + lyr*384; C = Cv; mode = 2; }
    gemm_t_body(A, wbt, woff, bb, boff, C, nullptr, M_, HID, HID, 0, mode,
                bx*64, by*64);
}

// m1 GEMM, 1D grid 1776 (= 8*222 exact) with XCD remap + M-major decode:
// per XCD A slice ~0.45MB + full W 1.18MB — both L2-resident.
__global__ __launch_bounds__(256) void k_gemm_t_m1(
    const bf16* __restrict__ A, const bf16* __restrict__ wbt, const bf16* __restrict__ bb,
    int lyr, bf16* __restrict__ m1f)
{
    const int bid = blockIdx.x;                    // 0..1775
    const int xcd = bid & 7, idx = bid >> 3;
    const int wg  = xcd*222 + idx;
    const int bx  = wg / 24;                       // M-tile 0..73 (M-major)
    const int by  = wg % 24;                       // N-tile 0..23
    gemm_t_body(A, wbt, WM1_ + (long long)lyr*589824, bb, BM1_ + lyr*MLPD,
                m1f, nullptr, M_, MLPD, HID, 1, 0, bx*64, by*64);
}

// -------- 32-row-tile prepped GEMM (f32 += epilogue), for grid-starved dispatches
// (O-proj, M2). 1D grid 882 with XCD remap + M-major decode: per XCD A slice
// (O: 0.45MB / M2: 1.8MB) + full W (0.3 / 1.18MB) — L2-resident; kills the ~6-8x
// A over-fetch (M2's A = 14.5MB m1f was the worst offender at ~87MB/dispatch).
__global__ __launch_bounds__(256) void k_gemm_t32(
    const bf16* __restrict__ A, const bf16* __restrict__ Wt, long long woff,
    const bf16* __restrict__ bias, long long boff,
    float* __restrict__ Cf, int M, int N, int K)
{
    __shared__ __align__(16) unsigned short Az[2][2048];   // [buf][32 rows x 64 k]
    __shared__ __align__(16) unsigned short Wz[2][4096];   // [buf][64 cols x 64 k]
    const int tid  = threadIdx.x;
    const int wv   = tid >> 6, lane = tid & 63;
    const int quad = lane >> 4, c = lane & 15;
    const int wm = wv & 1, wn = wv >> 1;
    // XCD-aware bijective remap of the 882-block 1D grid (882 = 8*110 + 2)
    const int bid = blockIdx.x;
    const int xcd = bid & 7, idx = bid >> 3;
    const int wg  = (xcd < 2 ? xcd*111 : 222 + (xcd - 2)*110) + idx;
    const int bm  = (wg / 6) * 32;                 // M-tile (M-major)
    const int bn  = (wg % 6) * 64;                 // N-tile
    const unsigned short* Ag = (const unsigned short*)A;
    const unsigned short* Wg = (const unsigned short*)Wt + woff;
    const int sr = tid >> 3;                       // 0..31
    const int csw0 = (((tid & 7) ^ (sr & 7)) << 3);
    const int ar = bm + sr;                        // 147x32 = M exactly, no clamp
    const int wr0 = bn + sr, wr1 = bn + 32 + sr;
    const int ldso = tid * 8;

    f32x4 acc[2] = {{0.f,0.f,0.f,0.f},{0.f,0.f,0.f,0.f}};

    #define STAGE_T32(buf, k0) do { \
        GLOAD16(Ag + (size_t)ar*K + (k0) + csw0, &Az[buf][ldso]); \
        GLOAD16(Wg + (size_t)wr0*K + (k0) + csw0, &Wz[buf][ldso]); \
        GLOAD16(Wg + (size_t)wr1*K + (k0) + csw0, &Wz[buf][2048 + ldso]); \
    } while (0)

    STAGE_T32(0, 0);
    __syncthreads();
    int cur = 0;
    for (int k0 = 0; k0 < K; k0 += 64) {
        if (k0 + 64 < K) STAGE_T32(cur ^ 1, k0 + 64);
        #pragma unroll
        for (int ks = 0; ks < 2; ++ks) {
            short8 af, bfr[2];
            {
                const int row = wm*16 + c;
                const char* p = (const char*)&Az[cur][0]
                              + (row*128 + ((ks*64 + quad*16) ^ ((row & 7) << 4)));
                af = *reinterpret_cast<const short8*>(p);
            }
            #pragma unroll
            for (int ni = 0; ni < 2; ++ni) {
                const int row = wn*32 + ni*16 + c;
                const char* p = (const char*)&Wz[cur][0]
                              + (row*128 + ((ks*64 + quad*16) ^ ((row & 7) << 4)));
                bfr[ni] = *reinterpret_cast<const short8*>(p);
            }
            #pragma unroll
            for (int ni = 0; ni < 2; ++ni)
                acc[ni] = __builtin_amdgcn_mfma_f32_16x16x32_bf16(af, bfr[ni], acc[ni], 0, 0, 0);
        }
        __syncthreads();
        cur ^= 1;
    }
    #undef STAGE_T32
    // epilogue: f32 += (bias included)
    #pragma unroll
    for (int ni = 0; ni < 2; ++ni) {
        const int col = bn + wn*32 + ni*16 + c;
        const float bcol = b2f(bias[boff + col]);
        #pragma unroll
        for (int r = 0; r < 4; ++r) {
            const int row = bm + wm*16 + quad*4 + r;
            Cf[(size_t)row*N + col] += acc[ni][r] + bcol;
        }
    }
}

// ---------------------------------------------------------------- MFMA flash attention
// (fallback) 64 queries/block, 8 waves, in-block split-K x2 — used when ws lacks
// room for flash-decode partials.
__global__ __launch_bounds__(512) void k_attn(
    const bf16* __restrict__ q, const bf16* __restrict__ k,
    const bf16* __restrict__ vt, bf16* __restrict__ ao)
{
    __shared__ __align__(16) unsigned short Ks[2][64][80];   // [split][key][d 0..63 +pad]
    __shared__ __align__(16) unsigned short Vt[2][48][72];   // [split][d][key 0..63 +pad]
    __shared__ __align__(16) unsigned short Pq[8][16][72];   // [wave][query][key 0..63 +pad]
    const int tid  = threadIdx.x;
    const int w    = tid >> 6, lane = tid & 63;
    const int quad = lane >> 4, c = lane & 15;
    const int qt = w & 3, sp = w >> 2;               // q-tile 0..3, split 0..1
    const int bh = blockIdx.y;                       // b*8+hh
    const size_t base  = (size_t)(bh >> 3)*L_*HID + (size_t)(bh & 7)*HD;
    const size_t vbase = (size_t)bh*48*VLP;
    const int q0 = blockIdx.x*64 + qt*16;
    const bool qvalid = q0 < L_;                     // wave-uniform
    const int qrow = qvalid ? (q0 + c) : c;

    short8 qf0, qf1;
    {
        const unsigned short* qp = (const unsigned short*)(q + base + (size_t)qrow*HID);
        qf0 = *reinterpret_cast<const short8*>(qp + quad*8);                 // d 0..31
        if (quad < 2) qf1 = *reinterpret_cast<const short8*>(qp + 32 + quad*8);  // d 32..47
        else          qf1 = short8{0,0,0,0,0,0,0,0};                         // d 48..63 pad
    }
    f32x4 o0 = {0.f,0.f,0.f,0.f}, o1 = {0.f,0.f,0.f,0.f}, o2 = {0.f,0.f,0.f,0.f};
    float m = -3.0e38f, lsum = 0.f;

    // ---- staging assignment: 256-thread group per split
    const int t256 = tid & 255, grp = tid >> 8;
    const int krow0 = t256 >> 3, kch = t256 & 7;     // K row 0..31 / ch 0..7
    const int krow1 = 32 + krow0;                    // K row 32..63
    const int vd0 = krow0;                           // V d 0..31
    const int vd1 = 32 + (krow0 & 15);               // V d 32..47 (t256<128 only)
    const bool vl1 = (t256 < 128);
    const unsigned short* kq = (const unsigned short*)(k + base);
    const unsigned short* vq = (const unsigned short*)(vt + vbase);
    const short8 Z8 = short8{0,0,0,0,0,0,0,0};
    short8 kr0 = Z8, kr1 = Z8, vr0, vr1 = Z8;
    {   // prefetch tile 0 (keys unclamped: OOB tail lands inside workspace, masked in S)
        const int kb0 = grp*1216;
        if (kch < 6) {
            kr0 = *reinterpret_cast<const short8*>(kq + (size_t)(kb0 + krow0)*HID + kch*8);
            kr1 = *reinterpret_cast<const short8*>(kq + (size_t)(kb0 + krow1)*HID + kch*8);
        }
        vr0 = *reinterpret_cast<const short8*>(vq + (size_t)vd0*VLP + kb0 + kch*8);
        if (vl1) vr1 = *reinterpret_cast<const short8*>(vq + (size_t)vd1*VLP + kb0 + kch*8);
    }

    for (int tt = 0; tt < 19; ++tt) {
        __syncthreads();                             // prev tile's LDS reads done
        *reinterpret_cast<short8*>(&Ks[grp][krow0][kch*8]) = kr0;
        *reinterpret_cast<short8*>(&Ks[grp][krow1][kch*8]) = kr1;
        *reinterpret_cast<short8*>(&Vt[grp][vd0][kch*8])   = vr0;
        if (vl1) *reinterpret_cast<short8*>(&Vt[grp][vd1][kch*8]) = vr1;
        __syncthreads();                             // this tile's LDS ready
        if (tt < 18) {                               // issue next tile's loads -> regs
            const int nb0 = grp*1216 + (tt + 1)*64;
            if (kch < 6) {
                kr0 = *reinterpret_cast<const short8*>(kq + (size_t)(nb0 + krow0)*HID + kch*8);
                kr1 = *reinterpret_cast<const short8*>(kq + (size_t)(nb0 + krow1)*HID + kch*8);
            }
            vr0 = *reinterpret_cast<const short8*>(vq + (size_t)vd0*VLP + nb0 + kch*8);
            if (vl1) vr1 = *reinterpret_cast<const short8*>(vq + (size_t)vd1*VLP + nb0 + kch*8);
        }

        const int kt = sp*1216 + tt*64;              // compute key base for this wave
        float sv[16];
        #pragma unroll
        for (int t = 0; t < 4; ++t) {
            f32x4 acc = {0.f,0.f,0.f,0.f};
            short8 a0 = *reinterpret_cast<const short8*>(&Ks[sp][t*16 + c][quad*8]);
            short8 a1 = *reinterpret_cast<const short8*>(&Ks[sp][t*16 + c][32 + quad*8]);
            acc = __builtin_amdgcn_mfma_f32_16x16x32_bf16(a0, qf0, acc, 0, 0, 0);
            acc = __builtin_amdgcn_mfma_f32_16x16x32_bf16(a1, qf1, acc, 0, 0, 0);
            #pragma unroll
            for (int r = 0; r < 4; ++r) sv[t*4 + r] = acc[r];   // already log2-scaled
        }
        if (sp == 1 && tt >= 17) {                   // tiles with keys >= L_ (2304.. / 2368..)
            #pragma unroll
            for (int t = 0; t < 4; ++t)
                #pragma unroll
                for (int r = 0; r < 4; ++r)
                    if (kt + t*16 + quad*4 + r >= L_) sv[t*4 + r] = -3.0e38f;
        }
        // tree max (depth 4, max3-fusable)
        float tmax = fmaxf(fmaxf(fmaxf(sv[0], sv[1]),  fmaxf(sv[2],  sv[3])),
                           fmaxf(fmaxf(sv[4], sv[5]),  fmaxf(sv[6],  sv[7])));
        float tmx2 = fmaxf(fmaxf(fmaxf(sv[8], sv[9]),  fmaxf(sv[10], sv[11])),
                           fmaxf(fmaxf(sv[12], sv[13]), fmaxf(sv[14], sv[15])));
        tmax = fmaxf(tmax, tmx2);
        tmax = fmaxf(tmax, __shfl_xor(tmax, 16));
        tmax = fmaxf(tmax, __shfl_xor(tmax, 32));
        if (!__all(tmax <= m + 8.0f)) {              // defer-max: rescale only on growth
            const float mn = fmaxf(m, tmax);
            const float alpha = exp2f(m - mn);
            m = mn;
            lsum *= alpha;
            o0 *= alpha; o1 *= alpha; o2 *= alpha;
        }
        float psum = 0.f;
        unsigned short pv[16];
        #pragma unroll
        for (int i = 0; i < 16; ++i) {
            const float p = exp2f(sv[i] - m);        // bounded by 2^8
            psum += p;
            pv[i] = f2us(p);
        }
        lsum += psum;
        // P row (query c) -> LDS; same-wave rw, no barrier needed
        #pragma unroll
        for (int t = 0; t < 4; ++t)
            *reinterpret_cast<ushort4*>(&Pq[w][c][t*16 + quad*4]) =
                make_ushort4(pv[t*4+0], pv[t*4+1], pv[t*4+2], pv[t*4+3]);
        // PV in 2 steps of 32 keys (b128 fragments)
        #pragma unroll
        for (int s = 0; s < 2; ++s) {
            short8 pf  = *reinterpret_cast<const short8*>(&Pq[w][c][s*32 + quad*8]);
            short8 vf0 = *reinterpret_cast<const short8*>(&Vt[sp][c][s*32 + quad*8]);
            short8 vf1 = *reinterpret_cast<const short8*>(&Vt[sp][16 + c][s*32 + quad*8]);
            short8 vf2 = *reinterpret_cast<const short8*>(&Vt[sp][32 + c][s*32 + quad*8]);
            o0 = __builtin_amdgcn_mfma_f32_16x16x32_bf16(vf0, pf, o0, 0, 0, 0);
            o1 = __builtin_amdgcn_mfma_f32_16x16x32_bf16(vf1, pf, o1, 0, 0, 0);
            o2 = __builtin_amdgcn_mfma_f32_16x16x32_bf16(vf2, pf, o2, 0, 0, 0);
        }
    }
    // ---- reduce l across quads within wave
    float lw = lsum;
    lw += __shfl_xor(lw, 16);
    lw += __shfl_xor(lw, 32);
    // ---- split merge through LDS (reuse Ks: 20480 B >= 4*64*14*4 = 14336 B; Ks dead here)
    float* Mg = (float*)&Ks[0][0][0];
    __syncthreads();
    if (sp == 1) {
        float* dst = Mg + (size_t)(qt*64 + lane)*14;
        dst[0] = o0[0]; dst[1] = o0[1]; dst[2]  = o0[2]; dst[3]  = o0[3];
        dst[4] = o1[0]; dst[5] = o1[1]; dst[6]  = o1[2]; dst[7]  = o1[3];
        dst[8] = o2[0]; dst[9] = o2[1]; dst[10] = o2[2]; dst[11] = o2[3];
        dst[12] = m; dst[13] = lw;
    }
    __syncthreads();
    if (sp == 0 && qvalid) {
        const float* src = Mg + (size_t)(qt*64 + lane)*14;
        const float m2 = src[12], l2 = src[13];
        const float mm = fmaxf(m, m2);
        const float a1 = exp2f(m - mm), a2 = exp2f(m2 - mm);
        const float inv = 1.0f / (lw*a1 + l2*a2);
        unsigned short* orow = (unsigned short*)(ao + base + (size_t)(q0 + c)*HID);
        const f32x4 ot[3] = {o0, o1, o2};
        #pragma unroll
        for (int dt = 0; dt < 3; ++dt) {
            ushort4 w4;
            w4.x = f2us((ot[dt][0]*a1 + src[dt*4+0]*a2) * inv);
            w4.y = f2us((ot[dt][1]*a1 + src[dt*4+1]*a2) * inv);
            w4.z = f2us((ot[dt][2]*a1 + src[dt*4+2]*a2) * inv);
            w4.w = f2us((ot[dt][3]*a1 + src[dt*4+3]*a2) * inv);
            *reinterpret_cast<ushort4*>(orow + dt*16 + quad*4) = w4;
        }
    }
}

// ---------------------------------------------------------------- flash-decode attention
// Key-split ACROSS blocks, XCD-aware bijective remap (T1, round 10: FETCH 34->6.7MB,
// hbm 812->255 GB/s confirmed). T5 setprio was null-to-negative (r11) — removed.
// gload_lds 2-phase double-buffer staging (rule #21 swizzle), raw v_exp_f32,
// truncation-packed bf16 P, max3-fusable reduce. K d-pad cols pre-zeroed.
__global__ __launch_bounds__(256) void k_attn_fd(
    const bf16* __restrict__ q, const bf16* __restrict__ k,
    const bf16* __restrict__ vt, bf16* __restrict__ pob, float* __restrict__ pml)
{
    __shared__ __align__(16) unsigned short Kz[2][4096];  // [buf][64 key x 64 d] swizzled
    __shared__ __align__(16) unsigned short Vz[2][3072];  // [buf][48 d x 64 key] swizzled
    __shared__ __align__(16) unsigned short Pq[4][16][72];
    const int tid  = threadIdx.x;
    const int w    = tid >> 6, lane = tid & 63;
    const int quad = lane >> 4, c = lane & 15;
    // XCD-aware decomposition of the 1184-block 1D grid
    const int bid  = blockIdx.x;
    const int wg   = (bid & 7)*148 + (bid >> 3);     // bijective: 148 blocks per XCD
    const int g    = wg / 37;                        // (bh,half) group 0..31
    const int qblk = wg - g*37;
    const int bh   = g >> 1;
    const int half = g & 1;
    const size_t base  = (size_t)(bh >> 3)*L_*HID + (size_t)(bh & 7)*HD;
    const size_t vbase = (size_t)bh*48*VLP;
    const int q0 = qblk*64 + w*16;
    const bool qvalid = q0 < L_;                     // wave-uniform
    const int qrow = qvalid ? (q0 + c) : c;

    short8 qf0, qf1;
    {
        const unsigned short* qp = (const unsigned short*)(q + base + (size_t)qrow*HID);
        qf0 = *reinterpret_cast<const short8*>(qp + quad*8);                 // d 0..31
        if (quad < 2) qf1 = *reinterpret_cast<const short8*>(qp + 32 + quad*8);  // d 32..47
        else          qf1 = short8{0,0,0,0,0,0,0,0};                         // d 48..63 pad
    }
    f32x4 o0 = {0.f,0.f,0.f,0.f}, o1 = {0.f,0.f,0.f,0.f}, o2 = {0.f,0.f,0.f,0.f};
    float m = -3.0e38f, lsum = 0.f;

    // staging geometry: per thread 2 K-slots + 1-2 V-slots, all linear (tid*16B) dests
    const int srow = tid >> 3;                       // 0..31
    const int sc   = (tid & 7) ^ (srow & 7);         // inverse-swizzled slot
    const int scol = sc << 3;                        // global col (elems)
    const bool kld = (sc < 6);                       // K cols 48..63 never loaded
    const int ldo  = tid * 8;                        // linear LDS dest (elems)
    const unsigned short* kq = (const unsigned short*)(k + base);
    const unsigned short* vq = (const unsigned short*)(vt + vbase);
    const int kbase = half*1216;

    #define STAGE_FD(buf, kb) do { \
        if (kld) { \
            GLOAD16(kq + (size_t)((kb) + srow)*HID + scol,      &Kz[buf][ldo]); \
            GLOAD16(kq + (size_t)((kb) + 32 + srow)*HID + scol, &Kz[buf][2048 + ldo]); \
        } \
        GLOAD16(vq + (size_t)srow*VLP + (kb) + scol, &Vz[buf][ldo]); \
        if (tid < 128) \
            GLOAD16(vq + (size_t)(32 + srow)*VLP + (kb) + scol, &Vz[buf][2048 + ldo]); \
    } while (0)

    {   // pre-zero K d-pad slots (cols 48..63) in both buffers — never loaded
        const short8 Z8 = short8{0,0,0,0,0,0,0,0};
        if (tid < 128) {
            const int r = tid >> 1, j = tid & 1;
            const int s = (6 + j) ^ (r & 7);
            *reinterpret_cast<short8*>(&Kz[0][r*64 + s*8]) = Z8;
            *reinterpret_cast<short8*>(&Kz[1][r*64 + s*8]) = Z8;
        }
    }
    STAGE_FD(0, kbase);
    __syncthreads();                                 // vmcnt drain + barrier
    int cur = 0;

    for (int tt = 0; tt < 19; ++tt) {
        if (tt < 18) STAGE_FD(cur ^ 1, kbase + (tt + 1)*64);   // async next-tile loads

        const int kt = kbase + tt*64;
        const char* kzb = (const char*)&Kz[cur][0];
        const char* vzb = (const char*)&Vz[cur][0];
        const int qx = quad << 4;                    // colbyte of this quad's 16B
        float sv[16];
        #pragma unroll
        for (int t = 0; t < 4; ++t) {
            const int kr = t*16 + c;
            const int rx = kr*128;
            const int x0 = qx ^ ((kr & 7) << 4);
            f32x4 acc = {0.f,0.f,0.f,0.f};
            short8 a0 = *reinterpret_cast<const short8*>(kzb + rx + x0);
            short8 a1 = *reinterpret_cast<const short8*>(kzb + rx + (x0 ^ 64));
            acc = __builtin_amdgcn_mfma_f32_16x16x32_bf16(a0, qf0, acc, 0, 0, 0);
            acc = __builtin_amdgcn_mfma_f32_16x16x32_bf16(a1, qf1, acc, 0, 0, 0);
            #pragma unroll
            for (int r = 0; r < 4; ++r) sv[t*4 + r] = acc[r];   // already log2-scaled
        }
        if (half == 1 && tt >= 17) {                 // keys >= L_ (2304.. / 2368..)
            #pragma unroll
            for (int t = 0; t < 4; ++t)
                #pragma unroll
                for (int r = 0; r < 4; ++r)
                    if (kt + t*16 + quad*4 + r >= L_) sv[t*4 + r] = -3.0e38f;
        }
        // tree max: two max3-fusable chains + combine
        float h0 = fmaxf(fmaxf(sv[0], sv[1]), sv[2]);
        h0 = fmaxf(fmaxf(h0, sv[3]), sv[4]);
        h0 = fmaxf(fmaxf(h0, sv[5]), sv[6]);
        h0 = fmaxf(h0, sv[7]);
        float h1 = fmaxf(fmaxf(sv[8], sv[9]), sv[10]);
        h1 = fmaxf(fmaxf(h1, sv[11]), sv[12]);
        h1 = fmaxf(fmaxf(h1, sv[13]), sv[14]);
        h1 = fmaxf(h1, sv[15]);
        float tmax = fmaxf(h0, h1);
        tmax = fmaxf(tmax, __shfl_xor(tmax, 16));
        tmax = fmaxf(tmax, __shfl_xor(tmax, 32));
        if (!__all(tmax <= m + 8.0f)) {              // defer-max
            const float mn = fmaxf(m, tmax);
            const float alpha = exp2_raw(m - mn);
            m = mn;
            lsum *= alpha;
            o0 *= alpha; o1 *= alpha; o2 *= alpha;
        }
        // P = exp2(S - m), truncation-packed to bf16 pairs
        float psum = 0.f;
        unsigned pk[8];
        #pragma unroll
        for (int i = 0; i < 8; ++i) {
            const float p0 = exp2_raw(sv[2*i]     - m);   // bounded by 2^8
            const float p1 = exp2_raw(sv[2*i + 1] - m);
            psum += p0 + p1;
            pk[i] = (__float_as_uint(p0) >> 16) | (__float_as_uint(p1) & 0xFFFF0000u);
        }
        lsum += psum;
        // P row (query c) -> LDS as b64 pairs; same-wave rw, no barrier needed
        #pragma unroll
        for (int t = 0; t < 4; ++t)
            *reinterpret_cast<uint2*>(&Pq[w][c][t*16 + quad*4]) =
                make_uint2(pk[2*t], pk[2*t + 1]);
        // PV in 2 steps of 32 keys (b128 fragments, swizzled V reads)
        const int mx = (c & 7) << 4;
        #pragma unroll
        for (int s = 0; s < 2; ++s) {
            const int va = ((s << 6) | qx) ^ mx;
            short8 pf  = *reinterpret_cast<const short8*>(&Pq[w][c][s*32 + quad*8]);
            short8 vf0 = *reinterpret_cast<const short8*>(vzb + c*128 + va);
            short8 vf1 = *reinterpret_cast<const short8*>(vzb + (16 + c)*128 + va);
            short8 vf2 = *reinterpret_cast<const short8*>(vzb + (32 + c)*128 + va);
            o0 = __builtin_amdgcn_mfma_f32_16x16x32_bf16(vf0, pf, o0, 0, 0, 0);
            o1 = __builtin_amdgcn_mfma_f32_16x16x32_bf16(vf1, pf, o1, 0, 0, 0);
            o2 = __builtin_amdgcn_mfma_f32_16x16x32_bf16(vf2, pf, o2, 0, 0, 0);
        }
        __syncthreads();                             // drains next-tile loads + read fence
        cur ^= 1;
    }
    #undef STAGE_FD
    // reduce l across quads, normalize, store partials
    float lw = lsum;
    lw += __shfl_xor(lw, 16);
    lw += __shfl_xor(lw, 32);
    const float invl = 1.0f / lw;
    const size_t ro = ((size_t)bh*2368 + q0 + c)*2 + half;
    unsigned short* pr = (unsigned short*)pob + ro*48;
    const f32x4 ot[3] = {o0, o1, o2};
    #pragma unroll
    for (int dt = 0; dt < 3; ++dt) {
        ushort4 w4;
        w4.x = f2us(ot[dt][0]*invl);
        w4.y = f2us(ot[dt][1]*invl);
        w4.z = f2us(ot[dt][2]*invl);
        w4.w = f2us(ot[dt][3]*invl);
        *reinterpret_cast<ushort4*>(pr + dt*16 + quad*4) = w4;
    }
    if (quad == 0) { pml[ro*2 + 0] = m; pml[ro*2 + 1] = lw; }
}

// merge the two key-halves: out = (o1*l1*a1 + o2*l2*a2) / (l1*a1 + l2*a2)
__global__ __launch_bounds__(256) void k_amerge(
    const bf16* __restrict__ pob, const float* __restrict__ pml, bf16* __restrict__ ao)
{
    const int tid = threadIdx.x;
    const int bh = blockIdx.y;
    const int qq = blockIdx.x*16 + (tid >> 4);       // 0..2351
    const int j = tid & 15;
    const size_t ro = ((size_t)bh*2368 + qq)*2;
    const float m1 = pml[ro*2 + 0], l1 = pml[ro*2 + 1];
    const float m2 = pml[ro*2 + 2], l2 = pml[ro*2 + 3];
    const float mm = fmaxf(m1, m2);
    const float b1 = exp2f(m1 - mm)*l1, b2 = exp2f(m2 - mm)*l2;
    const float inv = 1.0f / (b1 + b2);
    const float w1 = b1*inv, w2 = b2*inv;
    if (j < 12) {
        const unsigned short* p1 = (const unsigned short*)pob + ro*48 + j*4;
        ushort4 u1 = *reinterpret_cast<const ushort4*>(p1);
        ushort4 u2 = *reinterpret_cast<const ushort4*>(p1 + 48);
        ushort4 o4;
        o4.x = f2us(us2f(u1.x)*w1 + us2f(u2.x)*w2);
        o4.y = f2us(us2f(u1.y)*w1 + us2f(u2.y)*w2);
        o4.z = f2us(us2f(u1.z)*w1 + us2f(u2.z)*w2);
        o4.w = f2us(us2f(u1.w)*w1 + us2f(u2.w)*w2);
        const size_t base = (size_t)(bh >> 3)*L_*HID + (size_t)(bh & 7)*HD;
        *reinterpret_cast<ushort4*>((unsigned short*)ao + base + (size_t)qq*HID + j*4) = o4;
    }
}

// ------------------------------------------------------- final LN + heads
template <typename T, typename TO>
static __device__ void final_body(
    const float* h, const T* fn_g, const T* fn_b,
    const T* on_w, const T* on_b, const T* oe_w, const T* oe_b, TO* out)
{
    __shared__ float hf[HID];
    const int row = blockIdx.x;
    const int b = row / L_, l = row % L_;
    const int lane = threadIdx.x;
    const float* hr = h + (size_t)row*HID;
    float v[6]; float s = 0.f, ss = 0.f;
    #pragma unroll
    for (int j = 0; j < 6; ++j) { float t = hr[lane + j*64]; v[j] = t; s += t; ss += t*t; }
    #pragma unroll
    for (int off = 32; off; off >>= 1) { s += __shfl_xor(s, off); ss += __shfl_xor(ss, off); }
    const float mu = s * (1.0f/HID);
    const float rs = rsqrtf(fmaxf(ss * (1.0f/HID) - mu*mu, 0.0f) + 1e-5f);
    #pragma unroll
    for (int j = 0; j < 6; ++j) {
        int c = lane + j*64;
        hf[c] = (v[j] - mu) * rs * ldv(fn_g, c) + ldv(fn_b, c);
    }
    __syncthreads();
    if (l < N_) {
        if (lane < A_) {
            float acc = ldv(on_b, lane);
            for (int c = 0; c < HID; ++c) acc += hf[c] * ldv(on_w, (size_t)c*A_ + lane);
            stv(out, (size_t)(b*N_ + l)*A_ + lane, acc);
        }
    } else {
        const int e = l - N_;
        if (lane < E_) {
            float acc = ldv(oe_b, lane);
            for (int c = 0; c < HID; ++c) acc += hf[c] * ldv(oe_w, (size_t)c*E_ + lane);
            stv(out, (size_t)B_*N_*A_ + ((size_t)b*N_*N_ + e)*E_ + lane, acc);
        }
    }
}

__global__ __launch_bounds__(64) void k_final(
    const float* __restrict__ h, const void* fn_g, const void* fn_b,
    const void* on_w, const void* on_b, const void* oe_w, const void* oe_b,
    const int* __restrict__ fl, void* out)
{
    if (*fl) final_body<float, float>(h, (const float*)fn_g, (const float*)fn_b,
                                      (const float*)on_w, (const float*)on_b,
                                      (const float*)oe_w, (const float*)oe_b, (float*)out);
    else     final_body<bf16, bf16>(h, (const bf16*)fn_g, (const bf16*)fn_b,
                                    (const bf16*)on_w, (const bf16*)on_b,
                                    (const bf16*)oe_w, (const bf16*)oe_b, (bf16*)out);
}

// ---------------------------------------------------------------- launch
extern "C" void kernel_launch(void* const* d_in, const int* in_sizes, int n_in,
                              void* d_out, int out_size, void* d_ws, size_t ws_size,
                              hipStream_t stream) {
    const void* x      = d_in[0];
    const void* adj    = d_in[1];
    const void* t      = d_in[2];
    const void* node_w = d_in[3];
    const void* node_b = d_in[4];
    const void* edge_w = d_in[5];
    const void* edge_b = d_in[6];
    const void* pos    = d_in[7];
    const void* t_w1   = d_in[8];
    const void* t_b1   = d_in[9];
    const void* t_w2   = d_in[10];
    const void* t_b2   = d_in[11];
    const void* ada1_w = d_in[12];
    const void* ada1_b = d_in[13];
    const void* ada2_w = d_in[14];
    const void* ada2_b = d_in[15];
    const void* q_w    = d_in[16];
    const void* q_b    = d_in[17];
    const void* k_w    = d_in[18];
    const void* k_b    = d_in[19];
    const void* v_w    = d_in[20];
    const void* v_b    = d_in[21];
    const void* o_w    = d_in[22];
    const void* o_b    = d_in[23];
    const void* m1_w   = d_in[24];
    const void* m1_b   = d_in[25];
    const void* m2_w   = d_in[26];
    const void* m2_b   = d_in[27];
    const void* fn_g   = d_in[28];
    const void* fn_b   = d_in[29];
    const void* on_w   = d_in[30];
    const void* on_b   = d_in[31];
    const void* oe_w   = d_in[32];
    const void* oe_b   = d_in[33];

    const size_t SZ  = (size_t)M_ * HID;          // 1,806,336 elements
    const size_t VTZ = (size_t)B_*NHD*HD*VLP;     // 1,867,776 elements (padded V^T)
    const size_t FLT = SZ + 12288 + (size_t)B_*4*HID + (size_t)B_*12*HID;  // 1,830,912
    const size_t M1FULL = (size_t)M_ * MLPD;      // 7,225,344
    const size_t BF_BASE = 3*SZ + VTZ;            // nb..vtb end = 7,286,784
    const size_t BF_BIG  = SZ + M1FULL;           // nb + m1f(from qb) end = 9,031,680
    const size_t NEED      = 256 + sizeof(float)*FLT + sizeof(bf16)*BF_BASE;   // ~21.9 MB
    const size_t NEED_BIG  = 256 + sizeof(float)*FLT + sizeof(bf16)*BF_BIG;    // ~25.4 MB
    const size_t NEED_PREP = 256 + sizeof(float)*FLT
                           + sizeof(bf16)*(BF_BIG + WTOT + BTOT);              // ~39.6 MB
    const size_t NEED_FD   = NEED_PREP + sizeof(bf16)*PO_E + sizeof(float)*PML_E; // ~47.5 MB
    if (ws_size < NEED) {
        hipMemsetAsync(d_out, 0, (size_t)out_size*sizeof(bf16), stream);  // 1.14 signature
        return;
    }
    const bool big  = (ws_size >= NEED_BIG);
    const bool prep = (ws_size >= NEED_PREP);
    const bool fd   = (ws_size >= NEED_FD);
    int*   fl   = (int*)d_ws;
    float* h    = (float*)((char*)d_ws + 256);
    float* ada  = h + SZ;                  // [8][B_][768]
    float* hid  = ada + 12288;             // [B_][1536]
    float* part = hid + (size_t)B_*4*HID;  // [B_][12][384] cond partials
    bf16* nb  = (bf16*)(part + (size_t)B_*12*HID);
    bf16* qb  = nb + SZ;
    bf16* kb  = qb + SZ;
    bf16* vtb = kb + SZ;                   // transposed V, [bh*48+d][VLP]
    bf16* m1c = kb;                        // chunked m1: [2352,1536] spans kb+vtb
    bf16* m1f = qb;                        // full m1: [M_,1536] spans qb..vtb+tail
    bf16* wbt = nb + BF_BIG;               // prepped weights (bf16, [n][k])
    bf16* bb  = wbt + WTOT;                // prepped biases
    bf16* pob = bb + BTOT;                 // flash-decode partial o (normalized)
    float* pml = (float*)(pob + PO_E);     // flash-decode partial (m, l)

    k_detect<<<1, 64, 0, stream>>>(node_w, fl);
    if (prep) {
        k_prepw<<<dim3(144, 24), 256, 0, stream>>>(q_w, k_w, v_w, o_w, m1_w, m2_w, fl, wbt);
        k_prepb<<<1, 256, 0, stream>>>(q_b, k_b, v_b, o_b, m1_b, m2_b, fl, bb);
    }
    k_embed<<<M_, HID, 0, stream>>>(x, adj, node_w, node_b, edge_w, edge_b, pos, fl, h);
    k_cond1<<<dim3(B_, 24), 256, 0, stream>>>(t, t_w1, t_b1, fl, hid);
    k_cond2<<<dim3(B_, 12), 384, 0, stream>>>(t_w2, t_b2, fl, hid, part);
    k_cond3<<<dim3(24, B_), 256, 0, stream>>>(ada1_w, ada1_b, ada2_w, ada2_b, fl, part, ada);
    for (int i = 0; i < LYR; ++i) {
        const long long woff   = (long long)i * HID * HID;
        const long long boff   = (long long)i * HID;
        const long long m1woff = (long long)i * HID * MLPD;
        const long long m1boff = (long long)i * MLPD;
        const long long m2woff = (long long)i * MLPD * HID;

        k_adaln<<<M_/4, 256, 0, stream>>>(h, ada, nb, 2*i);
        if (prep) {
            k_gemm_qkv_t<<<1332, 256, 0, stream>>>(nb, wbt, bb, i, qb, kb, vtb);
            if (fd) {
                k_attn_fd<<<1184, 256, 0, stream>>>(qb, kb, vtb, pob, pml);
                k_amerge<<<dim3(147, 16), 256, 0, stream>>>(pob, pml, nb);   // ao -> nb
            } else {
                k_attn<<<dim3(37, B_*NHD), 512, 0, stream>>>(qb, kb, vtb, nb);
            }
            k_gemm_t32<<<882, 256, 0, stream>>>(nb, wbt, WO_ + (long long)i*147456,
                                                bb, BO_ + i*384,
                                                h, M_, HID, HID);
            k_adaln<<<M_/4, 256, 0, stream>>>(h, ada, nb, 2*i + 1);          // n2 -> nb
            k_gemm_t_m1<<<1776, 256, 0, stream>>>(nb, wbt, bb, i, m1f);
            k_gemm_t32<<<882, 256, 0, stream>>>(m1f, wbt, WM2_ + (long long)i*589824,
                                                bb, BM2_ + i*384,
                                                h, M_, HID, MLPD);
        } else {
            k_gemm_qkv<<<dim3(74, 6, 3), 256, 0, stream>>>(nb, q_w, k_w, v_w, q_b, k_b, v_b,
                                                           woff, boff, qb, kb, vtb, fl);
            k_attn<<<dim3(37, B_*NHD), 512, 0, stream>>>(qb, kb, vtb, nb);   // ao -> nb
            k_gemm<<<dim3(74, 6), 256, 0, stream>>>(nb, o_w, woff, o_b, boff,
                                                    nullptr, h, M_, HID, HID, 0, 1, fl);
            k_adaln<<<M_/4, 256, 0, stream>>>(h, ada, nb, 2*i + 1);          // n2 -> nb
            if (big) {
                k_gemm<<<dim3(74, 24), 256, 0, stream>>>(nb, m1_w, m1woff, m1_b, m1boff,
                                                         m1f, nullptr, M_, MLPD, HID, 1, 0, fl);
                k_gemm<<<dim3(74, 6), 256, 0, stream>>>(m1f, m2_w, m2woff, m2_b, boff,
                                                        nullptr, h, M_, HID, MLPD, 0, 1, fl);
            } else {
                for (int c = 0; c < 2; ++c) {
                    k_gemm<<<dim3(37, 24), 256, 0, stream>>>(nb + (size_t)c*2352*HID,
                                                             m1_w, m1woff, m1_b, m1boff,
                                                             m1c, nullptr, 2352, MLPD, HID, 1, 0, fl);
                    k_gemm<<<dim3(37, 6), 256, 0, stream>>>(m1c, m2_w, m2woff, m2_b, boff,
                                                            nullptr, h + (size_t)c*2352*HID,
                                                            2352, HID, MLPD, 0, 1, fl);
                }
            }
        }
    }
    k_final<<<M_, 64, 0, stream>>>(h, fn_g, fn_b, on_w, on_b, oe_w, oe_b, fl, (void*)d_out);
}

// Round 14
// 704.412 us; speedup vs baseline: 1.0908x; 1.0091x over previous
//
#include <hip/hip_runtime.h>
#include <hip/hip_bf16.h>
#include <math.h>

typedef __hip_bfloat16 bf16;
typedef __attribute__((ext_vector_type(8))) short short8;   // 8 bf16 in 4 VGPRs
typedef __attribute__((ext_vector_type(4))) float f32x4;

#define B_ 2
#define N_ 48
#define A_ 16
#define E_ 5
#define HID 384
#define NHD 8
#define HD 48
#define LYR 4
#define MLPD 1536
#define L_ 2352      // N_ + N_*N_
#define M_ 4704      // B_*L_
#define VLP 2432     // padded key stride of transposed-V buffer
// 1/sqrt(48) * log2(e): Q pre-scale so softmax runs in log2 domain (exp2f)
#define QSCALE 0.20823513f

// prepped-weight element offsets (bf16, transposed [n][k] per matrix)
#define WQ_  0LL
#define WK_  589824LL
#define WV_  1179648LL
#define WO_  1769472LL
#define WM1_ 2359296LL
#define WM2_ 4718592LL
#define WTOT 7077888
// prepped-bias offsets
#define BQ_  0
#define BK_  1536
#define BV_  3072
#define BO_  4608
#define BM1_ 6144
#define BM2_ 12288
#define BTOT 13824

// flash-decode partials: [16 bh][2368 q][2 half] — o normalized (48 bf16) + (m,l) f32
#define PO_E  ((size_t)16*2368*2*48)   // bf16 elems
#define PML_E ((size_t)16*2368*2*2)    // f32 elems

// async global->LDS 16B direct copy (gfx950); LDS dest must be linear per-lane
#define GLOAD16(gp, lp) __builtin_amdgcn_global_load_lds( \
    (const __attribute__((address_space(1))) unsigned int*)(gp), \
    (__attribute__((address_space(3))) unsigned int*)(lp), 16, 0, 0)

static __device__ __forceinline__ float b2f(bf16 v) { return __bfloat162float(v); }
static __device__ __forceinline__ float us2f(unsigned short u) {
    return __uint_as_float(((unsigned)u) << 16);
}
static __device__ __forceinline__ unsigned short f2us(float f) {
    bf16 h = __float2bfloat16(f);
    return *reinterpret_cast<unsigned short*>(&h);
}
// raw v_exp_f32: 1 inst vs libm exp2f's denorm-fixup sequence; inputs <= 0,
// HW flush-to-zero on underflow is exactly softmax semantics.
static __device__ __forceinline__ float exp2_raw(float x) {
    float r;
    asm("v_exp_f32 %0, %1" : "=v"(r) : "v"(x));
    return r;
}
static __device__ __forceinline__ float ldv(const float* p, size_t i) { return p[i]; }
static __device__ __forceinline__ float ldv(const bf16*  p, size_t i) { return b2f(p[i]); }
static __device__ __forceinline__ void  stv(float* p, size_t i, float v) { p[i] = v; }
static __device__ __forceinline__ void  stv(bf16*  p, size_t i, float v) { p[i] = __float2bfloat16(v); }
static __device__ __forceinline__ float4 ld4(const float* p, size_t i) {
    return *reinterpret_cast<const float4*>(p + i);
}
static __device__ __forceinline__ float4 ld4(const bf16* p, size_t i) {
    ushort4 u = *reinterpret_cast<const ushort4*>(p + i);
    return make_float4(us2f(u.x), us2f(u.y), us2f(u.z), us2f(u.w));
}

// ------------------------------------------------ dtype detect (flag: 1=fp32, 0=bf16)
__global__ void k_detect(const void* w, int* flag) {
    if (threadIdx.x == 0 && blockIdx.x == 0) {
        const bf16* p = (const bf16*)w;   // node_w: 6144 elems of 0.02*normal
        int isf = 0;
        for (int i = 0; i < 256; ++i) {
            float v = fabsf(b2f(p[i]));
            if (!(v <= 1000.0f)) { isf = 1; break; }
        }
        *flag = isf;
    }
}

// ------------------------------------- weight prep: convert + transpose to [n][k] bf16
template <typename T>
static __device__ void prepw_body(
    const T* q_w, const T* k_w, const T* v_w, const T* o_w,
    const T* m1_w, const T* m2_w, bf16* wbt)
{
    __shared__ unsigned short Ts[64][72];
    const int z = blockIdx.y;
    const int kind = z >> 2, l = z & 3;
    const T* src; int K, N; long long dbase;
    switch (kind) {
        case 0: src = q_w;  K = 384;  N = 384;  dbase = WQ_;  break;
        case 1: src = k_w;  K = 384;  N = 384;  dbase = WK_;  break;
        case 2: src = v_w;  K = 384;  N = 384;  dbase = WV_;  break;
        case 3: src = o_w;  K = 384;  N = 384;  dbase = WO_;  break;
        case 4: src = m1_w; K = 384;  N = 1536; dbase = WM1_; break;
        default: src = m2_w; K = 1536; N = 384; dbase = WM2_; break;
    }
    const int Nt = N >> 6;
    const int tiles = (K >> 6) * Nt;
    if (blockIdx.x >= tiles) return;
    const int tk = blockIdx.x / Nt, tn = blockIdx.x % Nt;
    const int k0 = tk*64, n0 = tn*64;
    const size_t soff = (size_t)l * K * N;
    const size_t doff = (size_t)dbase + (size_t)l * K * N;
    const int tid = threadIdx.x;
    {   // load 64x64 fp tile -> bf16 LDS
        const int kk = tid >> 2, nc = (tid & 3) * 16;
        #pragma unroll
        for (int j = 0; j < 16; ++j)
            Ts[kk][nc + j] = f2us(ldv(src, soff + (size_t)(k0 + kk)*N + n0 + nc + j));
    }
    __syncthreads();
    {   // store transposed [n][k] with b128 writes
        const int nn = tid >> 2, kc = (tid & 3) * 16;
        unsigned short tmp[16];
        #pragma unroll
        for (int j = 0; j < 16; ++j) tmp[j] = Ts[kc + j][nn];
        unsigned short* dst = (unsigned short*)wbt + doff + (size_t)(n0 + nn)*K + k0 + kc;
        *reinterpret_cast<short8*>(dst)     = *reinterpret_cast<short8*>(&tmp[0]);
        *reinterpret_cast<short8*>(dst + 8) = *reinterpret_cast<short8*>(&tmp[8]);
    }
}

__global__ __launch_bounds__(256) void k_prepw(
    const void* q_w, const void* k_w, const void* v_w, const void* o_w,
    const void* m1_w, const void* m2_w, const int* __restrict__ fl, bf16* __restrict__ wbt)
{
    if (*fl) prepw_body<float>((const float*)q_w, (const float*)k_w, (const float*)v_w,
                               (const float*)o_w, (const float*)m1_w, (const float*)m2_w, wbt);
    else     prepw_body<bf16>((const bf16*)q_w, (const bf16*)k_w, (const bf16*)v_w,
                              (const bf16*)o_w, (const bf16*)m1_w, (const bf16*)m2_w, wbt);
}

template <typename T>
static __device__ void prepb_body(
    const T* q_b, const T* k_b, const T* v_b, const T* o_b,
    const T* m1_b, const T* m2_b, bf16* bb)
{
    for (int i = threadIdx.x; i < BTOT; i += 256) {
        float v;
        if      (i < BK_)  v = ldv(q_b,  i);
        else if (i < BV_)  v = ldv(k_b,  i - BK_);
        else if (i < BO_)  v = ldv(v_b,  i - BV_);
        else if (i < BM1_) v = ldv(o_b,  i - BO_);
        else if (i < BM2_) v = ldv(m1_b, i - BM1_);
        else               v = ldv(m2_b, i - BM2_);
        bb[i] = __float2bfloat16(v);
    }
}

__global__ __launch_bounds__(256) void k_prepb(
    const void* q_b, const void* k_b, const void* v_b, const void* o_b,
    const void* m1_b, const void* m2_b, const int* __restrict__ fl, bf16* __restrict__ bb)
{
    if (*fl) prepb_body<float>((const float*)q_b, (const float*)k_b, (const float*)v_b,
                               (const float*)o_b, (const float*)m1_b, (const float*)m2_b, bb);
    else     prepb_body<bf16>((const bf16*)q_b, (const bf16*)k_b, (const bf16*)v_b,
                              (const bf16*)o_b, (const bf16*)m1_b, (const bf16*)m2_b, bb);
}

// ---------------------------------------------------------------- embed (-> f32 h)
template <typename T>
static __device__ void embed_body(
    const T* x, const T* adj, const T* node_w, const T* node_b,
    const T* edge_w, const T* edge_b, const T* pos, float* h)
{
    const int bl = blockIdx.x;
    const int b = bl / L_, l = bl % L_;
    const int c = threadIdx.x;          // 0..383
    float acc;
    if (l < N_) {
        acc = ldv(node_b, c);
        const size_t xr = (size_t)(b*N_ + l)*A_;
        #pragma unroll
        for (int a = 0; a < A_; ++a) acc += ldv(x, xr + a) * ldv(node_w, (size_t)a*HID + c);
    } else {
        const int e = l - N_;
        acc = ldv(edge_b, c);
        const size_t ar = ((size_t)b*N_*N_ + e)*E_;
        #pragma unroll
        for (int j = 0; j < E_; ++j) acc += ldv(adj, ar + j) * ldv(edge_w, (size_t)j*HID + c);
    }
    h[(size_t)bl*HID + c] = acc + ldv(pos, (size_t)l*HID + c);
}

__global__ __launch_bounds__(384) void k_embed(
    const void* x, const void* adj, const void* node_w, const void* node_b,
    const void* edge_w, const void* edge_b, const void* pos,
    const int* __restrict__ fl, float* __restrict__ h)
{
    if (*fl) embed_body<float>((const float*)x, (const float*)adj, (const float*)node_w,
                               (const float*)node_b, (const float*)edge_w, (const float*)edge_b,
                               (const float*)pos, h);
    else     embed_body<bf16>((const bf16*)x, (const bf16*)adj, (const bf16*)node_w,
                              (const bf16*)node_b, (const bf16*)edge_w, (const bf16*)edge_b,
                              (const bf16*)pos, h);
}

// ---------------------------------------- cond stage 1: temb -> hidden (SiLU)
template <typename T>
static __device__ void cond1_body(const T* t, const T* t_w1, const T* t_b1, float* hid)
{
    __shared__ float temb[HID];
    __shared__ float red[4][64];
    const int b = blockIdx.x, jb = blockIdx.y, tid = threadIdx.x;
    const float tv = ldv(t, b);
    for (int c = tid; c < HID; c += 256) {
        int i = (c < 192) ? c : c - 192;
        float f = expf(-9.2103403719761836f * (float)i / 192.0f);
        float ang = tv * f;
        temb[c] = (c < 192) ? sinf(ang) : cosf(ang);
    }
    __syncthreads();
    const int ko = tid >> 6, jo = tid & 63;
    const int j = jb*64 + jo;
    float acc = 0.f;
    for (int i = ko*96; i < (ko + 1)*96; ++i)
        acc += temb[i] * ldv(t_w1, (size_t)i*4*HID + j);
    red[ko][jo] = acc;
    __syncthreads();
    if (ko == 0) {
        float a = red[0][jo] + red[1][jo] + red[2][jo] + red[3][jo] + ldv(t_b1, j);
        hid[(size_t)b*4*HID + j] = a / (1.0f + expf(-a));   // SiLU
    }
}

__global__ __launch_bounds__(256) void k_cond1(
    const void* t, const void* t_w1, const void* t_b1,
    const int* __restrict__ fl, float* __restrict__ hid)
{
    if (*fl) cond1_body<float>((const float*)t, (const float*)t_w1, (const float*)t_b1, hid);
    else     cond1_body<bf16>((const bf16*)t, (const bf16*)t_w1, (const bf16*)t_b1, hid);
}

// ---------------------------------------- cond stage 2: hidden -> partial cond sums
template <typename T>
static __device__ void cond2_body(const T* t_w2, const T* t_b2, const float* hid, float* part)
{
    __shared__ float hs[128];
    const int b = blockIdx.x, ch = blockIdx.y, c = threadIdx.x;
    const int j0 = ch*128;
    if (c < 128) hs[c] = hid[(size_t)b*4*HID + j0 + c];
    __syncthreads();
    float acc = (ch == 0) ? ldv(t_b2, c) : 0.f;
    for (int jj = 0; jj < 128; ++jj)
        acc += hs[jj] * ldv(t_w2, (size_t)(j0 + jj)*HID + c);
    part[((size_t)b*12 + ch)*HID + c] = acc;
}

__global__ __launch_bounds__(384) void k_cond2(
    const void* t_w2, const void* t_b2, const int* __restrict__ fl,
    const float* __restrict__ hid, float* __restrict__ part)
{
    if (*fl) cond2_body<float>((const float*)t_w2, (const float*)t_b2, hid, part);
    else     cond2_body<bf16>((const bf16*)t_w2, (const bf16*)t_b2, hid, part);
}

// ---------------------------------------- cond stage 3: ada projections
template <typename T>
static __device__ void cond3_body(
    const T* ada1_w, const T* ada1_b, const T* ada2_w, const T* ada2_b,
    const float* part, float* ada_out)
{
    __shared__ float cs[HID];
    const int slot = blockIdx.x / 3, ob = blockIdx.x % 3, b = blockIdx.y;
    const int tid = threadIdx.x;
    for (int c = tid; c < HID; c += 256) {
        float s = 0.f;
        #pragma unroll
        for (int ch = 0; ch < 12; ++ch) s += part[((size_t)b*12 + ch)*HID + c];
        cs[c] = s;
    }
    __syncthreads();
    const int layer = slot >> 1, which = slot & 1;
    const int o = ob*256 + tid;
    const T* W  = which ? ada2_w : ada1_w;
    const T* Bi = which ? ada2_b : ada1_b;
    float acc = ldv(Bi, (size_t)layer*768 + o);
    const size_t wb = (size_t)layer*HID*768 + o;
    for (int c = 0; c < HID; ++c) acc += cs[c] * ldv(W, wb + (size_t)c*768);
    ada_out[((size_t)slot*B_ + b)*768 + o] = acc;
}

__global__ __launch_bounds__(256) void k_cond3(
    const void* ada1_w, const void* ada1_b, const void* ada2_w, const void* ada2_b,
    const int* __restrict__ fl, const float* __restrict__ part, float* __restrict__ ada_out)
{
    if (*fl) cond3_body<float>((const float*)ada1_w, (const float*)ada1_b,
                               (const float*)ada2_w, (const float*)ada2_b, part, ada_out);
    else     cond3_body<bf16>((const bf16*)ada1_w, (const bf16*)ada1_b,
                              (const bf16*)ada2_w, (const bf16*)ada2_b, part, ada_out);
}

// ---------------------------------------------------------------- adaLN (f32 h -> bf16 n)
__global__ __launch_bounds__(256) void k_adaln(
    const float* __restrict__ h, const float* __restrict__ ada,
    bf16* __restrict__ n, int slot)
{
    const int row  = blockIdx.x * 4 + (threadIdx.x >> 6);
    const int lane = threadIdx.x & 63;
    const int b = row / L_;
    const float* hr = h + (size_t)row*HID;
    float v[6]; float s = 0.f, ss = 0.f;
    #pragma unroll
    for (int j = 0; j < 6; ++j) { float t = hr[lane + j*64]; v[j] = t; s += t; ss += t*t; }
    #pragma unroll
    for (int off = 32; off; off >>= 1) { s += __shfl_xor(s, off); ss += __shfl_xor(ss, off); }
    const float mu = s * (1.0f/HID);
    const float rs = rsqrtf(fmaxf(ss * (1.0f/HID) - mu*mu, 0.0f) + 1e-5f);
    const float* ap = ada + ((size_t)slot*B_ + b)*768;
    bf16* nr = n + (size_t)row*HID;
    #pragma unroll
    for (int j = 0; j < 6; ++j) {
        int c = lane + j*64;
        nr[c] = __float2bfloat16((v[j] - mu)*rs*(1.0f + ap[c]) + ap[384 + c]);
    }
}

// ------------------------------------------------- MFMA GEMM epilogue (shared)
// mode: 0=bf16 store, 1=f32 +=, 2=V^T bf16 scatter, 3=bf16 store*QSCALE
static __device__ __forceinline__ void gemm_epilogue(
    f32x4 (&acc)[2][2], float bcol0, float bcol1,
    bf16* Cb, float* Cf, int M, int N, int act, int mode,
    int bm, int bn, int wm, int wn, int quad, int c)
{
    const float bcol[2] = {bcol0, bcol1};
    #pragma unroll
    for (int mi = 0; mi < 2; ++mi)
        #pragma unroll
        for (int ni = 0; ni < 2; ++ni) {
            const int col = bn + wn*32 + ni*16 + c;
            #pragma unroll
            for (int r = 0; r < 4; ++r) {
                const int row = bm + wm*32 + mi*16 + quad*4 + r;
                if (row < M) {
                    float v = acc[mi][ni][r] + bcol[ni];
                    if (act) v = 0.5f * v * (1.0f + erff(v * 0.70710678118654752f));  // GELU
                    if (mode == 1) Cf[(size_t)row*N + col] += v;
                    else if (mode == 0) Cb[(size_t)row*N + col] = __float2bfloat16(v);
                    else if (mode == 3) Cb[(size_t)row*N + col] = __float2bfloat16(v * QSCALE);
                    else {
                        const int b   = row >= L_ ? 1 : 0;
                        const int key = row - b*L_;
                        const int hh  = col / 48, d = col - hh*48;
                        Cb[((size_t)(b*8 + hh)*48 + d)*VLP + key] = __float2bfloat16(v);
                    }
                }
            }
        }
}

// -------- legacy GEMM: W fp32/bf16 [k][n], converted+transposed during staging
template <typename T>
static __device__ void gemm_body(
    const bf16* A, const T* W, long long woff, const T* bias, long long boff,
    bf16* Cb, float* Cf, int M, int N, int K, int act, int mode)
{
    __shared__ __align__(16) unsigned short As[64][72];
    __shared__ __align__(16) unsigned short Bt[64][72];
    const int tid  = threadIdx.x;
    const int wv   = tid >> 6, lane = tid & 63;
    const int quad = lane >> 4, c = lane & 15;
    const int wm = wv & 1, wn = wv >> 1;
    const int bm = blockIdx.x * 64, bn = blockIdx.y * 64;
    const int arow = tid >> 3, ach = tid & 7;
    f32x4 acc[2][2] = {{{0.f,0.f,0.f,0.f},{0.f,0.f,0.f,0.f}},
                       {{0.f,0.f,0.f,0.f},{0.f,0.f,0.f,0.f}}};
    for (int k0 = 0; k0 < K; k0 += 64) {
        short8 av[2]; float4 w0[2], w1[2];
        #pragma unroll
        for (int i = 0; i < 2; ++i) {
            const int row = i*32 + arow;
            av[i] = short8{0,0,0,0,0,0,0,0};
            if (bm + row < M)
                av[i] = *reinterpret_cast<const short8*>(
                            A + (size_t)(bm + row)*K + k0 + ach*8);
            const size_t wrow = (size_t)woff + (size_t)(k0 + i*32 + arow)*N + bn + ach*8;
            w0[i] = ld4(W, wrow);
            w1[i] = ld4(W, wrow + 4);
        }
        __syncthreads();
        #pragma unroll
        for (int i = 0; i < 2; ++i) {
            *reinterpret_cast<short8*>(&As[i*32 + arow][ach*8]) = av[i];
            const int kk = i*32 + arow, nb0 = ach*8;
            Bt[nb0+0][kk] = f2us(w0[i].x); Bt[nb0+1][kk] = f2us(w0[i].y);
            Bt[nb0+2][kk] = f2us(w0[i].z); Bt[nb0+3][kk] = f2us(w0[i].w);
            Bt[nb0+4][kk] = f2us(w1[i].x); Bt[nb0+5][kk] = f2us(w1[i].y);
            Bt[nb0+6][kk] = f2us(w1[i].z); Bt[nb0+7][kk] = f2us(w1[i].w);
        }
        __syncthreads();
        #pragma unroll
        for (int ks = 0; ks < 2; ++ks) {
            short8 af[2], bfr[2];
            #pragma unroll
            for (int mi = 0; mi < 2; ++mi)
                af[mi] = *reinterpret_cast<const short8*>(
                             &As[wm*32 + mi*16 + c][ks*32 + quad*8]);
            #pragma unroll
            for (int ni = 0; ni < 2; ++ni)
                bfr[ni] = *reinterpret_cast<const short8*>(
                              &Bt[wn*32 + ni*16 + c][ks*32 + quad*8]);
            #pragma unroll
            for (int mi = 0; mi < 2; ++mi)
                #pragma unroll
                for (int ni = 0; ni < 2; ++ni)
                    acc[mi][ni] = __builtin_amdgcn_mfma_f32_16x16x32_bf16(
                                      af[mi], bfr[ni], acc[mi][ni], 0, 0, 0);
        }
    }
    gemm_epilogue(acc, ldv(bias, (size_t)boff + bn + wn*32 + c),
                  ldv(bias, (size_t)boff + bn + wn*32 + 16 + c),
                  Cb, Cf, M, N, act, mode, bm, bn, wm, wn, quad, c);
}

__global__ __launch_bounds__(256) void k_gemm(
    const bf16* __restrict__ A, const void* W, long long woff, const void* bias, long long boff,
    bf16* Cb, float* Cf, int M, int N, int K, int act, int mode,
    const int* __restrict__ fl)
{
    if (*fl) gemm_body<float>(A, (const float*)W, woff, (const float*)bias, boff,
                              Cb, Cf, M, N, K, act, mode);
    else     gemm_body<bf16>(A, (const bf16*)W, woff, (const bf16*)bias, boff,
                             Cb, Cf, M, N, K, act, mode);
}

__global__ __launch_bounds__(256) void k_gemm_qkv(
    const bf16* __restrict__ A,
    const void* qw, const void* kw, const void* vw,
    const void* qb, const void* kb, const void* vb,
    long long woff, long long boff,
    bf16* Cq, bf16* Ck, bf16* Cv, const int* __restrict__ fl)
{
    const int z = blockIdx.z;
    const void* W  = (z == 0) ? qw : (z == 1) ? kw : vw;
    const void* Bi = (z == 0) ? qb : (z == 1) ? kb : vb;
    bf16* C        = (z == 0) ? Cq : (z == 1) ? Ck : Cv;
    const int mode = (z == 0) ? 3 : (z == 2) ? 2 : 0;
    if (*fl) gemm_body<float>(A, (const float*)W, woff, (const float*)Bi, boff,
                              C, nullptr, M_, HID, HID, 0, mode);
    else     gemm_body<bf16>(A, (const bf16*)W, woff, (const bf16*)Bi, boff,
                             C, nullptr, M_, HID, HID, 0, mode);
}

// -------- prepped GEMM: W bf16 pre-transposed [n][k].
// 2-phase schedule: double-buffered LDS, global_load_lds (16B, direct-to-LDS,
// no VGPR round-trip), ONE barrier per K-tile. Rule #21 both-sides swizzle.
// bm/bn passed in so callers can apply XCD-aware block remaps (T1).
static __device__ void gemm_t_body(
    const bf16* A, const bf16* Wt, long long woff, const bf16* bias, long long boff,
    bf16* Cb, float* Cf, int M, int N, int K, int act, int mode,
    int bm, int bn)
{
    __shared__ __align__(16) unsigned short Tz[2][2][4096];   // [buf][A/W][64*64] 32KB
    const int tid  = threadIdx.x;
    const int wv   = tid >> 6, lane = tid & 63;
    const int quad = lane >> 4, c = lane & 15;
    const int wm = wv & 1, wn = wv >> 1;
    const unsigned short* Ag = (const unsigned short*)A;
    const unsigned short* Wg = (const unsigned short*)Wt + woff;
    // staging geometry: thread -> 2 rows (j=0,1), 16B each, linear LDS dest
    const int sr = tid >> 3;                       // row within 32-row half
    const int csw0 = (((tid & 7) ^ (sr & 7)) << 3);      // inverse-swizzled col (elems)
    int ar0 = bm + sr;        ar0 = ar0 < M ? ar0 : M - 1;
    int ar1 = bm + 32 + sr;   ar1 = ar1 < M ? ar1 : M - 1;
    const int wr0 = bn + sr, wr1 = bn + 32 + sr;
    const int ldso = tid * 8;                      // elems within 2048-elem half

    f32x4 acc[2][2] = {{{0.f,0.f,0.f,0.f},{0.f,0.f,0.f,0.f}},
                       {{0.f,0.f,0.f,0.f},{0.f,0.f,0.f,0.f}}};

    #define STAGE_T(buf, k0) do { \
        GLOAD16(Ag + (size_t)ar0*K + (k0) + csw0, &Tz[buf][0][ldso]); \
        GLOAD16(Ag + (size_t)ar1*K + (k0) + csw0, &Tz[buf][0][2048 + ldso]); \
        GLOAD16(Wg + (size_t)wr0*K + (k0) + csw0, &Tz[buf][1][ldso]); \
        GLOAD16(Wg + (size_t)wr1*K + (k0) + csw0, &Tz[buf][1][2048 + ldso]); \
    } while (0)

    STAGE_T(0, 0);
    __syncthreads();                               // vmcnt(0) drain + barrier
    int cur = 0;
    for (int k0 = 0; k0 < K; k0 += 64) {
        if (k0 + 64 < K) STAGE_T(cur ^ 1, k0 + 64);    // async loads for next tile
        #pragma unroll
        for (int ks = 0; ks < 2; ++ks) {
            short8 af[2], bfr[2];
            #pragma unroll
            for (int mi = 0; mi < 2; ++mi) {
                const int row = wm*32 + mi*16 + c;
                const char* p = (const char*)&Tz[cur][0][0]
                              + (row*128 + (((ks*64 + quad*16)) ^ ((row & 7) << 4)));
                af[mi] = *reinterpret_cast<const short8*>(p);
            }
            #pragma unroll
            for (int ni = 0; ni < 2; ++ni) {
                const int row = wn*32 + ni*16 + c;
                const char* p = (const char*)&Tz[cur][1][0]
                              + (row*128 + (((ks*64 + quad*16)) ^ ((row & 7) << 4)));
                bfr[ni] = *reinterpret_cast<const short8*>(p);
            }
            #pragma unroll
            for (int mi = 0; mi < 2; ++mi)
                #pragma unroll
                for (int ni = 0; ni < 2; ++ni)
                    acc[mi][ni] = __builtin_amdgcn_mfma_f32_16x16x32_bf16(
                                      af[mi], bfr[ni], acc[mi][ni], 0, 0, 0);
        }
        __syncthreads();                           // drains next-tile loads + read fence
        cur ^= 1;
    }
    #undef STAGE_T
    gemm_epilogue(acc, b2f(bias[boff + bn + wn*32 + c]),
                  b2f(bias[boff + bn + wn*32 + 16 + c]),
                  Cb, Cf, M, N, act, mode, bm, bn, wm, wn, quad, c);
}

__global__ __launch_bounds__(256) void k_gemm_t(
    const bf16* __restrict__ A, const bf16* __restrict__ Wt, long long woff,
    const bf16* __restrict__ bias, long long boff,
    bf16* Cb, float* Cf, int M, int N, int K, int act, int mode)
{
    gemm_t_body(A, Wt, woff, bias, boff, Cb, Cf, M, N, K, act, mode,
                blockIdx.x*64, blockIdx.y*64);
}

// qkv GEMM, 1D grid 1332 with XCD-aware bijective remap (T1) + M-major decode:
// each XCD gets ~167 consecutive wg = a contiguous slice of A rows (0.45MB, L2-fits)
// for ALL (n-tile, matrix) pairs; W (0.9MB/layer total) L2-fits per XCD. Without the
// remap, A row-tiles are read by 18 blocks spread over all 8 XCDs -> A fetched ~8x.
__global__ __launch_bounds__(256) void k_gemm_qkv_t(
    const bf16* __restrict__ A, const bf16* __restrict__ wbt, const bf16* __restrict__ bb,
    int lyr, bf16* Cq, bf16* Ck, bf16* Cv)
{
    const int bid = blockIdx.x;                    // 0..1331
    const int xcd = bid & 7, idx = bid >> 3;       // 1332 = 8*166 + 4
    const int wg  = (xcd < 4 ? xcd*167 : 668 + (xcd - 4)*166) + idx;
    const int bx  = wg / 18;                       // M-tile 0..73 (M-major)
    const int rem = wg - bx*18;
    const int by  = rem % 6;                       // N-tile 0..5
    const int z   = rem / 6;                       // matrix 0..2
    long long woff; long long boff; bf16* C; int mode;
    if (z == 0)      { woff = WQ_ + (long long)lyr*147456; boff = BQ_ + lyr*384; C = Cq; mode = 3; }
    else if (z == 1) { woff = WK_ + (long long)lyr*147456; boff = BK_ + lyr*384; C = Ck; mode = 0; }
    else             { woff = WV_ + (long long)lyr*147456; boff = BV_ + lyr*384; C = Cv; mode = 2; }
    gemm_t_body(A, wbt, woff, bb, boff, C, nullptr, M_, HID, HID, 0, mode,
                bx*64, by*64);
}

// m1 GEMM, 1D grid 1776 (= 8*222 exact) with XCD remap + M-major decode:
// per XCD A slice ~0.45MB + full W 1.18MB — both L2-resident.
__global__ __launch_bounds__(256) void k_gemm_t_m1(
    const bf16* __restrict__ A, const bf16* __restrict__ wbt, const bf16* __restrict__ bb,
    int lyr, bf16* __restrict__ m1f)
{
    const int bid = blockIdx.x;                    // 0..1775
    const int xcd = bid & 7, idx = bid >> 3;
    const int wg  = xcd*222 + idx;
    const int bx  = wg / 24;                       // M-tile 0..73 (M-major)
    const int by  = wg % 24;                       // N-tile 0..23
    gemm_t_body(A, wbt, WM1_ + (long long)lyr*589824, bb, BM1_ + lyr*MLPD,
                m1f, nullptr, M_, MLPD, HID, 1, 0, bx*64, by*64);
}

// -------- 32-row-tile prepped GEMM (f32 += epilogue), for grid-starved dispatches
// (O-proj, M2). 1D grid 882 with XCD remap + M-major decode: per XCD A slice
// (O: 0.45MB / M2: 1.8MB) + full W (0.3 / 1.18MB) — L2-resident; kills the ~6-8x
// A over-fetch (M2's A = 14.5MB m1f was the worst offender at ~87MB/dispatch).
__global__ __launch_bounds__(256) void k_gemm_t32(
    const bf16* __restrict__ A, const bf16* __restrict__ Wt, long long woff,
    const bf16* __restrict__ bias, long long boff,
    float* __restrict__ Cf, int M, int N, int K)
{
    __shared__ __align__(16) unsigned short Az[2][2048];   // [buf][32 rows x 64 k]
    __shared__ __align__(16) unsigned short Wz[2][4096];   // [buf][64 cols x 64 k]
    const int tid  = threadIdx.x;
    const int wv   = tid >> 6, lane = tid & 63;
    const int quad = lane >> 4, c = lane & 15;
    const int wm = wv & 1, wn = wv >> 1;
    // XCD-aware bijective remap of the 882-block 1D grid (882 = 8*110 + 2)
    const int bid = blockIdx.x;
    const int xcd = bid & 7, idx = bid >> 3;
    const int wg  = (xcd < 2 ? xcd*111 : 222 + (xcd - 2)*110) + idx;
    const int bm  = (wg / 6) * 32;                 // M-tile (M-major)
    const int bn  = (wg % 6) * 64;                 // N-tile
    const unsigned short* Ag = (const unsigned short*)A;
    const unsigned short* Wg = (const unsigned short*)Wt + woff;
    const int sr = tid >> 3;                       // 0..31
    const int csw0 = (((tid & 7) ^ (sr & 7)) << 3);
    const int ar = bm + sr;                        // 147x32 = M exactly, no clamp
    const int wr0 = bn + sr, wr1 = bn + 32 + sr;
    const int ldso = tid * 8;

    f32x4 acc[2] = {{0.f,0.f,0.f,0.f},{0.f,0.f,0.f,0.f}};

    #define STAGE_T32(buf, k0) do { \
        GLOAD16(Ag + (size_t)ar*K + (k0) + csw0, &Az[buf][ldso]); \
        GLOAD16(Wg + (size_t)wr0*K + (k0) + csw0, &Wz[buf][ldso]); \
        GLOAD16(Wg + (size_t)wr1*K + (k0) + csw0, &Wz[buf][2048 + ldso]); \
    } while (0)

    STAGE_T32(0, 0);
    __syncthreads();
    int cur = 0;
    for (int k0 = 0; k0 < K; k0 += 64) {
        if (k0 + 64 < K) STAGE_T32(cur ^ 1, k0 + 64);
        #pragma unroll
        for (int ks = 0; ks < 2; ++ks) {
            short8 af, bfr[2];
            {
                const int row = wm*16 + c;
                const char* p = (const char*)&Az[cur][0]
                              + (row*128 + ((ks*64 + quad*16) ^ ((row & 7) << 4)));
                af = *reinterpret_cast<const short8*>(p);
            }
            #pragma unroll
            for (int ni = 0; ni < 2; ++ni) {
                const int row = wn*32 + ni*16 + c;
                const char* p = (const char*)&Wz[cur][0]
                              + (row*128 + ((ks*64 + quad*16) ^ ((row & 7) << 4)));
                bfr[ni] = *reinterpret_cast<const short8*>(p);
            }
            #pragma unroll
            for (int ni = 0; ni < 2; ++ni)
                acc[ni] = __builtin_amdgcn_mfma_f32_16x16x32_bf16(af, bfr[ni], acc[ni], 0, 0, 0);
        }
        __syncthreads();
        cur ^= 1;
    }
    #undef STAGE_T32
    // epilogue: f32 += (bias included)
    #pragma unroll
    for (int ni = 0; ni < 2; ++ni) {
        const int col = bn + wn*32 + ni*16 + c;
        const float bcol = b2f(bias[boff + col]);
        #pragma unroll
        for (int r = 0; r < 4; ++r) {
            const int row = bm + wm*16 + quad*4 + r;
            Cf[(size_t)row*N + col] += acc[ni][r] + bcol;
        }
    }
}

// ---------------------------------------------------------------- MFMA flash attention
// (fallback) 64 queries/block, 8 waves, in-block split-K x2 — used when ws lacks
// room for flash-decode partials.
__global__ __launch_bounds__(512) void k_attn(
    const bf16* __restrict__ q, const bf16* __restrict__ k,
    const bf16* __restrict__ vt, bf16* __restrict__ ao)
{
    __shared__ __align__(16) unsigned short Ks[2][64][80];   // [split][key][d 0..63 +pad]
    __shared__ __align__(16) unsigned short Vt[2][48][72];   // [split][d][key 0..63 +pad]
    __shared__ __align__(16) unsigned short Pq[8][16][72];   // [wave][query][key 0..63 +pad]
    const int tid  = threadIdx.x;
    const int w    = tid >> 6, lane = tid & 63;
    const int quad = lane >> 4, c = lane & 15;
    const int qt = w & 3, sp = w >> 2;               // q-tile 0..3, split 0..1
    const int bh = blockIdx.y;                       // b*8+hh
    const size_t base  = (size_t)(bh >> 3)*L_*HID + (size_t)(bh & 7)*HD;
    const size_t vbase = (size_t)bh*48*VLP;
    const int q0 = blockIdx.x*64 + qt*16;
    const bool qvalid = q0 < L_;                     // wave-uniform
    const int qrow = qvalid ? (q0 + c) : c;

    short8 qf0, qf1;
    {
        const unsigned short* qp = (const unsigned short*)(q + base + (size_t)qrow*HID);
        qf0 = *reinterpret_cast<const short8*>(qp + quad*8);                 // d 0..31
        if (quad < 2) qf1 = *reinterpret_cast<const short8*>(qp + 32 + quad*8);  // d 32..47
        else          qf1 = short8{0,0,0,0,0,0,0,0};                         // d 48..63 pad
    }
    f32x4 o0 = {0.f,0.f,0.f,0.f}, o1 = {0.f,0.f,0.f,0.f}, o2 = {0.f,0.f,0.f,0.f};
    float m = -3.0e38f, lsum = 0.f;

    // ---- staging assignment: 256-thread group per split
    const int t256 = tid & 255, grp = tid >> 8;
    const int krow0 = t256 >> 3, kch = t256 & 7;     // K row 0..31 / ch 0..7
    const int krow1 = 32 + krow0;                    // K row 32..63
    const int vd0 = krow0;                           // V d 0..31
    const int vd1 = 32 + (krow0 & 15);               // V d 32..47 (t256<128 only)
    const bool vl1 = (t256 < 128);
    const unsigned short* kq = (const unsigned short*)(k + base);
    const unsigned short* vq = (const unsigned short*)(vt + vbase);
    const short8 Z8 = short8{0,0,0,0,0,0,0,0};
    short8 kr0 = Z8, kr1 = Z8, vr0, vr1 = Z8;
    {   // prefetch tile 0 (keys unclamped: OOB tail lands inside workspace, masked in S)
        const int kb0 = grp*1216;
        if (kch < 6) {
            kr0 = *reinterpret_cast<const short8*>(kq + (size_t)(kb0 + krow0)*HID + kch*8);
            kr1 = *reinterpret_cast<const short8*>(kq + (size_t)(kb0 + krow1)*HID + kch*8);
        }
        vr0 = *reinterpret_cast<const short8*>(vq + (size_t)vd0*VLP + kb0 + kch*8);
        if (vl1) vr1 = *reinterpret_cast<const short8*>(vq + (size_t)vd1*VLP + kb0 + kch*8);
    }

    for (int tt = 0; tt < 19; ++tt) {
        __syncthreads();                             // prev tile's LDS reads done
        *reinterpret_cast<short8*>(&Ks[grp][krow0][kch*8]) = kr0;
        *reinterpret_cast<short8*>(&Ks[grp][krow1][kch*8]) = kr1;
        *reinterpret_cast<short8*>(&Vt[grp][vd0][kch*8])   = vr0;
        if (vl1) *reinterpret_cast<short8*>(&Vt[grp][vd1][kch*8]) = vr1;
        __syncthreads();                             // this tile's LDS ready
        if (tt < 18) {                               // issue next tile's loads -> regs
            const int nb0 = grp*1216 + (tt + 1)*64;
            if (kch < 6) {
                kr0 = *reinterpret_cast<const short8*>(kq + (size_t)(nb0 + krow0)*HID + kch*8);
                kr1 = *reinterpret_cast<const short8*>(kq + (size_t)(nb0 + krow1)*HID + kch*8);
            }
            vr0 = *reinterpret_cast<const short8*>(vq + (size_t)vd0*VLP + nb0 + kch*8);
            if (vl1) vr1 = *reinterpret_cast<const short8*>(vq + (size_t)vd1*VLP + nb0 + kch*8);
        }

        const int kt = sp*1216 + tt*64;              // compute key base for this wave
        float sv[16];
        #pragma unroll
        for (int t = 0; t < 4; ++t) {
            f32x4 acc = {0.f,0.f,0.f,0.f};
            short8 a0 = *reinterpret_cast<const short8*>(&Ks[sp][t*16 + c][quad*8]);
            short8 a1 = *reinterpret_cast<const short8*>(&Ks[sp][t*16 + c][32 + quad*8]);
            acc = __builtin_amdgcn_mfma_f32_16x16x32_bf16(a0, qf0, acc, 0, 0, 0);
            acc = __builtin_amdgcn_mfma_f32_16x16x32_bf16(a1, qf1, acc, 0, 0, 0);
            #pragma unroll
            for (int r = 0; r < 4; ++r) sv[t*4 + r] = acc[r];   // already log2-scaled
        }
        if (sp == 1 && tt >= 17) {                   // tiles with keys >= L_ (2304.. / 2368..)
            #pragma unroll
            for (int t = 0; t < 4; ++t)
                #pragma unroll
                for (int r = 0; r < 4; ++r)
                    if (kt + t*16 + quad*4 + r >= L_) sv[t*4 + r] = -3.0e38f;
        }
        // tree max (depth 4, max3-fusable)
        float tmax = fmaxf(fmaxf(fmaxf(sv[0], sv[1]),  fmaxf(sv[2],  sv[3])),
                           fmaxf(fmaxf(sv[4], sv[5]),  fmaxf(sv[6],  sv[7])));
        float tmx2 = fmaxf(fmaxf(fmaxf(sv[8], sv[9]),  fmaxf(sv[10], sv[11])),
                           fmaxf(fmaxf(sv[12], sv[13]), fmaxf(sv[14], sv[15])));
        tmax = fmaxf(tmax, tmx2);
        tmax = fmaxf(tmax, __shfl_xor(tmax, 16));
        tmax = fmaxf(tmax, __shfl_xor(tmax, 32));
        if (!__all(tmax <= m + 8.0f)) {              // defer-max: rescale only on growth
            const float mn = fmaxf(m, tmax);
            const float alpha = exp2f(m - mn);
            m = mn;
            lsum *= alpha;
            o0 *= alpha; o1 *= alpha; o2 *= alpha;
        }
        float psum = 0.f;
        unsigned short pv[16];
        #pragma unroll
        for (int i = 0; i < 16; ++i) {
            const float p = exp2f(sv[i] - m);        // bounded by 2^8
            psum += p;
            pv[i] = f2us(p);
        }
        lsum += psum;
        // P row (query c) -> LDS; same-wave rw, no barrier needed
        #pragma unroll
        for (int t = 0; t < 4; ++t)
            *reinterpret_cast<ushort4*>(&Pq[w][c][t*16 + quad*4]) =
                make_ushort4(pv[t*4+0], pv[t*4+1], pv[t*4+2], pv[t*4+3]);
        // PV in 2 steps of 32 keys (b128 fragments)
        #pragma unroll
        for (int s = 0; s < 2; ++s) {
            short8 pf  = *reinterpret_cast<const short8*>(&Pq[w][c][s*32 + quad*8]);
            short8 vf0 = *reinterpret_cast<const short8*>(&Vt[sp][c][s*32 + quad*8]);
            short8 vf1 = *reinterpret_cast<const short8*>(&Vt[sp][16 + c][s*32 + quad*8]);
            short8 vf2 = *reinterpret_cast<const short8*>(&Vt[sp][32 + c][s*32 + quad*8]);
            o0 = __builtin_amdgcn_mfma_f32_16x16x32_bf16(vf0, pf, o0, 0, 0, 0);
            o1 = __builtin_amdgcn_mfma_f32_16x16x32_bf16(vf1, pf, o1, 0, 0, 0);
            o2 = __builtin_amdgcn_mfma_f32_16x16x32_bf16(vf2, pf, o2, 0, 0, 0);
        }
    }
    // ---- reduce l across quads within wave
    float lw = lsum;
    lw += __shfl_xor(lw, 16);
    lw += __shfl_xor(lw, 32);
    // ---- split merge through LDS (reuse Ks: 20480 B >= 4*64*14*4 = 14336 B; Ks dead here)
    float* Mg = (float*)&Ks[0][0][0];
    __syncthreads();
    if (sp == 1) {
        float* dst = Mg + (size_t)(qt*64 + lane)*14;
        dst[0] = o0[0]; dst[1] = o0[1]; dst[2]  = o0[2]; dst[3]  = o0[3];
        dst[4] = o1[0]; dst[5] = o1[1]; dst[6]  = o1[2]; dst[7]  = o1[3];
        dst[8] = o2[0]; dst[9] = o2[1]; dst[10] = o2[2]; dst[11] = o2[3];
        dst[12] = m; dst[13] = lw;
    }
    __syncthreads();
    if (sp == 0 && qvalid) {
        const float* src = Mg + (size_t)(qt*64 + lane)*14;
        const float m2 = src[12], l2 = src[13];
        const float mm = fmaxf(m, m2);
        const float a1 = exp2f(m - mm), a2 = exp2f(m2 - mm);
        const float inv = 1.0f / (lw*a1 + l2*a2);
        unsigned short* orow = (unsigned short*)(ao + base + (size_t)(q0 + c)*HID);
        const f32x4 ot[3] = {o0, o1, o2};
        #pragma unroll
        for (int dt = 0; dt < 3; ++dt) {
            ushort4 w4;
            w4.x = f2us((ot[dt][0]*a1 + src[dt*4+0]*a2) * inv);
            w4.y = f2us((ot[dt][1]*a1 + src[dt*4+1]*a2) * inv);
            w4.z = f2us((ot[dt][2]*a1 + src[dt*4+2]*a2) * inv);
            w4.w = f2us((ot[dt][3]*a1 + src[dt*4+3]*a2) * inv);
            *reinterpret_cast<ushort4*>(orow + dt*16 + quad*4) = w4;
        }
    }
}

// ---------------------------------------------------------------- flash-decode attention
// Key-split ACROSS blocks, XCD-aware bijective remap (T1, r10: FETCH 34->6.7MB).
// Round 14: SINGLE-buffered K (Kz 16->8KB) cuts LDS 37.9->29.7KB -> 5 blocks/CU ->
// all 1184 blocks resident in ONE scheduling round (capacity 1280), eliminating the
// ~16% straggler tail of the 4-blocks/CU config (capacity 1024 < 1184). K is consumed
// in the FIRST phase (QK^T), so its next-tile stage issues after a post-QK barrier and
// its latency hides under softmax+PV; V stays double-buffered (consumed last).
// Cost: 2 barriers/tile instead of 1 (r7 measured that transition worth only ~1.6us).
// gload_lds staging (rule #21 swizzle), raw v_exp_f32, truncation-packed bf16 P.
__global__ __launch_bounds__(256) void k_attn_fd(
    const bf16* __restrict__ q, const bf16* __restrict__ k,
    const bf16* __restrict__ vt, bf16* __restrict__ pob, float* __restrict__ pml)
{
    __shared__ __align__(16) unsigned short Kz[4096];     // [64 key x 64 d] swizzled, 8KB
    __shared__ __align__(16) unsigned short Vz[2][3072];  // [buf][48 d x 64 key] swizzled
    __shared__ __align__(16) unsigned short Pq[4][16][72];
    const int tid  = threadIdx.x;
    const int w    = tid >> 6, lane = tid & 63;
    const int quad = lane >> 4, c = lane & 15;
    // XCD-aware decomposition of the 1184-block 1D grid
    const int bid  = blockIdx.x;
    const int wg   = (bid & 7)*148 + (bid >> 3);     // bijective: 148 blocks per XCD
    const int g    = wg / 37;                        // (bh,half) group 0..31
    const int qblk = wg - g*37;
    const int bh   = g >> 1;
    const int half = g & 1;
    const size_t base  = (size_t)(bh >> 3)*L_*HID + (size_t)(bh & 7)*HD;
    const size_t vbase = (size_t)bh*48*VLP;
    const int q0 = qblk*64 + w*16;
    const bool qvalid = q0 < L_;                     // wave-uniform
    const int qrow = qvalid ? (q0 + c) : c;

    short8 qf0, qf1;
    {
        const unsigned short* qp = (const unsigned short*)(q + base + (size_t)qrow*HID);
        qf0 = *reinterpret_cast<const short8*>(qp + quad*8);                 // d 0..31
        if (quad < 2) qf1 = *reinterpret_cast<const short8*>(qp + 32 + quad*8);  // d 32..47
        else          qf1 = short8{0,0,0,0,0,0,0,0};                         // d 48..63 pad
    }
    f32x4 o0 = {0.f,0.f,0.f,0.f}, o1 = {0.f,0.f,0.f,0.f}, o2 = {0.f,0.f,0.f,0.f};
    float m = -3.0e38f, lsum = 0.f;

    // staging geometry: per thread 2 K-slots + 1-2 V-slots, all linear (tid*16B) dests
    const int srow = tid >> 3;                       // 0..31
    const int sc   = (tid & 7) ^ (srow & 7);         // inverse-swizzled slot
    const int scol = sc << 3;                        // global col (elems)
    const bool kld = (sc < 6);                       // K cols 48..63 never loaded
    const int ldo  = tid * 8;                        // linear LDS dest (elems)
    const unsigned short* kq = (const unsigned short*)(k + base);
    const unsigned short* vq = (const unsigned short*)(vt + vbase);
    const int kbase = half*1216;

    #define STAGE_K(kb) do { \
        if (kld) { \
            GLOAD16(kq + (size_t)((kb) + srow)*HID + scol,      &Kz[ldo]); \
            GLOAD16(kq + (size_t)((kb) + 32 + srow)*HID + scol, &Kz[2048 + ldo]); \
        } \
    } while (0)
    #define STAGE_V(buf, kb) do { \
        GLOAD16(vq + (size_t)srow*VLP + (kb) + scol, &Vz[buf][ldo]); \
        if (tid < 128) \
            GLOAD16(vq + (size_t)(32 + srow)*VLP + (kb) + scol, &Vz[buf][2048 + ldo]); \
    } while (0)

    {   // pre-zero K d-pad slots (cols 48..63) — never overwritten by STAGE_K
        const short8 Z8 = short8{0,0,0,0,0,0,0,0};
        if (tid < 128) {
            const int r = tid >> 1, j = tid & 1;
            const int s = (6 + j) ^ (r & 7);
            *reinterpret_cast<short8*>(&Kz[r*64 + s*8]) = Z8;
        }
    }
    STAGE_K(kbase);
    STAGE_V(0, kbase);
    __syncthreads();                                 // vmcnt drain + barrier
    int cur = 0;

    for (int tt = 0; tt < 19; ++tt) {
        if (tt < 18) STAGE_V(cur ^ 1, kbase + (tt + 1)*64);    // async next-tile V loads

        const int kt = kbase + tt*64;
        const char* kzb = (const char*)&Kz[0];
        const char* vzb = (const char*)&Vz[cur][0];
        const int qx = quad << 4;                    // colbyte of this quad's 16B
        float sv[16];
        #pragma unroll
        for (int t = 0; t < 4; ++t) {
            const int kr = t*16 + c;
            const int rx = kr*128;
            const int x0 = qx ^ ((kr & 7) << 4);
            f32x4 acc = {0.f,0.f,0.f,0.f};
            short8 a0 = *reinterpret_cast<const short8*>(kzb + rx + x0);
            short8 a1 = *reinterpret_cast<const short8*>(kzb + rx + (x0 ^ 64));
            acc = __builtin_amdgcn_mfma_f32_16x16x32_bf16(a0, qf0, acc, 0, 0, 0);
            acc = __builtin_amdgcn_mfma_f32_16x16x32_bf16(a1, qf1, acc, 0, 0, 0);
            #pragma unroll
            for (int r = 0; r < 4; ++r) sv[t*4 + r] = acc[r];   // already log2-scaled
        }
        __syncthreads();                             // all waves' QK reads of Kz done
        if (tt < 18) STAGE_K(kbase + (tt + 1)*64);   // overwrite Kz with next tile's K

        if (half == 1 && tt >= 17) {                 // keys >= L_ (2304.. / 2368..)
            #pragma unroll
            for (int t = 0; t < 4; ++t)
                #pragma unroll
                for (int r = 0; r < 4; ++r)
                    if (kt + t*16 + quad*4 + r >= L_) sv[t*4 + r] = -3.0e38f;
        }
        // tree max: two max3-fusable chains + combine
        float h0 = fmaxf(fmaxf(sv[0], sv[1]), sv[2]);
        h0 = fmaxf(fmaxf(h0, sv[3]), sv[4]);
        h0 = fmaxf(fmaxf(h0, sv[5]), sv[6]);
        h0 = fmaxf(h0, sv[7]);
        float h1 = fmaxf(fmaxf(sv[8], sv[9]), sv[10]);
        h1 = fmaxf(fmaxf(h1, sv[11]), sv[12]);
        h1 = fmaxf(fmaxf(h1, sv[13]), sv[14]);
        h1 = fmaxf(h1, sv[15]);
        float tmax = fmaxf(h0, h1);
        tmax = fmaxf(tmax, __shfl_xor(tmax, 16));
        tmax = fmaxf(tmax, __shfl_xor(tmax, 32));
        if (!__all(tmax <= m + 8.0f)) {              // defer-max
            const float mn = fmaxf(m, tmax);
            const float alpha = exp2_raw(m - mn);
            m = mn;
            lsum *= alpha;
            o0 *= alpha; o1 *= alpha; o2 *= alpha;
        }
        // P = exp2(S - m), truncation-packed to bf16 pairs
        float psum = 0.f;
        unsigned pk[8];
        #pragma unroll
        for (int i = 0; i < 8; ++i) {
            const float p0 = exp2_raw(sv[2*i]     - m);   // bounded by 2^8
            const float p1 = exp2_raw(sv[2*i + 1] - m);
            psum += p0 + p1;
            pk[i] = (__float_as_uint(p0) >> 16) | (__float_as_uint(p1) & 0xFFFF0000u);
        }
        lsum += psum;
        // P row (query c) -> LDS as b64 pairs; same-wave rw, no barrier needed
        #pragma unroll
        for (int t = 0; t < 4; ++t)
            *reinterpret_cast<uint2*>(&Pq[w][c][t*16 + quad*4]) =
                make_uint2(pk[2*t], pk[2*t + 1]);
        // PV in 2 steps of 32 keys (b128 fragments, swizzled V reads)
        const int mx = (c & 7) << 4;
        #pragma unroll
        for (int s = 0; s < 2; ++s) {
            const int va = ((s << 6) | qx) ^ mx;
            short8 pf  = *reinterpret_cast<const short8*>(&Pq[w][c][s*32 + quad*8]);
            short8 vf0 = *reinterpret_cast<const short8*>(vzb + c*128 + va);
            short8 vf1 = *reinterpret_cast<const short8*>(vzb + (16 + c)*128 + va);
            short8 vf2 = *reinterpret_cast<const short8*>(vzb + (32 + c)*128 + va);
            o0 = __builtin_amdgcn_mfma_f32_16x16x32_bf16(vf0, pf, o0, 0, 0, 0);
            o1 = __builtin_amdgcn_mfma_f32_16x16x32_bf16(vf1, pf, o1, 0, 0, 0);
            o2 = __builtin_amdgcn_mfma_f32_16x16x32_bf16(vf2, pf, o2, 0, 0, 0);
        }
        __syncthreads();                             // drains next K+V loads; fences Vz[cur]
        cur ^= 1;
    }
    #undef STAGE_K
    #undef STAGE_V
    // reduce l across quads, normalize, store partials
    float lw = lsum;
    lw += __shfl_xor(lw, 16);
    lw += __shfl_xor(lw, 32);
    const float invl = 1.0f / lw;
    const size_t ro = ((size_t)bh*2368 + q0 + c)*2 + half;
    unsigned short* pr = (unsigned short*)pob + ro*48;
    const f32x4 ot[3] = {o0, o1, o2};
    #pragma unroll
    for (int dt = 0; dt < 3; ++dt) {
        ushort4 w4;
        w4.x = f2us(ot[dt][0]*invl);
        w4.y = f2us(ot[dt][1]*invl);
        w4.z = f2us(ot[dt][2]*invl);
        w4.w = f2us(ot[dt][3]*invl);
        *reinterpret_cast<ushort4*>(pr + dt*16 + quad*4) = w4;
    }
    if (quad == 0) { pml[ro*2 + 0] = m; pml[ro*2 + 1] = lw; }
}

// merge the two key-halves: out = (o1*l1*a1 + o2*l2*a2) / (l1*a1 + l2*a2)
__global__ __launch_bounds__(256) void k_amerge(
    const bf16* __restrict__ pob, const float* __restrict__ pml, bf16* __restrict__ ao)
{
    const int tid = threadIdx.x;
    const int bh = blockIdx.y;
    const int qq = blockIdx.x*16 + (tid >> 4);       // 0..2351
    const int j = tid & 15;
    const size_t ro = ((size_t)bh*2368 + qq)*2;
    const float m1 = pml[ro*2 + 0], l1 = pml[ro*2 + 1];
    const float m2 = pml[ro*2 + 2], l2 = pml[ro*2 + 3];
    const float mm = fmaxf(m1, m2);
    const float b1 = exp2f(m1 - mm)*l1, b2 = exp2f(m2 - mm)*l2;
    const float inv = 1.0f / (b1 + b2);
    const float w1 = b1*inv, w2 = b2*inv;
    if (j < 12) {
        const unsigned short* p1 = (const unsigned short*)pob + ro*48 + j*4;
        ushort4 u1 = *reinterpret_cast<const ushort4*>(p1);
        ushort4 u2 = *reinterpret_cast<const ushort4*>(p1 + 48);
        ushort4 o4;
        o4.x = f2us(us2f(u1.x)*w1 + us2f(u2.x)*w2);
        o4.y = f2us(us2f(u1.y)*w1 + us2f(u2.y)*w2);
        o4.z = f2us(us2f(u1.z)*w1 + us2f(u2.z)*w2);
        o4.w = f2us(us2f(u1.w)*w1 + us2f(u2.w)*w2);
        const size_t base = (size_t)(bh >> 3)*L_*HID + (size_t)(bh & 7)*HD;
        *reinterpret_cast<ushort4*>((unsigned short*)ao + base + (size_t)qq*HID + j*4) = o4;
    }
}

// ------------------------------------------------------- final LN + heads
template <typename T, typename TO>
static __device__ void final_body(
    const float* h, const T* fn_g, const T* fn_b,
    const T* on_w, const T* on_b, const T* oe_w, const T* oe_b, TO* out)
{
    __shared__ float hf[HID];
    const int row = blockIdx.x;
    const int b = row / L_, l = row % L_;
    const int lane = threadIdx.x;
    const float* hr = h + (size_t)row*HID;
    float v[6]; float s = 0.f, ss = 0.f;
    #pragma unroll
    for (int j = 0; j < 6; ++j) { float t = hr[lane + j*64]; v[j] = t; s += t; ss += t*t; }
    #pragma unroll
    for (int off = 32; off; off >>= 1) { s += __shfl_xor(s, off); ss += __shfl_xor(ss, off); }
    const float mu = s * (1.0f/HID);
    const float rs = rsqrtf(fmaxf(ss * (1.0f/HID) - mu*mu, 0.0f) + 1e-5f);
    #pragma unroll
    for (int j = 0; j < 6; ++j) {
        int c = lane + j*64;
        hf[c] = (v[j] - mu) * rs * ldv(fn_g, c) + ldv(fn_b, c);
    }
    __syncthreads();
    if (l < N_) {
        if (lane < A_) {
            float acc = ldv(on_b, lane);
            for (int c = 0; c < HID; ++c) acc += hf[c] * ldv(on_w, (size_t)c*A_ + lane);
            stv(out, (size_t)(b*N_ + l)*A_ + lane, acc);
        }
    } else {
        const int e = l - N_;
        if (lane < E_) {
            float acc = ldv(oe_b, lane);
            for (int c = 0; c < HID; ++c) acc += hf[c] * ldv(oe_w, (size_t)c*E_ + lane);
            stv(out, (size_t)B_*N_*A_ + ((size_t)b*N_*N_ + e)*E_ + lane, acc);
        }
    }
}

__global__ __launch_bounds__(64) void k_final(
    const float* __restrict__ h, const void* fn_g, const void* fn_b,
    const void* on_w, const void* on_b, const void* oe_w, const void* oe_b,
    const int* __restrict__ fl, void* out)
{
    if (*fl) final_body<float, float>(h, (const float*)fn_g, (const float*)fn_b,
                                      (const float*)on_w, (const float*)on_b,
                                      (const float*)oe_w, (const float*)oe_b, (float*)out);
    else     final_body<bf16, bf16>(h, (const bf16*)fn_g, (const bf16*)fn_b,
                                    (const bf16*)on_w, (const bf16*)on_b,
                                    (const bf16*)oe_w, (const bf16*)oe_b, (bf16*)out);
}

// ---------------------------------------------------------------- launch
extern "C" void kernel_launch(void* const* d_in, const int* in_sizes, int n_in,
                              void* d_out, int out_size, void* d_ws, size_t ws_size,
                              hipStream_t stream) {
    const void* x      = d_in[0];
    const void* adj    = d_in[1];
    const void* t      = d_in[2];
    const void* node_w = d_in[3];
    const void* node_b = d_in[4];
    const void* edge_w = d_in[5];
    const void* edge_b = d_in[6];
    const void* pos    = d_in[7];
    const void* t_w1   = d_in[8];
    const void* t_b1   = d_in[9];
    const void* t_w2   = d_in[10];
    const void* t_b2   = d_in[11];
    const void* ada1_w = d_in[12];
    const void* ada1_b = d_in[13];
    const void* ada2_w = d_in[14];
    const void* ada2_b = d_in[15];
    const void* q_w    = d_in[16];
    const void* q_b    = d_in[17];
    const void* k_w    = d_in[18];
    const void* k_b    = d_in[19];
    const void* v_w    = d_in[20];
    const void* v_b    = d_in[21];
    const void* o_w    = d_in[22];
    const void* o_b    = d_in[23];
    const void* m1_w   = d_in[24];
    const void* m1_b   = d_in[25];
    const void* m2_w   = d_in[26];
    const void* m2_b   = d_in[27];
    const void* fn_g   = d_in[28];
    const void* fn_b   = d_in[29];
    const void* on_w   = d_in[30];
    const void* on_b   = d_in[31];
    const void* oe_w   = d_in[32];
    const void* oe_b   = d_in[33];

    const size_t SZ  = (size_t)M_ * HID;          // 1,806,336 elements
    const size_t VTZ = (size_t)B_*NHD*HD*VLP;     // 1,867,776 elements (padded V^T)
    const size_t FLT = SZ + 12288 + (size_t)B_*4*HID + (size_t)B_*12*HID;  // 1,830,912
    const size_t M1FULL = (size_t)M_ * MLPD;      // 7,225,344
    const size_t BF_BASE = 3*SZ + VTZ;            // nb..vtb end = 7,286,784
    const size_t BF_BIG  = SZ + M1FULL;           // nb + m1f(from qb) end = 9,031,680
    const size_t NEED      = 256 + sizeof(float)*FLT + sizeof(bf16)*BF_BASE;   // ~21.9 MB
    const size_t NEED_BIG  = 256 + sizeof(float)*FLT + sizeof(bf16)*BF_BIG;    // ~25.4 MB
    const size_t NEED_PREP = 256 + sizeof(float)*FLT
                           + sizeof(bf16)*(BF_BIG + WTOT + BTOT);              // ~39.6 MB
    const size_t NEED_FD   = NEED_PREP + sizeof(bf16)*PO_E + sizeof(float)*PML_E; // ~47.5 MB
    if (ws_size < NEED) {
        hipMemsetAsync(d_out, 0, (size_t)out_size*sizeof(bf16), stream);  // 1.14 signature
        return;
    }
    const bool big  = (ws_size >= NEED_BIG);
    const bool prep = (ws_size >= NEED_PREP);
    const bool fd   = (ws_size >= NEED_FD);
    int*   fl   = (int*)d_ws;
    float* h    = (float*)((char*)d_ws + 256);
    float* ada  = h + SZ;                  // [8][B_][768]
    float* hid  = ada + 12288;             // [B_][1536]
    float* part = hid + (size_t)B_*4*HID;  // [B_][12][384] cond partials
    bf16* nb  = (bf16*)(part + (size_t)B_*12*HID);
    bf16* qb  = nb + SZ;
    bf16* kb  = qb + SZ;
    bf16* vtb = kb + SZ;                   // transposed V, [bh*48+d][VLP]
    bf16* m1c = kb;                        // chunked m1: [2352,1536] spans kb+vtb
    bf16* m1f = qb;                        // full m1: [M_,1536] spans qb..vtb+tail
    bf16* wbt = nb + BF_BIG;               // prepped weights (bf16, [n][k])
    bf16* bb  = wbt + WTOT;                // prepped biases
    bf16* pob = bb + BTOT;                 // flash-decode partial o (normalized)
    float* pml = (float*)(pob + PO_E);     // flash-decode partial (m, l)

    k_detect<<<1, 64, 0, stream>>>(node_w, fl);
    if (prep) {
        k_prepw<<<dim3(144, 24), 256, 0, stream>>>(q_w, k_w, v_w, o_w, m1_w, m2_w, fl, wbt);
        k_prepb<<<1, 256, 0, stream>>>(q_b, k_b, v_b, o_b, m1_b, m2_b, fl, bb);
    }
    k_embed<<<M_, HID, 0, stream>>>(x, adj, node_w, node_b, edge_w, edge_b, pos, fl, h);
    k_cond1<<<dim3(B_, 24), 256, 0, stream>>>(t, t_w1, t_b1, fl, hid);
    k_cond2<<<dim3(B_, 12), 384, 0, stream>>>(t_w2, t_b2, fl, hid, part);
    k_cond3<<<dim3(24, B_), 256, 0, stream>>>(ada1_w, ada1_b, ada2_w, ada2_b, fl, part, ada);
    for (int i = 0; i < LYR; ++i) {
        const long long woff   = (long long)i * HID * HID;
        const long long boff   = (long long)i * HID;
        const long long m1woff = (long long)i * HID * MLPD;
        const long long m1boff = (long long)i * MLPD;
        const long long m2woff = (long long)i * MLPD * HID;

        k_adaln<<<M_/4, 256, 0, stream>>>(h, ada, nb, 2*i);
        if (prep) {
            k_gemm_qkv_t<<<1332, 256, 0, stream>>>(nb, wbt, bb, i, qb, kb, vtb);
            if (fd) {
                k_attn_fd<<<1184, 256, 0, stream>>>(qb, kb, vtb, pob, pml);
                k_amerge<<<dim3(147, 16), 256, 0, stream>>>(pob, pml, nb);   // ao -> nb
            } else {
                k_attn<<<dim3(37, B_*NHD), 512, 0, stream>>>(qb, kb, vtb, nb);
            }
            k_gemm_t32<<<882, 256, 0, stream>>>(nb, wbt, WO_ + (long long)i*147456,
                                                bb, BO_ + i*384,
                                                h, M_, HID, HID);
            k_adaln<<<M_/4, 256, 0, stream>>>(h, ada, nb, 2*i + 1);          // n2 -> nb
            k_gemm_t_m1<<<1776, 256, 0, stream>>>(nb, wbt, bb, i, m1f);
            k_gemm_t32<<<882, 256, 0, stream>>>(m1f, wbt, WM2_ + (long long)i*589824,
                                                bb, BM2_ + i*384,
                                                h, M_, HID, MLPD);
        } else {
            k_gemm_qkv<<<dim3(74, 6, 3), 256, 0, stream>>>(nb, q_w, k_w, v_w, q_b, k_b, v_b,
                                                           woff, boff, qb, kb, vtb, fl);
            k_attn<<<dim3(37, B_*NHD), 512, 0, stream>>>(qb, kb, vtb, nb);   // ao -> nb
            k_gemm<<<dim3(74, 6), 256, 0, stream>>>(nb, o_w, woff, o_b, boff,
                                                    nullptr, h, M_, HID, HID, 0, 1, fl);
            k_adaln<<<M_/4, 256, 0, stream>>>(h, ada, nb, 2*i + 1);          // n2 -> nb
            if (big) {
                k_gemm<<<dim3(74, 24), 256, 0, stream>>>(nb, m1_w, m1woff, m1_b, m1boff,
                                                         m1f, nullptr, M_, MLPD, HID, 1, 0, fl);
                k_gemm<<<dim3(74, 6), 256, 0, stream>>>(m1f, m2_w, m2woff, m2_b, boff,
                                                        nullptr, h, M_, HID, MLPD, 0, 1, fl);
            } else {
                for (int c = 0; c < 2; ++c) {
                    k_gemm<<<dim3(37, 24), 256, 0, stream>>>(nb + (size_t)c*2352*HID,
                                                             m1_w, m1woff, m1_b, m1boff,
                                                             m1c, nullptr, 2352, MLPD, HID, 1, 0, fl);
                    k_gemm<<<dim3(37, 6), 256, 0, stream>>>(m1c, m2_w, m2woff, m2_b, boff,
                                                            nullptr, h + (size_t)c*2352*HID,
                                                            2352, HID, MLPD, 0, 1, fl);
                }
            }
        }
    }
    k_final<<<M_, 64, 0, stream>>>(h, fn_g, fn_b, on_w, on_b, oe_w, oe_b, fl, (void*)d_out);
}